// Round 1
// baseline (796.303 us; speedup 1.0000x reference)
//
#include <hip/hip_runtime.h>

#define N_NODES 50000
#define N_EDGES 800000

__device__ __forceinline__ float lrelu(float x) { return x > 0.f ? x : 0.2f * x; }
__device__ __forceinline__ float elu(float x) { return x > 0.f ? x : expf(x) - 1.f; }

// ---------------- CSR build ----------------
__global__ __launch_bounds__(256) void hist_kernel(const int* __restrict__ ei, int* __restrict__ deg) {
  int e = blockIdx.x * 256 + threadIdx.x;
  if (e < N_EDGES) atomicAdd(&deg[ei[N_EDGES + e]], 1);
}

__global__ __launch_bounds__(256) void scan_kernel(const int* __restrict__ deg, int* __restrict__ rowptr) {
  __shared__ int sh[256];
  int t = threadIdx.x;
  const int chunk = (N_NODES + 255) / 256;  // 196
  int lo = t * chunk;
  int hi = lo + chunk; if (hi > N_NODES) hi = N_NODES;
  int sum = 0;
  for (int i = lo; i < hi; ++i) sum += deg[i];
  sh[t] = sum;
  __syncthreads();
  int incl = sum;
  for (int off = 1; off < 256; off <<= 1) {
    int u = (t >= off) ? sh[t - off] : 0;
    __syncthreads();
    incl += u;
    sh[t] = incl;
    __syncthreads();
  }
  int run = incl - sum;  // exclusive prefix
  for (int i = lo; i < hi; ++i) { rowptr[i] = run; run += deg[i]; }
  if (t == 255) rowptr[N_NODES] = run;
}

__global__ __launch_bounds__(256) void scatter_kernel(const int* __restrict__ ei, const int* __restrict__ rowptr,
                                                      int* __restrict__ cursor, int* __restrict__ col) {
  int e = blockIdx.x * 256 + threadIdx.x;
  if (e < N_EDGES) {
    int d = ei[N_EDGES + e];
    int pos = rowptr[d] + atomicAdd(&cursor[d], 1);
    col[pos] = ei[e];
  }
}

// ---------------- GEMM: Y[N,COLS] = A[N,128] @ W[128,COLS] ----------------
template <int COLS>
__global__ __launch_bounds__(256) void gemm_kernel(const float* __restrict__ A, const float* __restrict__ W,
                                                   float* __restrict__ Y) {
  constexpr int CPT = COLS / 16;  // cols per thread (8 or 4)
  __shared__ float ws[64 * COLS];
  __shared__ float xs[64 * 64];
  int t = threadIdx.x;
  int rbase = blockIdx.x * 64;
  int tx = t & 15, ty = t >> 4;
  float acc[4][CPT];
#pragma unroll
  for (int r = 0; r < 4; ++r)
#pragma unroll
    for (int c = 0; c < CPT; ++c) acc[r][c] = 0.f;

  const float4* A4 = (const float4*)A;
  const float4* W4 = (const float4*)W;
  for (int kt = 0; kt < 2; ++kt) {
    float4* ws4 = (float4*)ws;
    for (int i = t; i < 64 * COLS / 4; i += 256) ws4[i] = W4[kt * 16 * COLS + i];
    float4* xs4 = (float4*)xs;
    for (int i = t; i < 64 * 64 / 4; i += 256) {
      int row = i >> 4, kc = i & 15;
      int gr = rbase + row; if (gr >= N_NODES) gr = N_NODES - 1;
      xs4[i] = A4[gr * 32 + kt * 16 + kc];
    }
    __syncthreads();
#pragma unroll 8
    for (int k = 0; k < 64; ++k) {
      float xr[4];
#pragma unroll
      for (int r = 0; r < 4; ++r) xr[r] = xs[(ty * 4 + r) * 64 + k];
#pragma unroll
      for (int c4 = 0; c4 < CPT / 4; ++c4) {
        float4 wv = *(const float4*)&ws[k * COLS + tx * CPT + c4 * 4];
#pragma unroll
        for (int r = 0; r < 4; ++r) {
          acc[r][c4 * 4 + 0] += xr[r] * wv.x;
          acc[r][c4 * 4 + 1] += xr[r] * wv.y;
          acc[r][c4 * 4 + 2] += xr[r] * wv.z;
          acc[r][c4 * 4 + 3] += xr[r] * wv.w;
        }
      }
    }
    __syncthreads();
  }
#pragma unroll
  for (int r = 0; r < 4; ++r) {
    int row = rbase + ty * 4 + r;
    if (row < N_NODES) {
#pragma unroll
      for (int c4 = 0; c4 < CPT / 4; ++c4) {
        float4 v = make_float4(acc[r][c4 * 4], acc[r][c4 * 4 + 1], acc[r][c4 * 4 + 2], acc[r][c4 * 4 + 3]);
        *(float4*)&Y[row * COLS + tx * CPT + c4 * 4] = v;
      }
    }
  }
}

// ---------------- attention dot products ----------------
// layer 1: 4 heads x 32 feats; one wave per node
__global__ __launch_bounds__(256) void attn1_kernel(const float* __restrict__ h1, const float* __restrict__ atts,
                                                    const float* __restrict__ attd, float* __restrict__ as1,
                                                    float* __restrict__ ad1) {
  int n = (blockIdx.x * 256 + threadIdx.x) >> 6;
  int lane = threadIdx.x & 63;
  float v0 = h1[n * 128 + lane];
  float v1 = h1[n * 128 + 64 + lane];
  float s0 = v0 * atts[lane], s1 = v1 * atts[64 + lane];
  float d0 = v0 * attd[lane], d1 = v1 * attd[64 + lane];
#pragma unroll
  for (int off = 16; off >= 1; off >>= 1) {
    s0 += __shfl_xor(s0, off); s1 += __shfl_xor(s1, off);
    d0 += __shfl_xor(d0, off); d1 += __shfl_xor(d1, off);
  }
  if (lane == 0) {
    as1[n * 4 + 0] = s0; as1[n * 4 + 2] = s1;
    ad1[n * 4 + 0] = d0; ad1[n * 4 + 2] = d1;
  } else if (lane == 32) {
    as1[n * 4 + 1] = s0; as1[n * 4 + 3] = s1;
    ad1[n * 4 + 1] = d0; ad1[n * 4 + 3] = d1;
  }
}

// layer 2: 1 head x 64 feats
__global__ __launch_bounds__(256) void attn2_kernel(const float* __restrict__ h2, const float* __restrict__ atts,
                                                    const float* __restrict__ attd, float* __restrict__ as2,
                                                    float* __restrict__ ad2) {
  int n = (blockIdx.x * 256 + threadIdx.x) >> 6;
  int lane = threadIdx.x & 63;
  float v = h2[n * 64 + lane];
  float s = v * atts[lane];
  float d = v * attd[lane];
#pragma unroll
  for (int off = 32; off >= 1; off >>= 1) {
    s += __shfl_xor(s, off);
    d += __shfl_xor(d, off);
  }
  if (lane == 0) { as2[n] = s; ad2[n] = d; }
}

// ---------------- layer-1 aggregation: one wave per node ----------------
__global__ __launch_bounds__(256) void agg1_kernel(const float* __restrict__ h1, const float* __restrict__ as1,
                                                   const float* __restrict__ ad1, const int* __restrict__ rowptr,
                                                   const int* __restrict__ col, const float* __restrict__ b1,
                                                   float* __restrict__ h1e) {
  int n = (blockIdx.x * 256 + threadIdx.x) >> 6;
  int lane = threadIdx.x & 63;
  int beg = rowptr[n], end = rowptr[n + 1];
  float4 ad = *(const float4*)(ad1 + n * 4);
  float4 asn = *(const float4*)(as1 + n * 4);

  // pass 1: online segment max+sumexp per head (lane-parallel over edges)
  float m0 = -1e30f, m1 = -1e30f, m2 = -1e30f, m3 = -1e30f;
  float s0 = 0.f, s1 = 0.f, s2 = 0.f, s3 = 0.f;
  for (int i = beg + lane; i < end; i += 64) {
    int src = col[i];
    float4 a = *(const float4*)(as1 + src * 4);
    float l0 = lrelu(a.x + ad.x), l1 = lrelu(a.y + ad.y);
    float l2 = lrelu(a.z + ad.z), l3 = lrelu(a.w + ad.w);
    float M;
    M = fmaxf(m0, l0); s0 = s0 * expf(m0 - M) + expf(l0 - M); m0 = M;
    M = fmaxf(m1, l1); s1 = s1 * expf(m1 - M) + expf(l1 - M); m1 = M;
    M = fmaxf(m2, l2); s2 = s2 * expf(m2 - M) + expf(l2 - M); m2 = M;
    M = fmaxf(m3, l3); s3 = s3 * expf(m3 - M) + expf(l3 - M); m3 = M;
  }
#pragma unroll
  for (int off = 32; off >= 1; off >>= 1) {
    float mo, so, M;
    mo = __shfl_xor(m0, off); so = __shfl_xor(s0, off);
    M = fmaxf(m0, mo); s0 = s0 * expf(m0 - M) + so * expf(mo - M); m0 = M;
    mo = __shfl_xor(m1, off); so = __shfl_xor(s1, off);
    M = fmaxf(m1, mo); s1 = s1 * expf(m1 - M) + so * expf(mo - M); m1 = M;
    mo = __shfl_xor(m2, off); so = __shfl_xor(s2, off);
    M = fmaxf(m2, mo); s2 = s2 * expf(m2 - M) + so * expf(mo - M); m2 = M;
    mo = __shfl_xor(m3, off); so = __shfl_xor(s3, off);
    M = fmaxf(m3, mo); s3 = s3 * expf(m3 - M) + so * expf(mo - M); m3 = M;
  }
  // self loop
  {
    float l0 = lrelu(asn.x + ad.x), l1 = lrelu(asn.y + ad.y);
    float l2 = lrelu(asn.z + ad.z), l3 = lrelu(asn.w + ad.w);
    float M;
    M = fmaxf(m0, l0); s0 = s0 * expf(m0 - M) + expf(l0 - M); m0 = M;
    M = fmaxf(m1, l1); s1 = s1 * expf(m1 - M) + expf(l1 - M); m1 = M;
    M = fmaxf(m2, l2); s2 = s2 * expf(m2 - M) + expf(l2 - M); m2 = M;
    M = fmaxf(m3, l3); s3 = s3 * expf(m3 - M) + expf(l3 - M); m3 = M;
  }
  float d0 = 1.f / s0, d1 = 1.f / s1, d2 = 1.f / s2, d3 = 1.f / s3;

  // per-lane head selection: feature j=lane -> head 0/1, j=lane+64 -> head 2/3
  int hsel = lane >> 5;
  float mA = hsel ? m1 : m0, dA = hsel ? d1 : d0, adA = hsel ? ad.y : ad.x;
  float mB = hsel ? m3 : m2, dB = hsel ? d3 : d2, adB = hsel ? ad.w : ad.z;

  float acc0 = 0.f, acc1 = 0.f;
  for (int i = beg; i < end; ++i) {
    int src = col[i];
    float4 a = *(const float4*)(as1 + src * 4);
    float aA = hsel ? a.y : a.x;
    float aB = hsel ? a.w : a.z;
    float wA = expf(lrelu(aA + adA) - mA) * dA;
    float wB = expf(lrelu(aB + adB) - mB) * dB;
    acc0 += wA * h1[src * 128 + lane];
    acc1 += wB * h1[src * 128 + 64 + lane];
  }
  // self loop
  {
    float aA = hsel ? asn.y : asn.x;
    float aB = hsel ? asn.w : asn.z;
    float wA = expf(lrelu(aA + adA) - mA) * dA;
    float wB = expf(lrelu(aB + adB) - mB) * dB;
    acc0 += wA * h1[n * 128 + lane];
    acc1 += wB * h1[n * 128 + 64 + lane];
  }
  float f0 = acc0 + b1[lane];
  float f1 = acc1 + b1[lane + 64];
  h1e[n * 128 + lane] = elu(f0);
  h1e[n * 128 + 64 + lane] = elu(f1);
}

// ---------------- layer-2 aggregation + fused global add pool ----------------
__global__ __launch_bounds__(256) void agg2_kernel(const float* __restrict__ h2, const float* __restrict__ as2,
                                                   const float* __restrict__ ad2, const int* __restrict__ rowptr,
                                                   const int* __restrict__ col, const float* __restrict__ b2,
                                                   float* __restrict__ pooled) {
  __shared__ float red[256];
  int n = (blockIdx.x * 256 + threadIdx.x) >> 6;
  int lane = threadIdx.x & 63;
  int beg = rowptr[n], end = rowptr[n + 1];
  float adv = ad2[n];
  float m = -1e30f, s = 0.f;
  for (int i = beg + lane; i < end; i += 64) {
    float l = lrelu(as2[col[i]] + adv);
    float M = fmaxf(m, l); s = s * expf(m - M) + expf(l - M); m = M;
  }
#pragma unroll
  for (int off = 32; off >= 1; off >>= 1) {
    float mo = __shfl_xor(m, off), so = __shfl_xor(s, off);
    float M = fmaxf(m, mo); s = s * expf(m - M) + so * expf(mo - M); m = M;
  }
  float lself = lrelu(as2[n] + adv);
  {
    float M = fmaxf(m, lself); s = s * expf(m - M) + expf(lself - M); m = M;
  }
  float dinv = 1.f / s;
  float acc = 0.f;
  for (int i = beg; i < end; ++i) {
    int src = col[i];
    float w = expf(lrelu(as2[src] + adv) - m) * dinv;
    acc += w * h2[src * 64 + lane];
  }
  acc += expf(lself - m) * dinv * h2[n * 64 + lane];
  float f = elu(acc + b2[lane]);
  red[threadIdx.x] = f;
  __syncthreads();
  if (threadIdx.x < 64) {
    float sum = red[threadIdx.x] + red[threadIdx.x + 64] + red[threadIdx.x + 128] + red[threadIdx.x + 192];
    atomicAdd(&pooled[threadIdx.x], sum);
  }
}

// ---------------- final: write pooled + pooled@Wl+bl ----------------
__global__ void final_kernel(const float* __restrict__ pooled, const float* __restrict__ Wl,
                             const float* __restrict__ bl, float* __restrict__ out) {
  __shared__ float p[64];
  int t = threadIdx.x;
  float v = pooled[t];
  p[t] = v;
  out[t] = v;
  __syncthreads();
  if (t < 2) {
    float s = bl[t];
    for (int k = 0; k < 64; ++k) s += p[k] * Wl[k * 2 + t];
    out[64 + t] = s;
  }
}

extern "C" void kernel_launch(void* const* d_in, const int* in_sizes, int n_in,
                              void* d_out, int out_size, void* d_ws, size_t ws_size,
                              hipStream_t stream) {
  (void)in_sizes; (void)n_in; (void)out_size; (void)ws_size;
  const float* x     = (const float*)d_in[0];
  const int*   ei    = (const int*)d_in[1];
  const float* W1    = (const float*)d_in[2];
  const float* atts1 = (const float*)d_in[3];
  const float* attd1 = (const float*)d_in[4];
  const float* b1    = (const float*)d_in[5];
  const float* W2    = (const float*)d_in[6];
  const float* atts2 = (const float*)d_in[7];
  const float* attd2 = (const float*)d_in[8];
  const float* b2    = (const float*)d_in[9];
  const float* Wl    = (const float*)d_in[10];
  const float* bl    = (const float*)d_in[11];
  float* out = (float*)d_out;

  char* w = (char*)d_ws;
  float* h1  = (float*)w; w += (size_t)N_NODES * 128 * 4;
  float* h1e = (float*)w; w += (size_t)N_NODES * 128 * 4;
  float* h2  = (float*)w; w += (size_t)N_NODES * 64 * 4;
  float* as1 = (float*)w; w += (size_t)N_NODES * 4 * 4;
  float* ad1 = (float*)w; w += (size_t)N_NODES * 4 * 4;
  float* as2 = (float*)w; w += (size_t)N_NODES * 4;
  float* ad2 = (float*)w; w += (size_t)N_NODES * 4;
  int* deg    = (int*)w; w += (size_t)N_NODES * 4;
  int* cursor = (int*)w; w += (size_t)N_NODES * 4;
  float* pooled = (float*)w; w += 64 * 4;
  int* rowptr = (int*)w; w += (size_t)(N_NODES + 1) * 4 + 12;
  int* col    = (int*)w; w += (size_t)N_EDGES * 4;

  // zero deg + cursor + pooled (contiguous)
  hipMemsetAsync(deg, 0, (size_t)N_NODES * 8 + 256, stream);

  hist_kernel<<<(N_EDGES + 255) / 256, 256, 0, stream>>>(ei, deg);
  scan_kernel<<<1, 256, 0, stream>>>(deg, rowptr);
  scatter_kernel<<<(N_EDGES + 255) / 256, 256, 0, stream>>>(ei, rowptr, cursor, col);

  gemm_kernel<128><<<(N_NODES + 63) / 64, 256, 0, stream>>>(x, W1, h1);
  attn1_kernel<<<N_NODES / 4, 256, 0, stream>>>(h1, atts1, attd1, as1, ad1);
  agg1_kernel<<<N_NODES / 4, 256, 0, stream>>>(h1, as1, ad1, rowptr, col, b1, h1e);

  gemm_kernel<64><<<(N_NODES + 63) / 64, 256, 0, stream>>>(h1e, W2, h2);
  attn2_kernel<<<N_NODES / 4, 256, 0, stream>>>(h2, atts2, attd2, as2, ad2);
  agg2_kernel<<<N_NODES / 4, 256, 0, stream>>>(h2, as2, ad2, rowptr, col, b2, pooled);

  final_kernel<<<1, 64, 0, stream>>>(pooled, Wl, bl, out);
}

// Round 2
// 696.140 us; speedup vs baseline: 1.1439x; 1.1439x over previous
//
#include <hip/hip_runtime.h>

#define N_NODES 50000
#define N_EDGES 800000

__device__ __forceinline__ float lrelu(float x) { return x > 0.f ? x : 0.2f * x; }
__device__ __forceinline__ float elu(float x) { return x > 0.f ? x : expf(x) - 1.f; }

// ---------------- CSR build ----------------
__global__ __launch_bounds__(256) void hist_kernel(const int* __restrict__ ei, int* __restrict__ deg) {
  int e = blockIdx.x * 256 + threadIdx.x;
  if (e < N_EDGES) atomicAdd(&deg[ei[N_EDGES + e]], 1);
}

__global__ __launch_bounds__(256) void scan_kernel(const int* __restrict__ deg, int* __restrict__ rowptr) {
  __shared__ int sh[256];
  int t = threadIdx.x;
  const int chunk = (N_NODES + 255) / 256;  // 196
  int lo = t * chunk;
  int hi = lo + chunk; if (hi > N_NODES) hi = N_NODES;
  int sum = 0;
  for (int i = lo; i < hi; ++i) sum += deg[i];
  sh[t] = sum;
  __syncthreads();
  int incl = sum;
  for (int off = 1; off < 256; off <<= 1) {
    int u = (t >= off) ? sh[t - off] : 0;
    __syncthreads();
    incl += u;
    sh[t] = incl;
    __syncthreads();
  }
  int run = incl - sum;  // exclusive prefix
  for (int i = lo; i < hi; ++i) { rowptr[i] = run; run += deg[i]; }
  if (t == 255) rowptr[N_NODES] = run;
}

__global__ __launch_bounds__(256) void scatter_kernel(const int* __restrict__ ei, const int* __restrict__ rowptr,
                                                      int* __restrict__ cursor, int* __restrict__ col,
                                                      int* __restrict__ cdst) {
  int e = blockIdx.x * 256 + threadIdx.x;
  if (e < N_EDGES) {
    int d = ei[N_EDGES + e];
    int pos = rowptr[d] + atomicAdd(&cursor[d], 1);
    col[pos] = ei[e];
    cdst[pos] = d;
  }
}

// ---------------- GEMM: Y[N,COLS] = A[N,128] @ W[128,COLS] ----------------
template <int COLS>
__global__ __launch_bounds__(256) void gemm_kernel(const float* __restrict__ A, const float* __restrict__ W,
                                                   float* __restrict__ Y) {
  constexpr int CPT = COLS / 16;  // cols per thread (8 or 4)
  __shared__ float ws[64 * COLS];
  __shared__ float xs[64 * 64];
  int t = threadIdx.x;
  int rbase = blockIdx.x * 64;
  int tx = t & 15, ty = t >> 4;
  float acc[4][CPT];
#pragma unroll
  for (int r = 0; r < 4; ++r)
#pragma unroll
    for (int c = 0; c < CPT; ++c) acc[r][c] = 0.f;

  const float4* A4 = (const float4*)A;
  const float4* W4 = (const float4*)W;
  for (int kt = 0; kt < 2; ++kt) {
    float4* ws4 = (float4*)ws;
    for (int i = t; i < 64 * COLS / 4; i += 256) ws4[i] = W4[kt * 16 * COLS + i];
    float4* xs4 = (float4*)xs;
    for (int i = t; i < 64 * 64 / 4; i += 256) {
      int row = i >> 4, kc = i & 15;
      int gr = rbase + row; if (gr >= N_NODES) gr = N_NODES - 1;
      xs4[i] = A4[gr * 32 + kt * 16 + kc];
    }
    __syncthreads();
#pragma unroll 8
    for (int k = 0; k < 64; ++k) {
      float xr[4];
#pragma unroll
      for (int r = 0; r < 4; ++r) xr[r] = xs[(ty * 4 + r) * 64 + k];
#pragma unroll
      for (int c4 = 0; c4 < CPT / 4; ++c4) {
        float4 wv = *(const float4*)&ws[k * COLS + tx * CPT + c4 * 4];
#pragma unroll
        for (int r = 0; r < 4; ++r) {
          acc[r][c4 * 4 + 0] += xr[r] * wv.x;
          acc[r][c4 * 4 + 1] += xr[r] * wv.y;
          acc[r][c4 * 4 + 2] += xr[r] * wv.z;
          acc[r][c4 * 4 + 3] += xr[r] * wv.w;
        }
      }
    }
    __syncthreads();
  }
#pragma unroll
  for (int r = 0; r < 4; ++r) {
    int row = rbase + ty * 4 + r;
    if (row < N_NODES) {
#pragma unroll
      for (int c4 = 0; c4 < CPT / 4; ++c4) {
        float4 v = make_float4(acc[r][c4 * 4], acc[r][c4 * 4 + 1], acc[r][c4 * 4 + 2], acc[r][c4 * 4 + 3]);
        *(float4*)&Y[row * COLS + tx * CPT + c4 * 4] = v;
      }
    }
  }
}

// ---------------- attention dot products ----------------
__global__ __launch_bounds__(256) void attn1_kernel(const float* __restrict__ h1, const float* __restrict__ atts,
                                                    const float* __restrict__ attd, float* __restrict__ as1,
                                                    float* __restrict__ ad1) {
  int n = (blockIdx.x * 256 + threadIdx.x) >> 6;
  int lane = threadIdx.x & 63;
  float v0 = h1[n * 128 + lane];
  float v1 = h1[n * 128 + 64 + lane];
  float s0 = v0 * atts[lane], s1 = v1 * atts[64 + lane];
  float d0 = v0 * attd[lane], d1 = v1 * attd[64 + lane];
#pragma unroll
  for (int off = 16; off >= 1; off >>= 1) {
    s0 += __shfl_xor(s0, off); s1 += __shfl_xor(s1, off);
    d0 += __shfl_xor(d0, off); d1 += __shfl_xor(d1, off);
  }
  if (lane == 0) {
    as1[n * 4 + 0] = s0; as1[n * 4 + 2] = s1;
    ad1[n * 4 + 0] = d0; ad1[n * 4 + 2] = d1;
  } else if (lane == 32) {
    as1[n * 4 + 1] = s0; as1[n * 4 + 3] = s1;
    ad1[n * 4 + 1] = d0; ad1[n * 4 + 3] = d1;
  }
}

__global__ __launch_bounds__(256) void attn2_kernel(const float* __restrict__ h2, const float* __restrict__ atts,
                                                    const float* __restrict__ attd, float* __restrict__ as2,
                                                    float* __restrict__ ad2) {
  int n = (blockIdx.x * 256 + threadIdx.x) >> 6;
  int lane = threadIdx.x & 63;
  float v = h2[n * 64 + lane];
  float s = v * atts[lane];
  float d = v * attd[lane];
#pragma unroll
  for (int off = 32; off >= 1; off >>= 1) {
    s += __shfl_xor(s, off);
    d += __shfl_xor(d, off);
  }
  if (lane == 0) { as2[n] = s; ad2[n] = d; }
}

// ---------------- softmax stats: per-node m and 1/sum (incl. self loop) ----------------
__global__ __launch_bounds__(256) void red1_kernel(const float4* __restrict__ as1v, const float4* __restrict__ ad1v,
                                                   const int* __restrict__ rowptr, const int* __restrict__ col,
                                                   float4* __restrict__ m1v, float4* __restrict__ di1v) {
  int n = (blockIdx.x * 256 + threadIdx.x) >> 6;
  int lane = threadIdx.x & 63;
  int beg = rowptr[n], end = rowptr[n + 1];
  float4 ad = ad1v[n];
  float4 asn = as1v[n];
  float m0 = -1e30f, m1 = -1e30f, m2 = -1e30f, m3 = -1e30f;
  float s0 = 0.f, s1 = 0.f, s2 = 0.f, s3 = 0.f;
  for (int i = beg + lane; i < end; i += 64) {
    float4 a = as1v[col[i]];
    float l0 = lrelu(a.x + ad.x), l1 = lrelu(a.y + ad.y);
    float l2 = lrelu(a.z + ad.z), l3 = lrelu(a.w + ad.w);
    float M;
    M = fmaxf(m0, l0); s0 = s0 * expf(m0 - M) + expf(l0 - M); m0 = M;
    M = fmaxf(m1, l1); s1 = s1 * expf(m1 - M) + expf(l1 - M); m1 = M;
    M = fmaxf(m2, l2); s2 = s2 * expf(m2 - M) + expf(l2 - M); m2 = M;
    M = fmaxf(m3, l3); s3 = s3 * expf(m3 - M) + expf(l3 - M); m3 = M;
  }
#pragma unroll
  for (int off = 32; off >= 1; off >>= 1) {
    float mo, so, M;
    mo = __shfl_xor(m0, off); so = __shfl_xor(s0, off);
    M = fmaxf(m0, mo); s0 = s0 * expf(m0 - M) + so * expf(mo - M); m0 = M;
    mo = __shfl_xor(m1, off); so = __shfl_xor(s1, off);
    M = fmaxf(m1, mo); s1 = s1 * expf(m1 - M) + so * expf(mo - M); m1 = M;
    mo = __shfl_xor(m2, off); so = __shfl_xor(s2, off);
    M = fmaxf(m2, mo); s2 = s2 * expf(m2 - M) + so * expf(mo - M); m2 = M;
    mo = __shfl_xor(m3, off); so = __shfl_xor(s3, off);
    M = fmaxf(m3, mo); s3 = s3 * expf(m3 - M) + so * expf(mo - M); m3 = M;
  }
  // self loop
  float l0 = lrelu(asn.x + ad.x), l1 = lrelu(asn.y + ad.y);
  float l2 = lrelu(asn.z + ad.z), l3 = lrelu(asn.w + ad.w);
  float M;
  M = fmaxf(m0, l0); s0 = s0 * expf(m0 - M) + expf(l0 - M); m0 = M;
  M = fmaxf(m1, l1); s1 = s1 * expf(m1 - M) + expf(l1 - M); m1 = M;
  M = fmaxf(m2, l2); s2 = s2 * expf(m2 - M) + expf(l2 - M); m2 = M;
  M = fmaxf(m3, l3); s3 = s3 * expf(m3 - M) + expf(l3 - M); m3 = M;
  if (lane == 0) {
    m1v[n] = make_float4(m0, m1, m2, m3);
    di1v[n] = make_float4(1.f / s0, 1.f / s1, 1.f / s2, 1.f / s3);
  }
}

__global__ __launch_bounds__(256) void red2_kernel(const float* __restrict__ as2, const float* __restrict__ ad2,
                                                   const int* __restrict__ rowptr, const int* __restrict__ col,
                                                   float* __restrict__ m2a, float* __restrict__ di2a) {
  int n = (blockIdx.x * 256 + threadIdx.x) >> 6;
  int lane = threadIdx.x & 63;
  int beg = rowptr[n], end = rowptr[n + 1];
  float adv = ad2[n];
  float m = -1e30f, s = 0.f;
  for (int i = beg + lane; i < end; i += 64) {
    float l = lrelu(as2[col[i]] + adv);
    float M = fmaxf(m, l); s = s * expf(m - M) + expf(l - M); m = M;
  }
#pragma unroll
  for (int off = 32; off >= 1; off >>= 1) {
    float mo = __shfl_xor(m, off), so = __shfl_xor(s, off);
    float M = fmaxf(m, mo); s = s * expf(m - M) + so * expf(mo - M); m = M;
  }
  float lself = lrelu(as2[n] + adv);
  float M = fmaxf(m, lself); s = s * expf(m - M) + expf(lself - M); m = M;
  if (lane == 0) { m2a[n] = M; di2a[n] = 1.f / s; }
}

// ---------------- edge-parallel alpha ----------------
__global__ __launch_bounds__(256) void alpha1_kernel(const int* __restrict__ col, const int* __restrict__ cdst,
                                                     const float4* __restrict__ as1v, const float4* __restrict__ ad1v,
                                                     const float4* __restrict__ m1v, const float4* __restrict__ di1v,
                                                     float4* __restrict__ alpha1v) {
  int p = blockIdx.x * 256 + threadIdx.x;
  if (p >= N_EDGES) return;
  int s = col[p], d = cdst[p];
  float4 a = as1v[s], b = ad1v[d], m = m1v[d], di = di1v[d];
  float4 o;
  o.x = expf(lrelu(a.x + b.x) - m.x) * di.x;
  o.y = expf(lrelu(a.y + b.y) - m.y) * di.y;
  o.z = expf(lrelu(a.z + b.z) - m.z) * di.z;
  o.w = expf(lrelu(a.w + b.w) - m.w) * di.w;
  alpha1v[p] = o;
}

__global__ __launch_bounds__(256) void alpha2_kernel(const int* __restrict__ col, const int* __restrict__ cdst,
                                                     const float* __restrict__ as2, const float* __restrict__ ad2,
                                                     const float* __restrict__ m2a, const float* __restrict__ di2a,
                                                     float* __restrict__ alpha2a) {
  int p = blockIdx.x * 256 + threadIdx.x;
  if (p >= N_EDGES) return;
  int s = col[p], d = cdst[p];
  alpha2a[p] = expf(lrelu(as2[s] + ad2[d]) - m2a[d]) * di2a[d];
}

// ---------------- layer-1 gather: one wave per node, unroll x4 ----------------
__global__ __launch_bounds__(256) void agg1_kernel(const float* __restrict__ h1, const float4* __restrict__ alpha1v,
                                                   const int* __restrict__ rowptr, const int* __restrict__ col,
                                                   const float4* __restrict__ as1v, const float4* __restrict__ ad1v,
                                                   const float4* __restrict__ m1v, const float4* __restrict__ di1v,
                                                   const float* __restrict__ b1, float* __restrict__ h1e) {
  int n = (blockIdx.x * 256 + threadIdx.x) >> 6;
  int lane = threadIdx.x & 63;
  int beg = rowptr[n], end = rowptr[n + 1];
  int hsel = lane >> 5;

  float acc0 = 0.f, acc1 = 0.f;
  int i = beg;
  for (; i + 4 <= end; i += 4) {
    int s0 = col[i + 0], s1 = col[i + 1], s2 = col[i + 2], s3 = col[i + 3];
    float4 A0 = alpha1v[i + 0], A1 = alpha1v[i + 1], A2 = alpha1v[i + 2], A3 = alpha1v[i + 3];
    float x00 = h1[s0 * 128 + lane],      x10 = h1[s1 * 128 + lane];
    float x20 = h1[s2 * 128 + lane],      x30 = h1[s3 * 128 + lane];
    float x01 = h1[s0 * 128 + 64 + lane], x11 = h1[s1 * 128 + 64 + lane];
    float x21 = h1[s2 * 128 + 64 + lane], x31 = h1[s3 * 128 + 64 + lane];
    acc0 += (hsel ? A0.y : A0.x) * x00 + (hsel ? A1.y : A1.x) * x10 +
            (hsel ? A2.y : A2.x) * x20 + (hsel ? A3.y : A3.x) * x30;
    acc1 += (hsel ? A0.w : A0.z) * x01 + (hsel ? A1.w : A1.z) * x11 +
            (hsel ? A2.w : A2.z) * x21 + (hsel ? A3.w : A3.z) * x31;
  }
  for (; i < end; ++i) {
    int s0 = col[i];
    float4 A = alpha1v[i];
    acc0 += (hsel ? A.y : A.x) * h1[s0 * 128 + lane];
    acc1 += (hsel ? A.w : A.z) * h1[s0 * 128 + 64 + lane];
  }
  // self loop
  float4 asn = as1v[n], adn = ad1v[n], mv = m1v[n], dv = di1v[n];
  float wA = expf(lrelu((hsel ? asn.y : asn.x) + (hsel ? adn.y : adn.x)) - (hsel ? mv.y : mv.x)) * (hsel ? dv.y : dv.x);
  float wB = expf(lrelu((hsel ? asn.w : asn.z) + (hsel ? adn.w : adn.z)) - (hsel ? mv.w : mv.z)) * (hsel ? dv.w : dv.z);
  acc0 += wA * h1[n * 128 + lane];
  acc1 += wB * h1[n * 128 + 64 + lane];

  h1e[n * 128 + lane] = elu(acc0 + b1[lane]);
  h1e[n * 128 + 64 + lane] = elu(acc1 + b1[lane + 64]);
}

// ---------------- layer-2 gather + fused global add pool ----------------
__global__ __launch_bounds__(256) void agg2_kernel(const float* __restrict__ h2, const float* __restrict__ alpha2a,
                                                   const int* __restrict__ rowptr, const int* __restrict__ col,
                                                   const float* __restrict__ as2, const float* __restrict__ ad2,
                                                   const float* __restrict__ m2a, const float* __restrict__ di2a,
                                                   const float* __restrict__ b2, float* __restrict__ pooled) {
  __shared__ float red[256];
  int n = (blockIdx.x * 256 + threadIdx.x) >> 6;
  int lane = threadIdx.x & 63;
  int beg = rowptr[n], end = rowptr[n + 1];

  float acc = 0.f;
  int i = beg;
  for (; i + 4 <= end; i += 4) {
    int s0 = col[i + 0], s1 = col[i + 1], s2 = col[i + 2], s3 = col[i + 3];
    float w0 = alpha2a[i + 0], w1 = alpha2a[i + 1], w2 = alpha2a[i + 2], w3 = alpha2a[i + 3];
    acc += w0 * h2[s0 * 64 + lane] + w1 * h2[s1 * 64 + lane] +
           w2 * h2[s2 * 64 + lane] + w3 * h2[s3 * 64 + lane];
  }
  for (; i < end; ++i) acc += alpha2a[i] * h2[col[i] * 64 + lane];
  // self loop
  float wself = expf(lrelu(as2[n] + ad2[n]) - m2a[n]) * di2a[n];
  acc += wself * h2[n * 64 + lane];

  float f = elu(acc + b2[lane]);
  red[threadIdx.x] = f;
  __syncthreads();
  if (threadIdx.x < 64) {
    float sum = red[threadIdx.x] + red[threadIdx.x + 64] + red[threadIdx.x + 128] + red[threadIdx.x + 192];
    atomicAdd(&pooled[threadIdx.x], sum);
  }
}

// ---------------- final: write pooled + pooled@Wl+bl ----------------
__global__ void final_kernel(const float* __restrict__ pooled, const float* __restrict__ Wl,
                             const float* __restrict__ bl, float* __restrict__ out) {
  __shared__ float p[64];
  int t = threadIdx.x;
  float v = pooled[t];
  p[t] = v;
  out[t] = v;
  __syncthreads();
  if (t < 2) {
    float s = bl[t];
    for (int k = 0; k < 64; ++k) s += p[k] * Wl[k * 2 + t];
    out[64 + t] = s;
  }
}

extern "C" void kernel_launch(void* const* d_in, const int* in_sizes, int n_in,
                              void* d_out, int out_size, void* d_ws, size_t ws_size,
                              hipStream_t stream) {
  (void)in_sizes; (void)n_in; (void)out_size; (void)ws_size;
  const float* x     = (const float*)d_in[0];
  const int*   ei    = (const int*)d_in[1];
  const float* W1    = (const float*)d_in[2];
  const float* atts1 = (const float*)d_in[3];
  const float* attd1 = (const float*)d_in[4];
  const float* b1    = (const float*)d_in[5];
  const float* W2    = (const float*)d_in[6];
  const float* atts2 = (const float*)d_in[7];
  const float* attd2 = (const float*)d_in[8];
  const float* b2    = (const float*)d_in[9];
  const float* Wl    = (const float*)d_in[10];
  const float* bl    = (const float*)d_in[11];
  float* out = (float*)d_out;

  char* w = (char*)d_ws;
  float* h1   = (float*)w; w += (size_t)N_NODES * 128 * 4;   // 25.6 MB (alias: alpha2 after agg1)
  float* h1e  = (float*)w; w += (size_t)N_NODES * 128 * 4;   // 25.6 MB
  float* h2   = (float*)w; w += (size_t)N_EDGES * 16;        // 12.8 MB (alias: alpha1 before gemm64)
  float* as1  = (float*)w; w += (size_t)N_NODES * 16;
  float* ad1  = (float*)w; w += (size_t)N_NODES * 16;
  float* m1   = (float*)w; w += (size_t)N_NODES * 16;
  float* di1  = (float*)w; w += (size_t)N_NODES * 16;
  float* as2  = (float*)w; w += (size_t)N_NODES * 4;
  float* ad2  = (float*)w; w += (size_t)N_NODES * 4;
  float* m2a  = (float*)w; w += (size_t)N_NODES * 4;
  float* di2a = (float*)w; w += (size_t)N_NODES * 4;
  int* deg    = (int*)w; w += (size_t)N_NODES * 4;
  int* cursor = (int*)w; w += (size_t)N_NODES * 4;
  float* pooled = (float*)w; w += 256;
  int* rowptr = (int*)w; w += (size_t)(N_NODES + 1) * 4 + 12;
  int* col    = (int*)w; w += (size_t)N_EDGES * 4;
  int* cdst   = (int*)w; w += (size_t)N_EDGES * 4;

  float4* alpha1v = (float4*)h2;   // lifetime: after red1 .. agg1; h2 written after agg1
  float*  alpha2a = h1;            // lifetime: after red2 .. agg2; h1 dead after agg1

  // zero deg + cursor + pooled (contiguous)
  hipMemsetAsync(deg, 0, (size_t)N_NODES * 8 + 256, stream);

  hist_kernel<<<(N_EDGES + 255) / 256, 256, 0, stream>>>(ei, deg);
  scan_kernel<<<1, 256, 0, stream>>>(deg, rowptr);
  scatter_kernel<<<(N_EDGES + 255) / 256, 256, 0, stream>>>(ei, rowptr, cursor, col, cdst);

  gemm_kernel<128><<<(N_NODES + 63) / 64, 256, 0, stream>>>(x, W1, h1);
  attn1_kernel<<<N_NODES / 4, 256, 0, stream>>>(h1, atts1, attd1, as1, ad1);
  red1_kernel<<<N_NODES / 4, 256, 0, stream>>>((const float4*)as1, (const float4*)ad1, rowptr, col,
                                               (float4*)m1, (float4*)di1);
  alpha1_kernel<<<(N_EDGES + 255) / 256, 256, 0, stream>>>(col, cdst, (const float4*)as1, (const float4*)ad1,
                                                           (const float4*)m1, (const float4*)di1, alpha1v);
  agg1_kernel<<<N_NODES / 4, 256, 0, stream>>>(h1, alpha1v, rowptr, col, (const float4*)as1, (const float4*)ad1,
                                               (const float4*)m1, (const float4*)di1, b1, h1e);

  gemm_kernel<64><<<(N_NODES + 63) / 64, 256, 0, stream>>>(h1e, W2, h2);
  attn2_kernel<<<N_NODES / 4, 256, 0, stream>>>(h2, atts2, attd2, as2, ad2);
  red2_kernel<<<N_NODES / 4, 256, 0, stream>>>(as2, ad2, rowptr, col, m2a, di2a);
  alpha2_kernel<<<(N_EDGES + 255) / 256, 256, 0, stream>>>(col, cdst, as2, ad2, m2a, di2a, alpha2a);
  agg2_kernel<<<N_NODES / 4, 256, 0, stream>>>(h2, alpha2a, rowptr, col, as2, ad2, m2a, di2a, b2, pooled);

  final_kernel<<<1, 64, 0, stream>>>(pooled, Wl, bl, out);
}

// Round 3
// 544.298 us; speedup vs baseline: 1.4630x; 1.2790x over previous
//
#include <hip/hip_runtime.h>

#define N_NODES 50000
#define N_EDGES 800000

__device__ __forceinline__ float lrelu(float x) { return x > 0.f ? x : 0.2f * x; }
__device__ __forceinline__ float elu(float x) { return x > 0.f ? x : expf(x) - 1.f; }

// ---------------- CSR build ----------------
__global__ __launch_bounds__(256) void hist_kernel(const int* __restrict__ ei, int* __restrict__ deg) {
  int e = blockIdx.x * 256 + threadIdx.x;
  if (e < N_EDGES) atomicAdd(&deg[ei[N_EDGES + e]], 1);
}

__global__ __launch_bounds__(256) void scan_kernel(const int* __restrict__ deg, int* __restrict__ rowptr) {
  __shared__ int sh[256];
  int t = threadIdx.x;
  const int chunk = (N_NODES + 255) / 256;  // 196
  int lo = t * chunk;
  int hi = lo + chunk; if (hi > N_NODES) hi = N_NODES;
  int sum = 0;
  for (int i = lo; i < hi; ++i) sum += deg[i];
  sh[t] = sum;
  __syncthreads();
  int incl = sum;
  for (int off = 1; off < 256; off <<= 1) {
    int u = (t >= off) ? sh[t - off] : 0;
    __syncthreads();
    incl += u;
    sh[t] = incl;
    __syncthreads();
  }
  int run = incl - sum;  // exclusive prefix
  for (int i = lo; i < hi; ++i) { rowptr[i] = run; run += deg[i]; }
  if (t == 255) rowptr[N_NODES] = run;
}

__global__ __launch_bounds__(256) void scatter_kernel(const int* __restrict__ ei, const int* __restrict__ rowptr,
                                                      int* __restrict__ cursor, int* __restrict__ col,
                                                      int* __restrict__ cdst) {
  int e = blockIdx.x * 256 + threadIdx.x;
  if (e < N_EDGES) {
    int d = ei[N_EDGES + e];
    int pos = rowptr[d] + atomicAdd(&cursor[d], 1);
    col[pos] = ei[e];
    cdst[pos] = d;
  }
}

// ---------------- GEMM: Y[N,COLS] = A[N,128] @ W[128,COLS] ----------------
template <int COLS>
__global__ __launch_bounds__(256) void gemm_kernel(const float* __restrict__ A, const float* __restrict__ W,
                                                   float* __restrict__ Y) {
  constexpr int CPT = COLS / 16;  // cols per thread (8 or 4)
  __shared__ float ws[64 * COLS];
  __shared__ float xs[64 * 64];
  int t = threadIdx.x;
  int rbase = blockIdx.x * 64;
  int tx = t & 15, ty = t >> 4;
  float acc[4][CPT];
#pragma unroll
  for (int r = 0; r < 4; ++r)
#pragma unroll
    for (int c = 0; c < CPT; ++c) acc[r][c] = 0.f;

  const float4* A4 = (const float4*)A;
  const float4* W4 = (const float4*)W;
  for (int kt = 0; kt < 2; ++kt) {
    float4* ws4 = (float4*)ws;
    for (int i = t; i < 64 * COLS / 4; i += 256) ws4[i] = W4[kt * 16 * COLS + i];
    float4* xs4 = (float4*)xs;
    for (int i = t; i < 64 * 64 / 4; i += 256) {
      int row = i >> 4, kc = i & 15;
      int gr = rbase + row; if (gr >= N_NODES) gr = N_NODES - 1;
      xs4[i] = A4[gr * 32 + kt * 16 + kc];
    }
    __syncthreads();
#pragma unroll 8
    for (int k = 0; k < 64; ++k) {
      float xr[4];
#pragma unroll
      for (int r = 0; r < 4; ++r) xr[r] = xs[(ty * 4 + r) * 64 + k];
#pragma unroll
      for (int c4 = 0; c4 < CPT / 4; ++c4) {
        float4 wv = *(const float4*)&ws[k * COLS + tx * CPT + c4 * 4];
#pragma unroll
        for (int r = 0; r < 4; ++r) {
          acc[r][c4 * 4 + 0] += xr[r] * wv.x;
          acc[r][c4 * 4 + 1] += xr[r] * wv.y;
          acc[r][c4 * 4 + 2] += xr[r] * wv.z;
          acc[r][c4 * 4 + 3] += xr[r] * wv.w;
        }
      }
    }
    __syncthreads();
  }
#pragma unroll
  for (int r = 0; r < 4; ++r) {
    int row = rbase + ty * 4 + r;
    if (row < N_NODES) {
#pragma unroll
      for (int c4 = 0; c4 < CPT / 4; ++c4) {
        float4 v = make_float4(acc[r][c4 * 4], acc[r][c4 * 4 + 1], acc[r][c4 * 4 + 2], acc[r][c4 * 4 + 3]);
        *(float4*)&Y[row * COLS + tx * CPT + c4 * 4] = v;
      }
    }
  }
}

// ---------------- attention dot products ----------------
__global__ __launch_bounds__(256) void attn1_kernel(const float* __restrict__ h1, const float* __restrict__ atts,
                                                    const float* __restrict__ attd, float* __restrict__ as1,
                                                    float* __restrict__ ad1) {
  int n = (blockIdx.x * 256 + threadIdx.x) >> 6;
  int lane = threadIdx.x & 63;
  float v0 = h1[n * 128 + lane];
  float v1 = h1[n * 128 + 64 + lane];
  float s0 = v0 * atts[lane], s1 = v1 * atts[64 + lane];
  float d0 = v0 * attd[lane], d1 = v1 * attd[64 + lane];
#pragma unroll
  for (int off = 16; off >= 1; off >>= 1) {
    s0 += __shfl_xor(s0, off); s1 += __shfl_xor(s1, off);
    d0 += __shfl_xor(d0, off); d1 += __shfl_xor(d1, off);
  }
  if (lane == 0) {
    as1[n * 4 + 0] = s0; as1[n * 4 + 2] = s1;
    ad1[n * 4 + 0] = d0; ad1[n * 4 + 2] = d1;
  } else if (lane == 32) {
    as1[n * 4 + 1] = s0; as1[n * 4 + 3] = s1;
    ad1[n * 4 + 1] = d0; ad1[n * 4 + 3] = d1;
  }
}

__global__ __launch_bounds__(256) void attn2_kernel(const float* __restrict__ h2, const float* __restrict__ atts,
                                                    const float* __restrict__ attd, float* __restrict__ as2,
                                                    float* __restrict__ ad2) {
  int n = (blockIdx.x * 256 + threadIdx.x) >> 6;
  int lane = threadIdx.x & 63;
  float v = h2[n * 64 + lane];
  float s = v * atts[lane];
  float d = v * attd[lane];
#pragma unroll
  for (int off = 32; off >= 1; off >>= 1) {
    s += __shfl_xor(s, off);
    d += __shfl_xor(d, off);
  }
  if (lane == 0) { as2[n] = s; ad2[n] = d; }
}

// ---------------- softmax stats: per-node m and 1/sum (incl. self loop) ----------------
__global__ __launch_bounds__(256) void red1_kernel(const float4* __restrict__ as1v, const float4* __restrict__ ad1v,
                                                   const int* __restrict__ rowptr, const int* __restrict__ col,
                                                   float4* __restrict__ m1v, float4* __restrict__ di1v) {
  int n = (blockIdx.x * 256 + threadIdx.x) >> 6;
  int lane = threadIdx.x & 63;
  int beg = rowptr[n], end = rowptr[n + 1];
  float4 ad = ad1v[n];
  float4 asn = as1v[n];
  float m0 = -1e30f, m1 = -1e30f, m2 = -1e30f, m3 = -1e30f;
  float s0 = 0.f, s1 = 0.f, s2 = 0.f, s3 = 0.f;
  for (int i = beg + lane; i < end; i += 64) {
    float4 a = as1v[col[i]];
    float l0 = lrelu(a.x + ad.x), l1 = lrelu(a.y + ad.y);
    float l2 = lrelu(a.z + ad.z), l3 = lrelu(a.w + ad.w);
    float M;
    M = fmaxf(m0, l0); s0 = s0 * expf(m0 - M) + expf(l0 - M); m0 = M;
    M = fmaxf(m1, l1); s1 = s1 * expf(m1 - M) + expf(l1 - M); m1 = M;
    M = fmaxf(m2, l2); s2 = s2 * expf(m2 - M) + expf(l2 - M); m2 = M;
    M = fmaxf(m3, l3); s3 = s3 * expf(m3 - M) + expf(l3 - M); m3 = M;
  }
#pragma unroll
  for (int off = 32; off >= 1; off >>= 1) {
    float mo, so, M;
    mo = __shfl_xor(m0, off); so = __shfl_xor(s0, off);
    M = fmaxf(m0, mo); s0 = s0 * expf(m0 - M) + so * expf(mo - M); m0 = M;
    mo = __shfl_xor(m1, off); so = __shfl_xor(s1, off);
    M = fmaxf(m1, mo); s1 = s1 * expf(m1 - M) + so * expf(mo - M); m1 = M;
    mo = __shfl_xor(m2, off); so = __shfl_xor(s2, off);
    M = fmaxf(m2, mo); s2 = s2 * expf(m2 - M) + so * expf(mo - M); m2 = M;
    mo = __shfl_xor(m3, off); so = __shfl_xor(s3, off);
    M = fmaxf(m3, mo); s3 = s3 * expf(m3 - M) + so * expf(mo - M); m3 = M;
  }
  // self loop
  float l0 = lrelu(asn.x + ad.x), l1 = lrelu(asn.y + ad.y);
  float l2 = lrelu(asn.z + ad.z), l3 = lrelu(asn.w + ad.w);
  float M;
  M = fmaxf(m0, l0); s0 = s0 * expf(m0 - M) + expf(l0 - M); m0 = M;
  M = fmaxf(m1, l1); s1 = s1 * expf(m1 - M) + expf(l1 - M); m1 = M;
  M = fmaxf(m2, l2); s2 = s2 * expf(m2 - M) + expf(l2 - M); m2 = M;
  M = fmaxf(m3, l3); s3 = s3 * expf(m3 - M) + expf(l3 - M); m3 = M;
  if (lane == 0) {
    m1v[n] = make_float4(m0, m1, m2, m3);
    di1v[n] = make_float4(1.f / s0, 1.f / s1, 1.f / s2, 1.f / s3);
  }
}

__global__ __launch_bounds__(256) void red2_kernel(const float* __restrict__ as2, const float* __restrict__ ad2,
                                                   const int* __restrict__ rowptr, const int* __restrict__ col,
                                                   float* __restrict__ m2a, float* __restrict__ di2a) {
  int n = (blockIdx.x * 256 + threadIdx.x) >> 6;
  int lane = threadIdx.x & 63;
  int beg = rowptr[n], end = rowptr[n + 1];
  float adv = ad2[n];
  float m = -1e30f, s = 0.f;
  for (int i = beg + lane; i < end; i += 64) {
    float l = lrelu(as2[col[i]] + adv);
    float M = fmaxf(m, l); s = s * expf(m - M) + expf(l - M); m = M;
  }
#pragma unroll
  for (int off = 32; off >= 1; off >>= 1) {
    float mo = __shfl_xor(m, off), so = __shfl_xor(s, off);
    float M = fmaxf(m, mo); s = s * expf(m - M) + so * expf(mo - M); m = M;
  }
  float lself = lrelu(as2[n] + adv);
  float M = fmaxf(m, lself); s = s * expf(m - M) + expf(lself - M); m = M;
  if (lane == 0) { m2a[n] = M; di2a[n] = 1.f / s; }
}

// ---------------- edge-parallel alpha ----------------
__global__ __launch_bounds__(256) void alpha1_kernel(const int* __restrict__ col, const int* __restrict__ cdst,
                                                     const float4* __restrict__ as1v, const float4* __restrict__ ad1v,
                                                     const float4* __restrict__ m1v, const float4* __restrict__ di1v,
                                                     float4* __restrict__ alpha1v) {
  int p = blockIdx.x * 256 + threadIdx.x;
  if (p >= N_EDGES) return;
  int s = col[p], d = cdst[p];
  float4 a = as1v[s], b = ad1v[d], m = m1v[d], di = di1v[d];
  float4 o;
  o.x = expf(lrelu(a.x + b.x) - m.x) * di.x;
  o.y = expf(lrelu(a.y + b.y) - m.y) * di.y;
  o.z = expf(lrelu(a.z + b.z) - m.z) * di.z;
  o.w = expf(lrelu(a.w + b.w) - m.w) * di.w;
  alpha1v[p] = o;
}

__global__ __launch_bounds__(256) void alpha2_kernel(const int* __restrict__ col, const int* __restrict__ cdst,
                                                     const float* __restrict__ as2, const float* __restrict__ ad2,
                                                     const float* __restrict__ m2a, const float* __restrict__ di2a,
                                                     float* __restrict__ alpha2a) {
  int p = blockIdx.x * 256 + threadIdx.x;
  if (p >= N_EDGES) return;
  int s = col[p], d = cdst[p];
  alpha2a[p] = expf(lrelu(as2[s] + ad2[d]) - m2a[d]) * di2a[d];
}

// ---------------- layer-1 gather: one wave per node, float4 lanes (2 rows/instr) ----------------
__global__ __launch_bounds__(256) void agg1_kernel(const float4* __restrict__ h1v, const float* __restrict__ alpha1,
                                                   const int* __restrict__ rowptr, const int* __restrict__ col,
                                                   const float* __restrict__ as1, const float* __restrict__ ad1,
                                                   const float* __restrict__ m1, const float* __restrict__ di1,
                                                   const float4* __restrict__ b1v, float4* __restrict__ h1ev) {
  int n = (blockIdx.x * 256 + threadIdx.x) >> 6;
  int lane = threadIdx.x & 63;
  int slot = lane >> 5;  // 0..1: which edge within a pair
  int fq = lane & 31;    // feature quarter: feats fq*4 .. fq*4+3
  int h = fq >> 3;       // head index for these 4 feats
  int beg = rowptr[n], end = rowptr[n + 1];

  float4 acc = make_float4(0.f, 0.f, 0.f, 0.f);
  int i = beg;
  for (; i + 8 <= end; i += 8) {
#pragma unroll
    for (int u = 0; u < 4; ++u) {
      int e = i + u * 2 + slot;
      int src = col[e];
      float a = alpha1[e * 4 + h];
      float4 v = h1v[src * 32 + fq];
      acc.x += a * v.x; acc.y += a * v.y; acc.z += a * v.z; acc.w += a * v.w;
    }
  }
  for (; i + 2 <= end; i += 2) {
    int e = i + slot;
    int src = col[e];
    float a = alpha1[e * 4 + h];
    float4 v = h1v[src * 32 + fq];
    acc.x += a * v.x; acc.y += a * v.y; acc.z += a * v.z; acc.w += a * v.w;
  }
  if (i < end && slot == 0) {
    int e = i;
    int src = col[e];
    float a = alpha1[e * 4 + h];
    float4 v = h1v[src * 32 + fq];
    acc.x += a * v.x; acc.y += a * v.y; acc.z += a * v.z; acc.w += a * v.w;
  }
  // self loop (slot 1 for balance)
  if (slot == 1) {
    float w = expf(lrelu(as1[n * 4 + h] + ad1[n * 4 + h]) - m1[n * 4 + h]) * di1[n * 4 + h];
    float4 v = h1v[n * 32 + fq];
    acc.x += w * v.x; acc.y += w * v.y; acc.z += w * v.z; acc.w += w * v.w;
  }
  // combine the two slots
  acc.x += __shfl_xor(acc.x, 32);
  acc.y += __shfl_xor(acc.y, 32);
  acc.z += __shfl_xor(acc.z, 32);
  acc.w += __shfl_xor(acc.w, 32);
  if (slot == 0) {
    float4 b = b1v[fq];
    float4 o;
    o.x = elu(acc.x + b.x); o.y = elu(acc.y + b.y);
    o.z = elu(acc.z + b.z); o.w = elu(acc.w + b.w);
    h1ev[n * 32 + fq] = o;
  }
}

// ---------------- layer-2 gather + fused global add pool (4 rows/instr) ----------------
__global__ __launch_bounds__(256) void agg2_kernel(const float4* __restrict__ h2v, const float* __restrict__ alpha2a,
                                                   const int* __restrict__ rowptr, const int* __restrict__ col,
                                                   const float* __restrict__ as2, const float* __restrict__ ad2,
                                                   const float* __restrict__ m2a, const float* __restrict__ di2a,
                                                   const float4* __restrict__ b2v, float* __restrict__ pooled) {
  __shared__ float4 red[4][16];
  int n = (blockIdx.x * 256 + threadIdx.x) >> 6;
  int lane = threadIdx.x & 63;
  int wid = threadIdx.x >> 6;
  int slot = lane >> 4;  // 0..3
  int fq = lane & 15;    // feats fq*4 .. fq*4+3
  int beg = rowptr[n], end = rowptr[n + 1];

  float4 acc = make_float4(0.f, 0.f, 0.f, 0.f);
  int i = beg;
  for (; i + 16 <= end; i += 16) {
#pragma unroll
    for (int u = 0; u < 4; ++u) {
      int e = i + u * 4 + slot;
      int src = col[e];
      float a = alpha2a[e];
      float4 v = h2v[src * 16 + fq];
      acc.x += a * v.x; acc.y += a * v.y; acc.z += a * v.z; acc.w += a * v.w;
    }
  }
  for (; i + 4 <= end; i += 4) {
    int e = i + slot;
    int src = col[e];
    float a = alpha2a[e];
    float4 v = h2v[src * 16 + fq];
    acc.x += a * v.x; acc.y += a * v.y; acc.z += a * v.z; acc.w += a * v.w;
  }
  int rem = end - i;
  if (slot < rem) {
    int e = i + slot;
    int src = col[e];
    float a = alpha2a[e];
    float4 v = h2v[src * 16 + fq];
    acc.x += a * v.x; acc.y += a * v.y; acc.z += a * v.z; acc.w += a * v.w;
  }
  // self loop
  if (slot == 0) {
    float w = expf(lrelu(as2[n] + ad2[n]) - m2a[n]) * di2a[n];
    float4 v = h2v[n * 16 + fq];
    acc.x += w * v.x; acc.y += w * v.y; acc.z += w * v.z; acc.w += w * v.w;
  }
  // combine 4 slots
#pragma unroll
  for (int off = 16; off <= 32; off <<= 1) {
    acc.x += __shfl_xor(acc.x, off);
    acc.y += __shfl_xor(acc.y, off);
    acc.z += __shfl_xor(acc.z, off);
    acc.w += __shfl_xor(acc.w, off);
  }
  if (slot == 0) {
    float4 b = b2v[fq];
    float4 f;
    f.x = elu(acc.x + b.x); f.y = elu(acc.y + b.y);
    f.z = elu(acc.z + b.z); f.w = elu(acc.w + b.w);
    red[wid][fq] = f;
  }
  __syncthreads();
  if (threadIdx.x < 64) {
    const float* r = (const float*)red;
    float sum = r[threadIdx.x] + r[64 + threadIdx.x] + r[128 + threadIdx.x] + r[192 + threadIdx.x];
    atomicAdd(&pooled[(blockIdx.x & 63) * 64 + threadIdx.x], sum);
  }
}

// ---------------- final: reduce pooled stripes + pooled@Wl+bl ----------------
__global__ void final_kernel(const float* __restrict__ pooledS, const float* __restrict__ Wl,
                             const float* __restrict__ bl, float* __restrict__ out) {
  __shared__ float p[64];
  int t = threadIdx.x;
  float v = 0.f;
  for (int k = 0; k < 64; ++k) v += pooledS[k * 64 + t];
  p[t] = v;
  out[t] = v;
  __syncthreads();
  if (t < 2) {
    float s = bl[t];
    for (int k = 0; k < 64; ++k) s += p[k] * Wl[k * 2 + t];
    out[64 + t] = s;
  }
}

extern "C" void kernel_launch(void* const* d_in, const int* in_sizes, int n_in,
                              void* d_out, int out_size, void* d_ws, size_t ws_size,
                              hipStream_t stream) {
  (void)in_sizes; (void)n_in; (void)out_size; (void)ws_size;
  const float* x     = (const float*)d_in[0];
  const int*   ei    = (const int*)d_in[1];
  const float* W1    = (const float*)d_in[2];
  const float* atts1 = (const float*)d_in[3];
  const float* attd1 = (const float*)d_in[4];
  const float* b1    = (const float*)d_in[5];
  const float* W2    = (const float*)d_in[6];
  const float* atts2 = (const float*)d_in[7];
  const float* attd2 = (const float*)d_in[8];
  const float* b2    = (const float*)d_in[9];
  const float* Wl    = (const float*)d_in[10];
  const float* bl    = (const float*)d_in[11];
  float* out = (float*)d_out;

  char* w = (char*)d_ws;
  float* h1   = (float*)w; w += (size_t)N_NODES * 128 * 4;   // 25.6 MB (alias: alpha2 after agg1)
  float* h1e  = (float*)w; w += (size_t)N_NODES * 128 * 4;   // 25.6 MB
  float* h2   = (float*)w; w += (size_t)N_EDGES * 16;        // 12.8 MB (alias: alpha1 before gemm64)
  float* as1  = (float*)w; w += (size_t)N_NODES * 16;
  float* ad1  = (float*)w; w += (size_t)N_NODES * 16;
  float* m1   = (float*)w; w += (size_t)N_NODES * 16;
  float* di1  = (float*)w; w += (size_t)N_NODES * 16;
  float* as2  = (float*)w; w += (size_t)N_NODES * 4;
  float* ad2  = (float*)w; w += (size_t)N_NODES * 4;
  float* m2a  = (float*)w; w += (size_t)N_NODES * 4;
  float* di2a = (float*)w; w += (size_t)N_NODES * 4;
  int* deg    = (int*)w; w += (size_t)N_NODES * 4;
  int* cursor = (int*)w; w += (size_t)N_NODES * 4;
  float* pooled = (float*)w; w += 64 * 64 * 4;               // 64 stripes x 64
  int* rowptr = (int*)w; w += (size_t)(N_NODES + 1) * 4 + 12;
  int* col    = (int*)w; w += (size_t)N_EDGES * 4;
  int* cdst   = (int*)w; w += (size_t)N_EDGES * 4;

  float4* alpha1v = (float4*)h2;   // lifetime: after red1 .. agg1; h2 written after agg1
  float*  alpha2a = h1;            // lifetime: after red2 .. agg2; h1 dead after agg1

  // zero deg + cursor + pooled (contiguous)
  hipMemsetAsync(deg, 0, (size_t)N_NODES * 8 + 64 * 64 * 4, stream);

  hist_kernel<<<(N_EDGES + 255) / 256, 256, 0, stream>>>(ei, deg);
  scan_kernel<<<1, 256, 0, stream>>>(deg, rowptr);
  scatter_kernel<<<(N_EDGES + 255) / 256, 256, 0, stream>>>(ei, rowptr, cursor, col, cdst);

  gemm_kernel<128><<<(N_NODES + 63) / 64, 256, 0, stream>>>(x, W1, h1);
  attn1_kernel<<<N_NODES / 4, 256, 0, stream>>>(h1, atts1, attd1, as1, ad1);
  red1_kernel<<<N_NODES / 4, 256, 0, stream>>>((const float4*)as1, (const float4*)ad1, rowptr, col,
                                               (float4*)m1, (float4*)di1);
  alpha1_kernel<<<(N_EDGES + 255) / 256, 256, 0, stream>>>(col, cdst, (const float4*)as1, (const float4*)ad1,
                                                           (const float4*)m1, (const float4*)di1, alpha1v);
  agg1_kernel<<<N_NODES / 4, 256, 0, stream>>>((const float4*)h1, (const float*)alpha1v, rowptr, col,
                                               as1, ad1, m1, di1, (const float4*)b1, (float4*)h1e);

  gemm_kernel<64><<<(N_NODES + 63) / 64, 256, 0, stream>>>(h1e, W2, h2);
  attn2_kernel<<<N_NODES / 4, 256, 0, stream>>>(h2, atts2, attd2, as2, ad2);
  red2_kernel<<<N_NODES / 4, 256, 0, stream>>>(as2, ad2, rowptr, col, m2a, di2a);
  alpha2_kernel<<<(N_EDGES + 255) / 256, 256, 0, stream>>>(col, cdst, as2, ad2, m2a, di2a, alpha2a);
  agg2_kernel<<<N_NODES / 4, 256, 0, stream>>>((const float4*)h2, alpha2a, rowptr, col,
                                               as2, ad2, m2a, di2a, (const float4*)b2, pooled);

  final_kernel<<<1, 64, 0, stream>>>(pooled, Wl, bl, out);
}

// Round 4
// 460.836 us; speedup vs baseline: 1.7280x; 1.1811x over previous
//
#include <hip/hip_runtime.h>

#define N_NODES 50000
#define N_EDGES 800000

__device__ __forceinline__ float lrelu(float x) { return x > 0.f ? x : 0.2f * x; }
__device__ __forceinline__ float elu(float x) { return x > 0.f ? x : expf(x) - 1.f; }

// ---------------- CSR build ----------------
__global__ __launch_bounds__(256) void hist_kernel(const int* __restrict__ ei, int* __restrict__ deg) {
  int e = blockIdx.x * 256 + threadIdx.x;
  if (e < N_EDGES) atomicAdd(&deg[ei[N_EDGES + e]], 1);
}

__global__ __launch_bounds__(256) void scan_kernel(const int* __restrict__ deg, int* __restrict__ rowptr) {
  __shared__ int sh[256];
  int t = threadIdx.x;
  const int chunk = (N_NODES + 255) / 256;  // 196
  int lo = t * chunk;
  int hi = lo + chunk; if (hi > N_NODES) hi = N_NODES;
  int sum = 0;
  for (int i = lo; i < hi; ++i) sum += deg[i];
  sh[t] = sum;
  __syncthreads();
  int incl = sum;
  for (int off = 1; off < 256; off <<= 1) {
    int u = (t >= off) ? sh[t - off] : 0;
    __syncthreads();
    incl += u;
    sh[t] = incl;
    __syncthreads();
  }
  int run = incl - sum;  // exclusive prefix
  for (int i = lo; i < hi; ++i) { rowptr[i] = run; run += deg[i]; }
  if (t == 255) rowptr[N_NODES] = run;
}

__global__ __launch_bounds__(256) void scatter_kernel(const int* __restrict__ ei, const int* __restrict__ rowptr,
                                                      int* __restrict__ cursor, int* __restrict__ col,
                                                      int* __restrict__ cdst) {
  int e = blockIdx.x * 256 + threadIdx.x;
  if (e < N_EDGES) {
    int d = ei[N_EDGES + e];
    int pos = rowptr[d] + atomicAdd(&cursor[d], 1);
    col[pos] = ei[e];
    cdst[pos] = d;
  }
}

// ---------------- GEMM: Y[N,COLS] = A[N,128] @ W[128,COLS] ----------------
template <int COLS>
__global__ __launch_bounds__(256) void gemm_kernel(const float* __restrict__ A, const float* __restrict__ W,
                                                   float* __restrict__ Y) {
  constexpr int CPT = COLS / 16;  // cols per thread (8 or 4)
  __shared__ float ws[64 * COLS];
  __shared__ float xs[64 * 64];
  int t = threadIdx.x;
  int rbase = blockIdx.x * 64;
  int tx = t & 15, ty = t >> 4;
  float acc[4][CPT];
#pragma unroll
  for (int r = 0; r < 4; ++r)
#pragma unroll
    for (int c = 0; c < CPT; ++c) acc[r][c] = 0.f;

  const float4* A4 = (const float4*)A;
  const float4* W4 = (const float4*)W;
  for (int kt = 0; kt < 2; ++kt) {
    float4* ws4 = (float4*)ws;
    for (int i = t; i < 64 * COLS / 4; i += 256) ws4[i] = W4[kt * 16 * COLS + i];
    float4* xs4 = (float4*)xs;
    for (int i = t; i < 64 * 64 / 4; i += 256) {
      int row = i >> 4, kc = i & 15;
      int gr = rbase + row; if (gr >= N_NODES) gr = N_NODES - 1;
      xs4[i] = A4[gr * 32 + kt * 16 + kc];
    }
    __syncthreads();
#pragma unroll 8
    for (int k = 0; k < 64; ++k) {
      float xr[4];
#pragma unroll
      for (int r = 0; r < 4; ++r) xr[r] = xs[(ty * 4 + r) * 64 + k];
#pragma unroll
      for (int c4 = 0; c4 < CPT / 4; ++c4) {
        float4 wv = *(const float4*)&ws[k * COLS + tx * CPT + c4 * 4];
#pragma unroll
        for (int r = 0; r < 4; ++r) {
          acc[r][c4 * 4 + 0] += xr[r] * wv.x;
          acc[r][c4 * 4 + 1] += xr[r] * wv.y;
          acc[r][c4 * 4 + 2] += xr[r] * wv.z;
          acc[r][c4 * 4 + 3] += xr[r] * wv.w;
        }
      }
    }
    __syncthreads();
  }
#pragma unroll
  for (int r = 0; r < 4; ++r) {
    int row = rbase + ty * 4 + r;
    if (row < N_NODES) {
#pragma unroll
      for (int c4 = 0; c4 < CPT / 4; ++c4) {
        float4 v = make_float4(acc[r][c4 * 4], acc[r][c4 * 4 + 1], acc[r][c4 * 4 + 2], acc[r][c4 * 4 + 3]);
        *(float4*)&Y[row * COLS + tx * CPT + c4 * 4] = v;
      }
    }
  }
}

// ---------------- attention dot products ----------------
__global__ __launch_bounds__(256) void attn1_kernel(const float* __restrict__ h1, const float* __restrict__ atts,
                                                    const float* __restrict__ attd, float* __restrict__ as1,
                                                    float* __restrict__ ad1) {
  int n = (blockIdx.x * 256 + threadIdx.x) >> 6;
  int lane = threadIdx.x & 63;
  float v0 = h1[n * 128 + lane];
  float v1 = h1[n * 128 + 64 + lane];
  float s0 = v0 * atts[lane], s1 = v1 * atts[64 + lane];
  float d0 = v0 * attd[lane], d1 = v1 * attd[64 + lane];
#pragma unroll
  for (int off = 16; off >= 1; off >>= 1) {
    s0 += __shfl_xor(s0, off); s1 += __shfl_xor(s1, off);
    d0 += __shfl_xor(d0, off); d1 += __shfl_xor(d1, off);
  }
  if (lane == 0) {
    as1[n * 4 + 0] = s0; as1[n * 4 + 2] = s1;
    ad1[n * 4 + 0] = d0; ad1[n * 4 + 2] = d1;
  } else if (lane == 32) {
    as1[n * 4 + 1] = s0; as1[n * 4 + 3] = s1;
    ad1[n * 4 + 1] = d0; ad1[n * 4 + 3] = d1;
  }
}

__global__ __launch_bounds__(256) void attn2_kernel(const float* __restrict__ h2, const float* __restrict__ atts,
                                                    const float* __restrict__ attd, float* __restrict__ as2,
                                                    float* __restrict__ ad2) {
  int n = (blockIdx.x * 256 + threadIdx.x) >> 6;
  int lane = threadIdx.x & 63;
  float v = h2[n * 64 + lane];
  float s = v * atts[lane];
  float d = v * attd[lane];
#pragma unroll
  for (int off = 32; off >= 1; off >>= 1) {
    s += __shfl_xor(s, off);
    d += __shfl_xor(d, off);
  }
  if (lane == 0) { as2[n] = s; ad2[n] = d; }
}

// ---------------- edge-parallel unnormalized weights e = exp(lrelu(as+ad)) ----------------
__global__ __launch_bounds__(256) void ealpha1_kernel(const int* __restrict__ col, const int* __restrict__ cdst,
                                                      const float4* __restrict__ as1v, const float4* __restrict__ ad1v,
                                                      float4* __restrict__ e1v) {
  int p = blockIdx.x * 256 + threadIdx.x;
  if (p >= N_EDGES) return;
  int s = col[p], d = cdst[p];
  float4 a = as1v[s], b = ad1v[d];
  float4 o;
  o.x = expf(lrelu(a.x + b.x));
  o.y = expf(lrelu(a.y + b.y));
  o.z = expf(lrelu(a.z + b.z));
  o.w = expf(lrelu(a.w + b.w));
  e1v[p] = o;
}

__global__ __launch_bounds__(256) void ealpha2_kernel(const int* __restrict__ col, const int* __restrict__ cdst,
                                                      const float* __restrict__ as2, const float* __restrict__ ad2,
                                                      float* __restrict__ e2a) {
  int p = blockIdx.x * 256 + threadIdx.x;
  if (p >= N_EDGES) return;
  e2a[p] = expf(lrelu(as2[col[p]] + ad2[cdst[p]]));
}

// ---------------- per-node denom: contiguous sum of e + self term; 16 lanes/node ----------------
__global__ __launch_bounds__(256) void red1_kernel(const float4* __restrict__ e1v, const int* __restrict__ rowptr,
                                                   const float4* __restrict__ as1v, const float4* __restrict__ ad1v,
                                                   float4* __restrict__ di1v, float4* __restrict__ es1v) {
  int n = blockIdx.x * 16 + (threadIdx.x >> 4);
  int sub = threadIdx.x & 15;
  int beg = rowptr[n], end = rowptr[n + 1];
  float4 s = make_float4(0.f, 0.f, 0.f, 0.f);
  for (int i = beg + sub; i < end; i += 16) {
    float4 v = e1v[i];
    s.x += v.x; s.y += v.y; s.z += v.z; s.w += v.w;
  }
#pragma unroll
  for (int off = 1; off < 16; off <<= 1) {
    s.x += __shfl_xor(s.x, off);
    s.y += __shfl_xor(s.y, off);
    s.z += __shfl_xor(s.z, off);
    s.w += __shfl_xor(s.w, off);
  }
  if (sub == 0) {
    float4 a = as1v[n], b = ad1v[n];
    float4 es;
    es.x = expf(lrelu(a.x + b.x));
    es.y = expf(lrelu(a.y + b.y));
    es.z = expf(lrelu(a.z + b.z));
    es.w = expf(lrelu(a.w + b.w));
    es1v[n] = es;
    di1v[n] = make_float4(1.f / (s.x + es.x), 1.f / (s.y + es.y), 1.f / (s.z + es.z), 1.f / (s.w + es.w));
  }
}

__global__ __launch_bounds__(256) void red2_kernel(const float* __restrict__ e2a, const int* __restrict__ rowptr,
                                                   const float* __restrict__ as2, const float* __restrict__ ad2,
                                                   float* __restrict__ di2a, float* __restrict__ es2a) {
  int n = blockIdx.x * 16 + (threadIdx.x >> 4);
  int sub = threadIdx.x & 15;
  int beg = rowptr[n], end = rowptr[n + 1];
  float s = 0.f;
  for (int i = beg + sub; i < end; i += 16) s += e2a[i];
#pragma unroll
  for (int off = 1; off < 16; off <<= 1) s += __shfl_xor(s, off);
  if (sub == 0) {
    float es = expf(lrelu(as2[n] + ad2[n]));
    es2a[n] = es;
    di2a[n] = 1.f / (s + es);
  }
}

// ---------------- layer-1 gather: one wave per node, float4 lanes (2 rows/instr) ----------------
__global__ __launch_bounds__(256) void agg1_kernel(const float4* __restrict__ h1v, const float* __restrict__ e1,
                                                   const int* __restrict__ rowptr, const int* __restrict__ col,
                                                   const float* __restrict__ di1, const float* __restrict__ es1,
                                                   const float4* __restrict__ b1v, float4* __restrict__ h1ev) {
  int n = (blockIdx.x * 256 + threadIdx.x) >> 6;
  int lane = threadIdx.x & 63;
  int slot = lane >> 5;  // 0..1: which edge within a pair
  int fq = lane & 31;    // feature quarter: feats fq*4 .. fq*4+3
  int h = fq >> 3;       // head index for these 4 feats
  int beg = rowptr[n], end = rowptr[n + 1];

  float4 acc = make_float4(0.f, 0.f, 0.f, 0.f);
  int i = beg;
  for (; i + 8 <= end; i += 8) {
#pragma unroll
    for (int u = 0; u < 4; ++u) {
      int e = i + u * 2 + slot;
      int src = col[e];
      float a = e1[e * 4 + h];
      float4 v = h1v[src * 32 + fq];
      acc.x += a * v.x; acc.y += a * v.y; acc.z += a * v.z; acc.w += a * v.w;
    }
  }
  for (; i + 2 <= end; i += 2) {
    int e = i + slot;
    int src = col[e];
    float a = e1[e * 4 + h];
    float4 v = h1v[src * 32 + fq];
    acc.x += a * v.x; acc.y += a * v.y; acc.z += a * v.z; acc.w += a * v.w;
  }
  if (i < end && slot == 0) {
    int e = i;
    int src = col[e];
    float a = e1[e * 4 + h];
    float4 v = h1v[src * 32 + fq];
    acc.x += a * v.x; acc.y += a * v.y; acc.z += a * v.z; acc.w += a * v.w;
  }
  // self loop (slot 1 for balance)
  if (slot == 1) {
    float w = es1[n * 4 + h];
    float4 v = h1v[n * 32 + fq];
    acc.x += w * v.x; acc.y += w * v.y; acc.z += w * v.z; acc.w += w * v.w;
  }
  // combine the two slots
  acc.x += __shfl_xor(acc.x, 32);
  acc.y += __shfl_xor(acc.y, 32);
  acc.z += __shfl_xor(acc.z, 32);
  acc.w += __shfl_xor(acc.w, 32);
  if (slot == 0) {
    float d = di1[n * 4 + h];
    float4 b = b1v[fq];
    float4 o;
    o.x = elu(acc.x * d + b.x); o.y = elu(acc.y * d + b.y);
    o.z = elu(acc.z * d + b.z); o.w = elu(acc.w * d + b.w);
    h1ev[n * 32 + fq] = o;
  }
}

// ---------------- layer-2 gather + fused global add pool (4 rows/instr) ----------------
__global__ __launch_bounds__(256) void agg2_kernel(const float4* __restrict__ h2v, const float* __restrict__ e2a,
                                                   const int* __restrict__ rowptr, const int* __restrict__ col,
                                                   const float* __restrict__ di2a, const float* __restrict__ es2a,
                                                   const float4* __restrict__ b2v, float* __restrict__ pooled) {
  __shared__ float4 red[4][16];
  int n = (blockIdx.x * 256 + threadIdx.x) >> 6;
  int lane = threadIdx.x & 63;
  int wid = threadIdx.x >> 6;
  int slot = lane >> 4;  // 0..3
  int fq = lane & 15;    // feats fq*4 .. fq*4+3
  int beg = rowptr[n], end = rowptr[n + 1];

  float4 acc = make_float4(0.f, 0.f, 0.f, 0.f);
  int i = beg;
  for (; i + 16 <= end; i += 16) {
#pragma unroll
    for (int u = 0; u < 4; ++u) {
      int e = i + u * 4 + slot;
      int src = col[e];
      float a = e2a[e];
      float4 v = h2v[src * 16 + fq];
      acc.x += a * v.x; acc.y += a * v.y; acc.z += a * v.z; acc.w += a * v.w;
    }
  }
  for (; i + 4 <= end; i += 4) {
    int e = i + slot;
    int src = col[e];
    float a = e2a[e];
    float4 v = h2v[src * 16 + fq];
    acc.x += a * v.x; acc.y += a * v.y; acc.z += a * v.z; acc.w += a * v.w;
  }
  int rem = end - i;
  if (slot < rem) {
    int e = i + slot;
    int src = col[e];
    float a = e2a[e];
    float4 v = h2v[src * 16 + fq];
    acc.x += a * v.x; acc.y += a * v.y; acc.z += a * v.z; acc.w += a * v.w;
  }
  // self loop
  if (slot == 0) {
    float w = es2a[n];
    float4 v = h2v[n * 16 + fq];
    acc.x += w * v.x; acc.y += w * v.y; acc.z += w * v.z; acc.w += w * v.w;
  }
  // combine 4 slots
#pragma unroll
  for (int off = 16; off <= 32; off <<= 1) {
    acc.x += __shfl_xor(acc.x, off);
    acc.y += __shfl_xor(acc.y, off);
    acc.z += __shfl_xor(acc.z, off);
    acc.w += __shfl_xor(acc.w, off);
  }
  if (slot == 0) {
    float d = di2a[n];
    float4 b = b2v[fq];
    float4 f;
    f.x = elu(acc.x * d + b.x); f.y = elu(acc.y * d + b.y);
    f.z = elu(acc.z * d + b.z); f.w = elu(acc.w * d + b.w);
    red[wid][fq] = f;
  }
  __syncthreads();
  if (threadIdx.x < 64) {
    const float* r = (const float*)red;
    float sum = r[threadIdx.x] + r[64 + threadIdx.x] + r[128 + threadIdx.x] + r[192 + threadIdx.x];
    atomicAdd(&pooled[(blockIdx.x & 63) * 64 + threadIdx.x], sum);
  }
}

// ---------------- final: reduce pooled stripes + pooled@Wl+bl ----------------
__global__ void final_kernel(const float* __restrict__ pooledS, const float* __restrict__ Wl,
                             const float* __restrict__ bl, float* __restrict__ out) {
  __shared__ float p[64];
  int t = threadIdx.x;
  float v = 0.f;
  for (int k = 0; k < 64; ++k) v += pooledS[k * 64 + t];
  p[t] = v;
  out[t] = v;
  __syncthreads();
  if (t < 2) {
    float s = bl[t];
    for (int k = 0; k < 64; ++k) s += p[k] * Wl[k * 2 + t];
    out[64 + t] = s;
  }
}

extern "C" void kernel_launch(void* const* d_in, const int* in_sizes, int n_in,
                              void* d_out, int out_size, void* d_ws, size_t ws_size,
                              hipStream_t stream) {
  (void)in_sizes; (void)n_in; (void)out_size; (void)ws_size;
  const float* x     = (const float*)d_in[0];
  const int*   ei    = (const int*)d_in[1];
  const float* W1    = (const float*)d_in[2];
  const float* atts1 = (const float*)d_in[3];
  const float* attd1 = (const float*)d_in[4];
  const float* b1    = (const float*)d_in[5];
  const float* W2    = (const float*)d_in[6];
  const float* atts2 = (const float*)d_in[7];
  const float* attd2 = (const float*)d_in[8];
  const float* b2    = (const float*)d_in[9];
  const float* Wl    = (const float*)d_in[10];
  const float* bl    = (const float*)d_in[11];
  float* out = (float*)d_out;

  char* w = (char*)d_ws;
  float* h1   = (float*)w; w += (size_t)N_NODES * 128 * 4;   // 25.6 MB (alias: e2 after agg1)
  float* h1e  = (float*)w; w += (size_t)N_NODES * 128 * 4;   // 25.6 MB
  float* h2   = (float*)w; w += (size_t)N_EDGES * 16;        // 12.8 MB (alias: e1 before gemm64)
  float* as1  = (float*)w; w += (size_t)N_NODES * 16;
  float* ad1  = (float*)w; w += (size_t)N_NODES * 16;
  float* di1  = (float*)w; w += (size_t)N_NODES * 16;
  float* es1  = (float*)w; w += (size_t)N_NODES * 16;
  float* as2  = (float*)w; w += (size_t)N_NODES * 4;
  float* ad2  = (float*)w; w += (size_t)N_NODES * 4;
  float* di2a = (float*)w; w += (size_t)N_NODES * 4;
  float* es2a = (float*)w; w += (size_t)N_NODES * 4;
  int* deg    = (int*)w; w += (size_t)N_NODES * 4;
  int* cursor = (int*)w; w += (size_t)N_NODES * 4;
  float* pooled = (float*)w; w += 64 * 64 * 4;               // 64 stripes x 64
  int* rowptr = (int*)w; w += (size_t)(N_NODES + 1) * 4 + 12;
  int* col    = (int*)w; w += (size_t)N_EDGES * 4;
  int* cdst   = (int*)w; w += (size_t)N_EDGES * 4;

  float4* e1v = (float4*)h2;   // lifetime: after ealpha1 .. agg1; h2 written after agg1
  float*  e2a = h1;            // lifetime: after ealpha2 .. agg2; h1 dead after agg1

  // zero deg + cursor + pooled (contiguous)
  hipMemsetAsync(deg, 0, (size_t)N_NODES * 8 + 64 * 64 * 4, stream);

  hist_kernel<<<(N_EDGES + 255) / 256, 256, 0, stream>>>(ei, deg);
  scan_kernel<<<1, 256, 0, stream>>>(deg, rowptr);
  scatter_kernel<<<(N_EDGES + 255) / 256, 256, 0, stream>>>(ei, rowptr, cursor, col, cdst);

  gemm_kernel<128><<<(N_NODES + 63) / 64, 256, 0, stream>>>(x, W1, h1);
  attn1_kernel<<<N_NODES / 4, 256, 0, stream>>>(h1, atts1, attd1, as1, ad1);
  ealpha1_kernel<<<(N_EDGES + 255) / 256, 256, 0, stream>>>(col, cdst, (const float4*)as1, (const float4*)ad1, e1v);
  red1_kernel<<<(N_NODES + 15) / 16, 256, 0, stream>>>(e1v, rowptr, (const float4*)as1, (const float4*)ad1,
                                                       (float4*)di1, (float4*)es1);
  agg1_kernel<<<N_NODES / 4, 256, 0, stream>>>((const float4*)h1, (const float*)e1v, rowptr, col,
                                               di1, es1, (const float4*)b1, (float4*)h1e);

  gemm_kernel<64><<<(N_NODES + 63) / 64, 256, 0, stream>>>(h1e, W2, h2);
  attn2_kernel<<<N_NODES / 4, 256, 0, stream>>>(h2, atts2, attd2, as2, ad2);
  ealpha2_kernel<<<(N_EDGES + 255) / 256, 256, 0, stream>>>(col, cdst, as2, ad2, e2a);
  red2_kernel<<<(N_NODES + 15) / 16, 256, 0, stream>>>(e2a, rowptr, as2, ad2, di2a, es2a);
  agg2_kernel<<<N_NODES / 4, 256, 0, stream>>>((const float4*)h2, e2a, rowptr, col,
                                               di2a, es2a, (const float4*)b2, pooled);

  final_kernel<<<1, 64, 0, stream>>>(pooled, Wl, bl, out);
}

// Round 5
// 391.712 us; speedup vs baseline: 2.0329x; 1.1765x over previous
//
#include <hip/hip_runtime.h>

#define N_NODES 50000
#define N_EDGES 800000
#define SCAN_BLOCKS ((N_NODES + 255) / 256)  // 196

__device__ __forceinline__ float lrelu(float x) { return x > 0.f ? x : 0.2f * x; }
__device__ __forceinline__ float elu(float x) { return x > 0.f ? x : expf(x) - 1.f; }

// ---------------- CSR build ----------------
__global__ __launch_bounds__(256) void hist_kernel(const int* __restrict__ ei, int* __restrict__ deg) {
  int e = blockIdx.x * 256 + threadIdx.x;
  if (e < N_EDGES) atomicAdd(&deg[ei[N_EDGES + e]], 1);
}

__device__ __forceinline__ int block_excl_scan(int v, int* total_out) {
  int lane = threadIdx.x & 63;
  int wid = threadIdx.x >> 6;
  int x = v;
#pragma unroll
  for (int off = 1; off < 64; off <<= 1) {
    int u = __shfl_up(x, off);
    if (lane >= off) x += u;
  }
  __shared__ int wsum[4];
  if (lane == 63) wsum[wid] = x;
  __syncthreads();
  int add = 0;
#pragma unroll
  for (int k = 0; k < 4; ++k)
    if (k < wid) add += wsum[k];
  if (total_out) *total_out = wsum[0] + wsum[1] + wsum[2] + wsum[3];
  return x + add - v;
}

// phase 1: block-local exclusive scan into rowptr, block totals into blocksum
__global__ __launch_bounds__(256) void scan_part_kernel(const int* __restrict__ deg, int* __restrict__ rowptr,
                                                        int* __restrict__ blocksum) {
  int g = blockIdx.x * 256 + threadIdx.x;
  int v = (g < N_NODES) ? deg[g] : 0;
  int total;
  int ex = block_excl_scan(v, &total);
  if (g < N_NODES) rowptr[g] = ex;
  if (threadIdx.x == 0) blocksum[blockIdx.x] = total;
}

// phase 2: exclusive scan of the block sums (SCAN_BLOCKS <= 256)
__global__ __launch_bounds__(256) void scan_top_kernel(const int* __restrict__ blocksum, int* __restrict__ blockoff) {
  int t = threadIdx.x;
  int v = (t < SCAN_BLOCKS) ? blocksum[t] : 0;
  int ex = block_excl_scan(v, nullptr);
  if (t < SCAN_BLOCKS) blockoff[t] = ex;
}

// phase 3: add block offsets
__global__ __launch_bounds__(256) void scan_add_kernel(const int* __restrict__ blockoff, int* __restrict__ rowptr) {
  int g = blockIdx.x * 256 + threadIdx.x;
  if (g < N_NODES) rowptr[g] += blockoff[g >> 8];
  if (g == 0) rowptr[N_NODES] = N_EDGES;
}

__global__ __launch_bounds__(256) void scatter_kernel(const int* __restrict__ ei, const int* __restrict__ rowptr,
                                                      int* __restrict__ cursor, int* __restrict__ col,
                                                      int* __restrict__ cdst) {
  int e = blockIdx.x * 256 + threadIdx.x;
  if (e < N_EDGES) {
    int d = ei[N_EDGES + e];
    int pos = rowptr[d] + atomicAdd(&cursor[d], 1);
    col[pos] = ei[e];
    cdst[pos] = d;
  }
}

// ---------------- GEMM: Y[N,COLS] = A[N,128] @ W[128,COLS] ----------------
template <int COLS>
__global__ __launch_bounds__(256) void gemm_kernel(const float* __restrict__ A, const float* __restrict__ W,
                                                   float* __restrict__ Y) {
  constexpr int CPT = COLS / 16;  // cols per thread (8 or 4)
  __shared__ float ws[64 * COLS];
  __shared__ float xs[64 * 64];
  int t = threadIdx.x;
  int rbase = blockIdx.x * 64;
  int tx = t & 15, ty = t >> 4;
  float acc[4][CPT];
#pragma unroll
  for (int r = 0; r < 4; ++r)
#pragma unroll
    for (int c = 0; c < CPT; ++c) acc[r][c] = 0.f;

  const float4* A4 = (const float4*)A;
  const float4* W4 = (const float4*)W;
  for (int kt = 0; kt < 2; ++kt) {
    float4* ws4 = (float4*)ws;
    for (int i = t; i < 64 * COLS / 4; i += 256) ws4[i] = W4[kt * 16 * COLS + i];
    float4* xs4 = (float4*)xs;
    for (int i = t; i < 64 * 64 / 4; i += 256) {
      int row = i >> 4, kc = i & 15;
      int gr = rbase + row; if (gr >= N_NODES) gr = N_NODES - 1;
      xs4[i] = A4[gr * 32 + kt * 16 + kc];
    }
    __syncthreads();
#pragma unroll 8
    for (int k = 0; k < 64; ++k) {
      float xr[4];
#pragma unroll
      for (int r = 0; r < 4; ++r) xr[r] = xs[(ty * 4 + r) * 64 + k];
#pragma unroll
      for (int c4 = 0; c4 < CPT / 4; ++c4) {
        float4 wv = *(const float4*)&ws[k * COLS + tx * CPT + c4 * 4];
#pragma unroll
        for (int r = 0; r < 4; ++r) {
          acc[r][c4 * 4 + 0] += xr[r] * wv.x;
          acc[r][c4 * 4 + 1] += xr[r] * wv.y;
          acc[r][c4 * 4 + 2] += xr[r] * wv.z;
          acc[r][c4 * 4 + 3] += xr[r] * wv.w;
        }
      }
    }
    __syncthreads();
  }
#pragma unroll
  for (int r = 0; r < 4; ++r) {
    int row = rbase + ty * 4 + r;
    if (row < N_NODES) {
#pragma unroll
      for (int c4 = 0; c4 < CPT / 4; ++c4) {
        float4 v = make_float4(acc[r][c4 * 4], acc[r][c4 * 4 + 1], acc[r][c4 * 4 + 2], acc[r][c4 * 4 + 3]);
        *(float4*)&Y[row * COLS + tx * CPT + c4 * 4] = v;
      }
    }
  }
}

// ---------------- attention dot products ----------------
__global__ __launch_bounds__(256) void attn1_kernel(const float* __restrict__ h1, const float* __restrict__ atts,
                                                    const float* __restrict__ attd, float* __restrict__ as1,
                                                    float* __restrict__ ad1) {
  int n = (blockIdx.x * 256 + threadIdx.x) >> 6;
  int lane = threadIdx.x & 63;
  float v0 = h1[n * 128 + lane];
  float v1 = h1[n * 128 + 64 + lane];
  float s0 = v0 * atts[lane], s1 = v1 * atts[64 + lane];
  float d0 = v0 * attd[lane], d1 = v1 * attd[64 + lane];
#pragma unroll
  for (int off = 16; off >= 1; off >>= 1) {
    s0 += __shfl_xor(s0, off); s1 += __shfl_xor(s1, off);
    d0 += __shfl_xor(d0, off); d1 += __shfl_xor(d1, off);
  }
  if (lane == 0) {
    as1[n * 4 + 0] = s0; as1[n * 4 + 2] = s1;
    ad1[n * 4 + 0] = d0; ad1[n * 4 + 2] = d1;
  } else if (lane == 32) {
    as1[n * 4 + 1] = s0; as1[n * 4 + 3] = s1;
    ad1[n * 4 + 1] = d0; ad1[n * 4 + 3] = d1;
  }
}

__global__ __launch_bounds__(256) void attn2_kernel(const float* __restrict__ h2, const float* __restrict__ atts,
                                                    const float* __restrict__ attd, float* __restrict__ as2,
                                                    float* __restrict__ ad2) {
  int n = (blockIdx.x * 256 + threadIdx.x) >> 6;
  int lane = threadIdx.x & 63;
  float v = h2[n * 64 + lane];
  float s = v * atts[lane];
  float d = v * attd[lane];
#pragma unroll
  for (int off = 32; off >= 1; off >>= 1) {
    s += __shfl_xor(s, off);
    d += __shfl_xor(d, off);
  }
  if (lane == 0) { as2[n] = s; ad2[n] = d; }
}

// ---------------- edge-parallel unnormalized weights e = exp(lrelu(as+ad)) ----------------
__global__ __launch_bounds__(256) void ealpha1_kernel(const int* __restrict__ col, const int* __restrict__ cdst,
                                                      const float4* __restrict__ as1v, const float4* __restrict__ ad1v,
                                                      float4* __restrict__ e1v) {
  int p = blockIdx.x * 256 + threadIdx.x;
  if (p >= N_EDGES) return;
  int s = col[p], d = cdst[p];
  float4 a = as1v[s], b = ad1v[d];
  float4 o;
  o.x = expf(lrelu(a.x + b.x));
  o.y = expf(lrelu(a.y + b.y));
  o.z = expf(lrelu(a.z + b.z));
  o.w = expf(lrelu(a.w + b.w));
  e1v[p] = o;
}

__global__ __launch_bounds__(256) void ealpha2_kernel(const int* __restrict__ col, const int* __restrict__ cdst,
                                                      const float* __restrict__ as2, const float* __restrict__ ad2,
                                                      float* __restrict__ e2a) {
  int p = blockIdx.x * 256 + threadIdx.x;
  if (p >= N_EDGES) return;
  e2a[p] = expf(lrelu(as2[col[p]] + ad2[cdst[p]]));
}

// ---------------- per-node denom: contiguous sum of e + self term; 16 lanes/node ----------------
__global__ __launch_bounds__(256) void red1_kernel(const float4* __restrict__ e1v, const int* __restrict__ rowptr,
                                                   const float4* __restrict__ as1v, const float4* __restrict__ ad1v,
                                                   float4* __restrict__ di1v, float4* __restrict__ es1v) {
  int n = blockIdx.x * 16 + (threadIdx.x >> 4);
  int sub = threadIdx.x & 15;
  int beg = rowptr[n], end = rowptr[n + 1];
  float4 s = make_float4(0.f, 0.f, 0.f, 0.f);
  for (int i = beg + sub; i < end; i += 16) {
    float4 v = e1v[i];
    s.x += v.x; s.y += v.y; s.z += v.z; s.w += v.w;
  }
#pragma unroll
  for (int off = 1; off < 16; off <<= 1) {
    s.x += __shfl_xor(s.x, off);
    s.y += __shfl_xor(s.y, off);
    s.z += __shfl_xor(s.z, off);
    s.w += __shfl_xor(s.w, off);
  }
  if (sub == 0) {
    float4 a = as1v[n], b = ad1v[n];
    float4 es;
    es.x = expf(lrelu(a.x + b.x));
    es.y = expf(lrelu(a.y + b.y));
    es.z = expf(lrelu(a.z + b.z));
    es.w = expf(lrelu(a.w + b.w));
    es1v[n] = es;
    di1v[n] = make_float4(1.f / (s.x + es.x), 1.f / (s.y + es.y), 1.f / (s.z + es.z), 1.f / (s.w + es.w));
  }
}

__global__ __launch_bounds__(256) void red2_kernel(const float* __restrict__ e2a, const int* __restrict__ rowptr,
                                                   const float* __restrict__ as2, const float* __restrict__ ad2,
                                                   float* __restrict__ di2a, float* __restrict__ es2a) {
  int n = blockIdx.x * 16 + (threadIdx.x >> 4);
  int sub = threadIdx.x & 15;
  int beg = rowptr[n], end = rowptr[n + 1];
  float s = 0.f;
  for (int i = beg + sub; i < end; i += 16) s += e2a[i];
#pragma unroll
  for (int off = 1; off < 16; off <<= 1) s += __shfl_xor(s, off);
  if (sub == 0) {
    float es = expf(lrelu(as2[n] + ad2[n]));
    es2a[n] = es;
    di2a[n] = 1.f / (s + es);
  }
}

// ---------------- layer-1 gather: one wave per node, float4 lanes (2 rows/instr) ----------------
__global__ __launch_bounds__(256) void agg1_kernel(const float4* __restrict__ h1v, const float* __restrict__ e1,
                                                   const int* __restrict__ rowptr, const int* __restrict__ col,
                                                   const float* __restrict__ di1, const float* __restrict__ es1,
                                                   const float4* __restrict__ b1v, float4* __restrict__ h1ev) {
  int n = (blockIdx.x * 256 + threadIdx.x) >> 6;
  int lane = threadIdx.x & 63;
  int slot = lane >> 5;  // 0..1: which edge within a pair
  int fq = lane & 31;    // feature quarter: feats fq*4 .. fq*4+3
  int h = fq >> 3;       // head index for these 4 feats
  int beg = rowptr[n], end = rowptr[n + 1];

  float4 acc = make_float4(0.f, 0.f, 0.f, 0.f);
  int i = beg;
  for (; i + 8 <= end; i += 8) {
#pragma unroll
    for (int u = 0; u < 4; ++u) {
      int e = i + u * 2 + slot;
      int src = col[e];
      float a = e1[e * 4 + h];
      float4 v = h1v[src * 32 + fq];
      acc.x += a * v.x; acc.y += a * v.y; acc.z += a * v.z; acc.w += a * v.w;
    }
  }
  for (; i + 2 <= end; i += 2) {
    int e = i + slot;
    int src = col[e];
    float a = e1[e * 4 + h];
    float4 v = h1v[src * 32 + fq];
    acc.x += a * v.x; acc.y += a * v.y; acc.z += a * v.z; acc.w += a * v.w;
  }
  if (i < end && slot == 0) {
    int e = i;
    int src = col[e];
    float a = e1[e * 4 + h];
    float4 v = h1v[src * 32 + fq];
    acc.x += a * v.x; acc.y += a * v.y; acc.z += a * v.z; acc.w += a * v.w;
  }
  // self loop (slot 1 for balance)
  if (slot == 1) {
    float w = es1[n * 4 + h];
    float4 v = h1v[n * 32 + fq];
    acc.x += w * v.x; acc.y += w * v.y; acc.z += w * v.z; acc.w += w * v.w;
  }
  // combine the two slots
  acc.x += __shfl_xor(acc.x, 32);
  acc.y += __shfl_xor(acc.y, 32);
  acc.z += __shfl_xor(acc.z, 32);
  acc.w += __shfl_xor(acc.w, 32);
  if (slot == 0) {
    float d = di1[n * 4 + h];
    float4 b = b1v[fq];
    float4 o;
    o.x = elu(acc.x * d + b.x); o.y = elu(acc.y * d + b.y);
    o.z = elu(acc.z * d + b.z); o.w = elu(acc.w * d + b.w);
    h1ev[n * 32 + fq] = o;
  }
}

// ---------------- layer-2 gather + fused global add pool (4 rows/instr) ----------------
__global__ __launch_bounds__(256) void agg2_kernel(const float4* __restrict__ h2v, const float* __restrict__ e2a,
                                                   const int* __restrict__ rowptr, const int* __restrict__ col,
                                                   const float* __restrict__ di2a, const float* __restrict__ es2a,
                                                   const float4* __restrict__ b2v, float* __restrict__ pooled) {
  __shared__ float4 red[4][16];
  int n = (blockIdx.x * 256 + threadIdx.x) >> 6;
  int lane = threadIdx.x & 63;
  int wid = threadIdx.x >> 6;
  int slot = lane >> 4;  // 0..3
  int fq = lane & 15;    // feats fq*4 .. fq*4+3
  int beg = rowptr[n], end = rowptr[n + 1];

  float4 acc = make_float4(0.f, 0.f, 0.f, 0.f);
  int i = beg;
  for (; i + 16 <= end; i += 16) {
#pragma unroll
    for (int u = 0; u < 4; ++u) {
      int e = i + u * 4 + slot;
      int src = col[e];
      float a = e2a[e];
      float4 v = h2v[src * 16 + fq];
      acc.x += a * v.x; acc.y += a * v.y; acc.z += a * v.z; acc.w += a * v.w;
    }
  }
  for (; i + 4 <= end; i += 4) {
    int e = i + slot;
    int src = col[e];
    float a = e2a[e];
    float4 v = h2v[src * 16 + fq];
    acc.x += a * v.x; acc.y += a * v.y; acc.z += a * v.z; acc.w += a * v.w;
  }
  int rem = end - i;
  if (slot < rem) {
    int e = i + slot;
    int src = col[e];
    float a = e2a[e];
    float4 v = h2v[src * 16 + fq];
    acc.x += a * v.x; acc.y += a * v.y; acc.z += a * v.z; acc.w += a * v.w;
  }
  // self loop
  if (slot == 0) {
    float w = es2a[n];
    float4 v = h2v[n * 16 + fq];
    acc.x += w * v.x; acc.y += w * v.y; acc.z += w * v.z; acc.w += w * v.w;
  }
  // combine 4 slots
#pragma unroll
  for (int off = 16; off <= 32; off <<= 1) {
    acc.x += __shfl_xor(acc.x, off);
    acc.y += __shfl_xor(acc.y, off);
    acc.z += __shfl_xor(acc.z, off);
    acc.w += __shfl_xor(acc.w, off);
  }
  if (slot == 0) {
    float d = di2a[n];
    float4 b = b2v[fq];
    float4 f;
    f.x = elu(acc.x * d + b.x); f.y = elu(acc.y * d + b.y);
    f.z = elu(acc.z * d + b.z); f.w = elu(acc.w * d + b.w);
    red[wid][fq] = f;
  }
  __syncthreads();
  if (threadIdx.x < 64) {
    const float* r = (const float*)red;
    float sum = r[threadIdx.x] + r[64 + threadIdx.x] + r[128 + threadIdx.x] + r[192 + threadIdx.x];
    atomicAdd(&pooled[(blockIdx.x & 63) * 64 + threadIdx.x], sum);
  }
}

// ---------------- final: reduce pooled stripes + pooled@Wl+bl ----------------
__global__ void final_kernel(const float* __restrict__ pooledS, const float* __restrict__ Wl,
                             const float* __restrict__ bl, float* __restrict__ out) {
  __shared__ float p[64];
  int t = threadIdx.x;
  float v = 0.f;
  for (int k = 0; k < 64; ++k) v += pooledS[k * 64 + t];
  p[t] = v;
  out[t] = v;
  __syncthreads();
  if (t < 2) {
    float s = bl[t];
    for (int k = 0; k < 64; ++k) s += p[k] * Wl[k * 2 + t];
    out[64 + t] = s;
  }
}

extern "C" void kernel_launch(void* const* d_in, const int* in_sizes, int n_in,
                              void* d_out, int out_size, void* d_ws, size_t ws_size,
                              hipStream_t stream) {
  (void)in_sizes; (void)n_in; (void)out_size; (void)ws_size;
  const float* x     = (const float*)d_in[0];
  const int*   ei    = (const int*)d_in[1];
  const float* W1    = (const float*)d_in[2];
  const float* atts1 = (const float*)d_in[3];
  const float* attd1 = (const float*)d_in[4];
  const float* b1    = (const float*)d_in[5];
  const float* W2    = (const float*)d_in[6];
  const float* atts2 = (const float*)d_in[7];
  const float* attd2 = (const float*)d_in[8];
  const float* b2    = (const float*)d_in[9];
  const float* Wl    = (const float*)d_in[10];
  const float* bl    = (const float*)d_in[11];
  float* out = (float*)d_out;

  char* w = (char*)d_ws;
  float* h1   = (float*)w; w += (size_t)N_NODES * 128 * 4;   // 25.6 MB (alias: e2 after agg1)
  float* h1e  = (float*)w; w += (size_t)N_NODES * 128 * 4;   // 25.6 MB
  float* h2   = (float*)w; w += (size_t)N_EDGES * 16;        // 12.8 MB (alias: e1 before gemm64)
  float* as1  = (float*)w; w += (size_t)N_NODES * 16;
  float* ad1  = (float*)w; w += (size_t)N_NODES * 16;
  float* di1  = (float*)w; w += (size_t)N_NODES * 16;
  float* es1  = (float*)w; w += (size_t)N_NODES * 16;
  float* as2  = (float*)w; w += (size_t)N_NODES * 4;
  float* ad2  = (float*)w; w += (size_t)N_NODES * 4;
  float* di2a = (float*)w; w += (size_t)N_NODES * 4;
  float* es2a = (float*)w; w += (size_t)N_NODES * 4;
  int* deg    = (int*)w; w += (size_t)N_NODES * 4;
  int* cursor = (int*)w; w += (size_t)N_NODES * 4;
  float* pooled = (float*)w; w += 64 * 64 * 4;               // 64 stripes x 64
  int* rowptr = (int*)w; w += (size_t)(N_NODES + 1) * 4 + 12;
  int* col    = (int*)w; w += (size_t)N_EDGES * 4;
  int* cdst   = (int*)w; w += (size_t)N_EDGES * 4;
  int* blocksum = (int*)w; w += 256 * 4;
  int* blockoff = (int*)w; w += 256 * 4;

  float4* e1v = (float4*)h2;   // lifetime: after ealpha1 .. agg1; h2 written after agg1
  float*  e2a = h1;            // lifetime: after ealpha2 .. agg2; h1 dead after agg1

  // zero deg + cursor + pooled (contiguous)
  hipMemsetAsync(deg, 0, (size_t)N_NODES * 8 + 64 * 64 * 4, stream);

  hist_kernel<<<(N_EDGES + 255) / 256, 256, 0, stream>>>(ei, deg);
  scan_part_kernel<<<SCAN_BLOCKS, 256, 0, stream>>>(deg, rowptr, blocksum);
  scan_top_kernel<<<1, 256, 0, stream>>>(blocksum, blockoff);
  scan_add_kernel<<<SCAN_BLOCKS, 256, 0, stream>>>(blockoff, rowptr);
  scatter_kernel<<<(N_EDGES + 255) / 256, 256, 0, stream>>>(ei, rowptr, cursor, col, cdst);

  gemm_kernel<128><<<(N_NODES + 63) / 64, 256, 0, stream>>>(x, W1, h1);
  attn1_kernel<<<N_NODES / 4, 256, 0, stream>>>(h1, atts1, attd1, as1, ad1);
  ealpha1_kernel<<<(N_EDGES + 255) / 256, 256, 0, stream>>>(col, cdst, (const float4*)as1, (const float4*)ad1, e1v);
  red1_kernel<<<(N_NODES + 15) / 16, 256, 0, stream>>>(e1v, rowptr, (const float4*)as1, (const float4*)ad1,
                                                       (float4*)di1, (float4*)es1);
  agg1_kernel<<<N_NODES / 4, 256, 0, stream>>>((const float4*)h1, (const float*)e1v, rowptr, col,
                                               di1, es1, (const float4*)b1, (float4*)h1e);

  gemm_kernel<64><<<(N_NODES + 63) / 64, 256, 0, stream>>>(h1e, W2, h2);
  attn2_kernel<<<N_NODES / 4, 256, 0, stream>>>(h2, atts2, attd2, as2, ad2);
  ealpha2_kernel<<<(N_EDGES + 255) / 256, 256, 0, stream>>>(col, cdst, as2, ad2, e2a);
  red2_kernel<<<(N_NODES + 15) / 16, 256, 0, stream>>>(e2a, rowptr, as2, ad2, di2a, es2a);
  agg2_kernel<<<N_NODES / 4, 256, 0, stream>>>((const float4*)h2, e2a, rowptr, col,
                                               di2a, es2a, (const float4*)b2, pooled);

  final_kernel<<<1, 64, 0, stream>>>(pooled, Wl, bl, out);
}

// Round 6
// 347.003 us; speedup vs baseline: 2.2948x; 1.1288x over previous
//
#include <hip/hip_runtime.h>

#define N_NODES 50000
#define N_EDGES 800000
#define SCAN_BLOCKS ((N_NODES + 255) / 256)  // 196

__device__ __forceinline__ float lrelu(float x) { return x > 0.f ? x : 0.2f * x; }
__device__ __forceinline__ float elu(float x) { return x > 0.f ? x : expf(x) - 1.f; }

// bf16 helpers: lo/hi halves of a uint holding 2 consecutive bf16 elements
__device__ __forceinline__ float bfl(unsigned u) { return __uint_as_float(u << 16); }
__device__ __forceinline__ float bfh(unsigned u) { return __uint_as_float(u & 0xffff0000u); }
__device__ __forceinline__ unsigned f2bf_rn(float x) {
  unsigned u = __float_as_uint(x);
  return (u + 0x7fffu + ((u >> 16) & 1u)) >> 16;
}
__device__ __forceinline__ unsigned pack2bf(float a, float b) {
  return f2bf_rn(a) | (f2bf_rn(b) << 16);
}

// ---------------- CSR build ----------------
__global__ __launch_bounds__(256) void hist_kernel(const int* __restrict__ ei, int* __restrict__ deg) {
  int e = blockIdx.x * 256 + threadIdx.x;
  if (e < N_EDGES) atomicAdd(&deg[ei[N_EDGES + e]], 1);
}

__device__ __forceinline__ int block_excl_scan(int v, int* total_out) {
  int lane = threadIdx.x & 63;
  int wid = threadIdx.x >> 6;
  int x = v;
#pragma unroll
  for (int off = 1; off < 64; off <<= 1) {
    int u = __shfl_up(x, off);
    if (lane >= off) x += u;
  }
  __shared__ int wsum[4];
  if (lane == 63) wsum[wid] = x;
  __syncthreads();
  int add = 0;
#pragma unroll
  for (int k = 0; k < 4; ++k)
    if (k < wid) add += wsum[k];
  if (total_out) *total_out = wsum[0] + wsum[1] + wsum[2] + wsum[3];
  return x + add - v;
}

__global__ __launch_bounds__(256) void scan_part_kernel(const int* __restrict__ deg, int* __restrict__ rowptr,
                                                        int* __restrict__ blocksum) {
  int g = blockIdx.x * 256 + threadIdx.x;
  int v = (g < N_NODES) ? deg[g] : 0;
  int total;
  int ex = block_excl_scan(v, &total);
  if (g < N_NODES) rowptr[g] = ex;
  if (threadIdx.x == 0) blocksum[blockIdx.x] = total;
}

__global__ __launch_bounds__(256) void scan_top_kernel(const int* __restrict__ blocksum, int* __restrict__ blockoff) {
  int t = threadIdx.x;
  int v = (t < SCAN_BLOCKS) ? blocksum[t] : 0;
  int ex = block_excl_scan(v, nullptr);
  if (t < SCAN_BLOCKS) blockoff[t] = ex;
}

__global__ __launch_bounds__(256) void scan_add_kernel(const int* __restrict__ blockoff, int* __restrict__ rowptr) {
  int g = blockIdx.x * 256 + threadIdx.x;
  if (g < N_NODES) rowptr[g] += blockoff[g >> 8];
  if (g == 0) rowptr[N_NODES] = N_EDGES;
}

__global__ __launch_bounds__(256) void scatter_kernel(const int* __restrict__ ei, const int* __restrict__ rowptr,
                                                      int* __restrict__ cursor, int* __restrict__ col,
                                                      int* __restrict__ cdst) {
  int e = blockIdx.x * 256 + threadIdx.x;
  if (e < N_EDGES) {
    int d = ei[N_EDGES + e];
    int pos = rowptr[d] + atomicAdd(&cursor[d], 1);
    col[pos] = ei[e];
    cdst[pos] = d;
  }
}

// ---------------- GEMM: Yb[N,COLS](bf16) = A[N,128] @ W[128,COLS]; A fp32 or bf16 ----------------
template <int COLS, bool ABF16>
__global__ __launch_bounds__(256) void gemm_kernel(const void* __restrict__ Ap, const float* __restrict__ W,
                                                   unsigned* __restrict__ Yb) {
  constexpr int CPT = COLS / 16;  // cols per thread (8 or 4)
  __shared__ float ws[64 * COLS];
  __shared__ float xs[64 * 64];
  int t = threadIdx.x;
  int rbase = blockIdx.x * 64;
  int tx = t & 15, ty = t >> 4;
  float acc[4][CPT];
#pragma unroll
  for (int r = 0; r < 4; ++r)
#pragma unroll
    for (int c = 0; c < CPT; ++c) acc[r][c] = 0.f;

  const float4* W4 = (const float4*)W;
  for (int kt = 0; kt < 2; ++kt) {
    float4* ws4 = (float4*)ws;
    for (int i = t; i < 64 * COLS / 4; i += 256) ws4[i] = W4[kt * 16 * COLS + i];
    if constexpr (ABF16) {
      const uint4* A4 = (const uint4*)Ap;  // row = 128 bf16 = 16 uint4
      for (int i = t; i < 512; i += 256) {
        int row = i >> 3, q = i & 7;
        int gr = rbase + row; if (gr >= N_NODES) gr = N_NODES - 1;
        uint4 u = A4[gr * 16 + kt * 8 + q];
        float4 lo = make_float4(bfl(u.x), bfh(u.x), bfl(u.y), bfh(u.y));
        float4 hi = make_float4(bfl(u.z), bfh(u.z), bfl(u.w), bfh(u.w));
        float4* dst = (float4*)&xs[row * 64 + q * 8];
        dst[0] = lo; dst[1] = hi;
      }
    } else {
      const float4* A4 = (const float4*)Ap;
      float4* xs4 = (float4*)xs;
      for (int i = t; i < 1024; i += 256) {
        int row = i >> 4, kc = i & 15;
        int gr = rbase + row; if (gr >= N_NODES) gr = N_NODES - 1;
        xs4[i] = A4[gr * 32 + kt * 16 + kc];
      }
    }
    __syncthreads();
#pragma unroll 8
    for (int k = 0; k < 64; ++k) {
      float xr[4];
#pragma unroll
      for (int r = 0; r < 4; ++r) xr[r] = xs[(ty * 4 + r) * 64 + k];
#pragma unroll
      for (int c4 = 0; c4 < CPT / 4; ++c4) {
        float4 wv = *(const float4*)&ws[k * COLS + tx * CPT + c4 * 4];
#pragma unroll
        for (int r = 0; r < 4; ++r) {
          acc[r][c4 * 4 + 0] += xr[r] * wv.x;
          acc[r][c4 * 4 + 1] += xr[r] * wv.y;
          acc[r][c4 * 4 + 2] += xr[r] * wv.z;
          acc[r][c4 * 4 + 3] += xr[r] * wv.w;
        }
      }
    }
    __syncthreads();
  }
#pragma unroll
  for (int r = 0; r < 4; ++r) {
    int row = rbase + ty * 4 + r;
    if (row < N_NODES) {
      if constexpr (CPT == 8) {
        uint4 o;
        o.x = pack2bf(acc[r][0], acc[r][1]);
        o.y = pack2bf(acc[r][2], acc[r][3]);
        o.z = pack2bf(acc[r][4], acc[r][5]);
        o.w = pack2bf(acc[r][6], acc[r][7]);
        ((uint4*)Yb)[row * 16 + tx] = o;
      } else {
        uint2 o;
        o.x = pack2bf(acc[r][0], acc[r][1]);
        o.y = pack2bf(acc[r][2], acc[r][3]);
        ((uint2*)Yb)[row * 16 + tx] = o;
      }
    }
  }
}

// ---------------- attention dot products (bf16 inputs) ----------------
__global__ __launch_bounds__(256) void attn1_kernel(const unsigned* __restrict__ h1b, const float* __restrict__ atts,
                                                    const float* __restrict__ attd, float* __restrict__ as1,
                                                    float* __restrict__ ad1) {
  int n = (blockIdx.x * 256 + threadIdx.x) >> 6;
  int lane = threadIdx.x & 63;
  unsigned u = h1b[n * 64 + lane];
  float v0 = bfl(u), v1 = bfh(u);
  int f = lane * 2;
  float s = v0 * atts[f] + v1 * atts[f + 1];
  float d = v0 * attd[f] + v1 * attd[f + 1];
#pragma unroll
  for (int off = 1; off < 16; off <<= 1) {
    s += __shfl_xor(s, off);
    d += __shfl_xor(d, off);
  }
  if ((lane & 15) == 0) {
    int h = lane >> 4;
    as1[n * 4 + h] = s;
    ad1[n * 4 + h] = d;
  }
}

__global__ __launch_bounds__(256) void attn2_kernel(const unsigned* __restrict__ h2b, const float* __restrict__ atts,
                                                    const float* __restrict__ attd, float* __restrict__ as2,
                                                    float* __restrict__ ad2) {
  int n = (blockIdx.x * 256 + threadIdx.x) >> 5;
  int l = threadIdx.x & 31;
  unsigned u = h2b[n * 32 + l];
  float v0 = bfl(u), v1 = bfh(u);
  int f = l * 2;
  float s = v0 * atts[f] + v1 * atts[f + 1];
  float d = v0 * attd[f] + v1 * attd[f + 1];
#pragma unroll
  for (int off = 1; off < 32; off <<= 1) {
    s += __shfl_xor(s, off);
    d += __shfl_xor(d, off);
  }
  if (l == 0) { as2[n] = s; ad2[n] = d; }
}

// ---------------- edge-parallel unnormalized weights e = exp(lrelu(as+ad)) ----------------
__global__ __launch_bounds__(256) void ealpha1_kernel(const int* __restrict__ col, const int* __restrict__ cdst,
                                                      const float4* __restrict__ as1v, const float4* __restrict__ ad1v,
                                                      float4* __restrict__ e1v) {
  int p = blockIdx.x * 256 + threadIdx.x;
  if (p >= N_EDGES) return;
  int s = col[p], d = cdst[p];
  float4 a = as1v[s], b = ad1v[d];
  float4 o;
  o.x = expf(lrelu(a.x + b.x));
  o.y = expf(lrelu(a.y + b.y));
  o.z = expf(lrelu(a.z + b.z));
  o.w = expf(lrelu(a.w + b.w));
  e1v[p] = o;
}

__global__ __launch_bounds__(256) void ealpha2_kernel(const int* __restrict__ col, const int* __restrict__ cdst,
                                                      const float* __restrict__ as2, const float* __restrict__ ad2,
                                                      float* __restrict__ e2a) {
  int p = blockIdx.x * 256 + threadIdx.x;
  if (p >= N_EDGES) return;
  e2a[p] = expf(lrelu(as2[col[p]] + ad2[cdst[p]]));
}

// ---------------- per-node denom: contiguous sum of e + self term; 16 lanes/node ----------------
__global__ __launch_bounds__(256) void red1_kernel(const float4* __restrict__ e1v, const int* __restrict__ rowptr,
                                                   const float4* __restrict__ as1v, const float4* __restrict__ ad1v,
                                                   float4* __restrict__ di1v, float4* __restrict__ es1v) {
  int n = blockIdx.x * 16 + (threadIdx.x >> 4);
  int sub = threadIdx.x & 15;
  int beg = rowptr[n], end = rowptr[n + 1];
  float4 s = make_float4(0.f, 0.f, 0.f, 0.f);
  for (int i = beg + sub; i < end; i += 16) {
    float4 v = e1v[i];
    s.x += v.x; s.y += v.y; s.z += v.z; s.w += v.w;
  }
#pragma unroll
  for (int off = 1; off < 16; off <<= 1) {
    s.x += __shfl_xor(s.x, off);
    s.y += __shfl_xor(s.y, off);
    s.z += __shfl_xor(s.z, off);
    s.w += __shfl_xor(s.w, off);
  }
  if (sub == 0) {
    float4 a = as1v[n], b = ad1v[n];
    float4 es;
    es.x = expf(lrelu(a.x + b.x));
    es.y = expf(lrelu(a.y + b.y));
    es.z = expf(lrelu(a.z + b.z));
    es.w = expf(lrelu(a.w + b.w));
    es1v[n] = es;
    di1v[n] = make_float4(1.f / (s.x + es.x), 1.f / (s.y + es.y), 1.f / (s.z + es.z), 1.f / (s.w + es.w));
  }
}

__global__ __launch_bounds__(256) void red2_kernel(const float* __restrict__ e2a, const int* __restrict__ rowptr,
                                                   const float* __restrict__ as2, const float* __restrict__ ad2,
                                                   float* __restrict__ di2a, float* __restrict__ es2a) {
  int n = blockIdx.x * 16 + (threadIdx.x >> 4);
  int sub = threadIdx.x & 15;
  int beg = rowptr[n], end = rowptr[n + 1];
  float s = 0.f;
  for (int i = beg + sub; i < end; i += 16) s += e2a[i];
#pragma unroll
  for (int off = 1; off < 16; off <<= 1) s += __shfl_xor(s, off);
  if (sub == 0) {
    float es = expf(lrelu(as2[n] + ad2[n]));
    es2a[n] = es;
    di2a[n] = 1.f / (s + es);
  }
}

// ---------------- layer-1 gather: bf16 rows, 4 rows per wave-load ----------------
__global__ __launch_bounds__(256) void agg1_kernel(const uint4* __restrict__ h1b4, const float* __restrict__ e1,
                                                   const int* __restrict__ rowptr, const int* __restrict__ col,
                                                   const float* __restrict__ di1, const float* __restrict__ es1,
                                                   const float4* __restrict__ b1v, uint4* __restrict__ h1eb4) {
  int n = (blockIdx.x * 256 + threadIdx.x) >> 6;
  int lane = threadIdx.x & 63;
  int slot = lane >> 4;  // 0..3
  int fo = lane & 15;    // feats fo*8 .. fo*8+7
  int h = fo >> 2;       // head for these 8 feats
  int beg = rowptr[n], end = rowptr[n + 1];

  float acc[8];
#pragma unroll
  for (int j = 0; j < 8; ++j) acc[j] = 0.f;

#define ACC_EDGE1(E)                                        \
  {                                                         \
    int src = col[E];                                       \
    float a = e1[(E) * 4 + h];                              \
    uint4 uu = h1b4[src * 16 + fo];                         \
    acc[0] += a * bfl(uu.x); acc[1] += a * bfh(uu.x);       \
    acc[2] += a * bfl(uu.y); acc[3] += a * bfh(uu.y);       \
    acc[4] += a * bfl(uu.z); acc[5] += a * bfh(uu.z);       \
    acc[6] += a * bfl(uu.w); acc[7] += a * bfh(uu.w);       \
  }

  int i = beg;
  for (; i + 16 <= end; i += 16) {
#pragma unroll
    for (int u = 0; u < 4; ++u) ACC_EDGE1(i + u * 4 + slot);
  }
  for (; i + 4 <= end; i += 4) ACC_EDGE1(i + slot);
  int rem = end - i;
  if (slot < rem) ACC_EDGE1(i + slot);
  // self loop
  if (slot == 0) {
    float wv = es1[n * 4 + h];
    uint4 uu = h1b4[n * 16 + fo];
    acc[0] += wv * bfl(uu.x); acc[1] += wv * bfh(uu.x);
    acc[2] += wv * bfl(uu.y); acc[3] += wv * bfh(uu.y);
    acc[4] += wv * bfl(uu.z); acc[5] += wv * bfh(uu.z);
    acc[6] += wv * bfl(uu.w); acc[7] += wv * bfh(uu.w);
  }
#pragma unroll
  for (int j = 0; j < 8; ++j) {
    acc[j] += __shfl_xor(acc[j], 16);
    acc[j] += __shfl_xor(acc[j], 32);
  }
  if (slot == 0) {
    float dsc = di1[n * 4 + h];
    float4 b0 = b1v[fo * 2], b1 = b1v[fo * 2 + 1];
    float f0 = elu(acc[0] * dsc + b0.x), f1 = elu(acc[1] * dsc + b0.y);
    float f2 = elu(acc[2] * dsc + b0.z), f3 = elu(acc[3] * dsc + b0.w);
    float f4 = elu(acc[4] * dsc + b1.x), f5 = elu(acc[5] * dsc + b1.y);
    float f6 = elu(acc[6] * dsc + b1.z), f7 = elu(acc[7] * dsc + b1.w);
    uint4 o;
    o.x = pack2bf(f0, f1); o.y = pack2bf(f2, f3);
    o.z = pack2bf(f4, f5); o.w = pack2bf(f6, f7);
    h1eb4[n * 16 + fo] = o;
  }
#undef ACC_EDGE1
}

// ---------------- layer-2 gather + fused global add pool: bf16 rows, 8 rows per wave-load ----------------
__global__ __launch_bounds__(256) void agg2_kernel(const uint4* __restrict__ h2b4, const float* __restrict__ e2a,
                                                   const int* __restrict__ rowptr, const int* __restrict__ col,
                                                   const float* __restrict__ di2a, const float* __restrict__ es2a,
                                                   const float4* __restrict__ b2v, float* __restrict__ pooled) {
  __shared__ float red[4][64];
  int n = (blockIdx.x * 256 + threadIdx.x) >> 6;
  int lane = threadIdx.x & 63;
  int wid = threadIdx.x >> 6;
  int slot = lane >> 3;  // 0..7
  int fo = lane & 7;     // feats fo*8 .. fo*8+7
  int beg = rowptr[n], end = rowptr[n + 1];

  float acc[8];
#pragma unroll
  for (int j = 0; j < 8; ++j) acc[j] = 0.f;

#define ACC_EDGE2(E)                                        \
  {                                                         \
    int src = col[E];                                       \
    float a = e2a[E];                                       \
    uint4 uu = h2b4[src * 8 + fo];                          \
    acc[0] += a * bfl(uu.x); acc[1] += a * bfh(uu.x);       \
    acc[2] += a * bfl(uu.y); acc[3] += a * bfh(uu.y);       \
    acc[4] += a * bfl(uu.z); acc[5] += a * bfh(uu.z);       \
    acc[6] += a * bfl(uu.w); acc[7] += a * bfh(uu.w);       \
  }

  int i = beg;
  for (; i + 32 <= end; i += 32) {
#pragma unroll
    for (int u = 0; u < 4; ++u) ACC_EDGE2(i + u * 8 + slot);
  }
  for (; i + 8 <= end; i += 8) ACC_EDGE2(i + slot);
  int rem = end - i;
  if (slot < rem) ACC_EDGE2(i + slot);
  // self loop
  if (slot == 0) {
    float wv = es2a[n];
    uint4 uu = h2b4[n * 8 + fo];
    acc[0] += wv * bfl(uu.x); acc[1] += wv * bfh(uu.x);
    acc[2] += wv * bfl(uu.y); acc[3] += wv * bfh(uu.y);
    acc[4] += wv * bfl(uu.z); acc[5] += wv * bfh(uu.z);
    acc[6] += wv * bfl(uu.w); acc[7] += wv * bfh(uu.w);
  }
#pragma unroll
  for (int j = 0; j < 8; ++j) {
    acc[j] += __shfl_xor(acc[j], 8);
    acc[j] += __shfl_xor(acc[j], 16);
    acc[j] += __shfl_xor(acc[j], 32);
  }
  if (slot == 0) {
    float dsc = di2a[n];
    float4 b0 = b2v[fo * 2], b1 = b2v[fo * 2 + 1];
    red[wid][fo * 8 + 0] = elu(acc[0] * dsc + b0.x);
    red[wid][fo * 8 + 1] = elu(acc[1] * dsc + b0.y);
    red[wid][fo * 8 + 2] = elu(acc[2] * dsc + b0.z);
    red[wid][fo * 8 + 3] = elu(acc[3] * dsc + b0.w);
    red[wid][fo * 8 + 4] = elu(acc[4] * dsc + b1.x);
    red[wid][fo * 8 + 5] = elu(acc[5] * dsc + b1.y);
    red[wid][fo * 8 + 6] = elu(acc[6] * dsc + b1.z);
    red[wid][fo * 8 + 7] = elu(acc[7] * dsc + b1.w);
  }
  __syncthreads();
  if (threadIdx.x < 64) {
    float sum = red[0][threadIdx.x] + red[1][threadIdx.x] + red[2][threadIdx.x] + red[3][threadIdx.x];
    atomicAdd(&pooled[(blockIdx.x & 63) * 64 + threadIdx.x], sum);
  }
#undef ACC_EDGE2
}

// ---------------- final: reduce pooled stripes + pooled@Wl+bl ----------------
__global__ void final_kernel(const float* __restrict__ pooledS, const float* __restrict__ Wl,
                             const float* __restrict__ bl, float* __restrict__ out) {
  __shared__ float p[64];
  int t = threadIdx.x;
  float v = 0.f;
  for (int k = 0; k < 64; ++k) v += pooledS[k * 64 + t];
  p[t] = v;
  out[t] = v;
  __syncthreads();
  if (t < 2) {
    float s = bl[t];
    for (int k = 0; k < 64; ++k) s += p[k] * Wl[k * 2 + t];
    out[64 + t] = s;
  }
}

extern "C" void kernel_launch(void* const* d_in, const int* in_sizes, int n_in,
                              void* d_out, int out_size, void* d_ws, size_t ws_size,
                              hipStream_t stream) {
  (void)in_sizes; (void)n_in; (void)out_size; (void)ws_size;
  const float* x     = (const float*)d_in[0];
  const int*   ei    = (const int*)d_in[1];
  const float* W1    = (const float*)d_in[2];
  const float* atts1 = (const float*)d_in[3];
  const float* attd1 = (const float*)d_in[4];
  const float* b1    = (const float*)d_in[5];
  const float* W2    = (const float*)d_in[6];
  const float* atts2 = (const float*)d_in[7];
  const float* attd2 = (const float*)d_in[8];
  const float* b2    = (const float*)d_in[9];
  const float* Wl    = (const float*)d_in[10];
  const float* bl    = (const float*)d_in[11];
  float* out = (float*)d_out;

  char* w = (char*)d_ws;
  unsigned* h1b  = (unsigned*)w; w += (size_t)N_NODES * 128 * 2;  // 12.8 MB bf16
  unsigned* h1eb = (unsigned*)w; w += (size_t)N_NODES * 128 * 2;  // 12.8 MB bf16
  unsigned* h2b  = (unsigned*)w; w += (size_t)N_NODES * 64 * 2;   // 6.4 MB bf16
  float* e1   = (float*)w; w += (size_t)N_EDGES * 16;             // 12.8 MB
  float* e2a  = (float*)w; w += (size_t)N_EDGES * 4;              // 3.2 MB
  float* as1  = (float*)w; w += (size_t)N_NODES * 16;
  float* ad1  = (float*)w; w += (size_t)N_NODES * 16;
  float* di1  = (float*)w; w += (size_t)N_NODES * 16;
  float* es1  = (float*)w; w += (size_t)N_NODES * 16;
  float* as2  = (float*)w; w += (size_t)N_NODES * 4;
  float* ad2  = (float*)w; w += (size_t)N_NODES * 4;
  float* di2a = (float*)w; w += (size_t)N_NODES * 4;
  float* es2a = (float*)w; w += (size_t)N_NODES * 4;
  int* deg    = (int*)w; w += (size_t)N_NODES * 4;
  int* cursor = (int*)w; w += (size_t)N_NODES * 4;
  float* pooled = (float*)w; w += 64 * 64 * 4;                    // 64 stripes x 64
  int* rowptr = (int*)w; w += (size_t)(N_NODES + 1) * 4 + 12;
  int* col    = (int*)w; w += (size_t)N_EDGES * 4;
  int* cdst   = (int*)w; w += (size_t)N_EDGES * 4;
  int* blocksum = (int*)w; w += 256 * 4;
  int* blockoff = (int*)w; w += 256 * 4;

  // zero deg + cursor + pooled (contiguous)
  hipMemsetAsync(deg, 0, (size_t)N_NODES * 8 + 64 * 64 * 4, stream);

  hist_kernel<<<(N_EDGES + 255) / 256, 256, 0, stream>>>(ei, deg);
  scan_part_kernel<<<SCAN_BLOCKS, 256, 0, stream>>>(deg, rowptr, blocksum);
  scan_top_kernel<<<1, 256, 0, stream>>>(blocksum, blockoff);
  scan_add_kernel<<<SCAN_BLOCKS, 256, 0, stream>>>(blockoff, rowptr);
  scatter_kernel<<<(N_EDGES + 255) / 256, 256, 0, stream>>>(ei, rowptr, cursor, col, cdst);

  gemm_kernel<128, false><<<(N_NODES + 63) / 64, 256, 0, stream>>>(x, W1, h1b);
  attn1_kernel<<<N_NODES / 4, 256, 0, stream>>>(h1b, atts1, attd1, as1, ad1);
  ealpha1_kernel<<<(N_EDGES + 255) / 256, 256, 0, stream>>>(col, cdst, (const float4*)as1, (const float4*)ad1,
                                                            (float4*)e1);
  red1_kernel<<<(N_NODES + 15) / 16, 256, 0, stream>>>((const float4*)e1, rowptr, (const float4*)as1,
                                                       (const float4*)ad1, (float4*)di1, (float4*)es1);
  agg1_kernel<<<N_NODES / 4, 256, 0, stream>>>((const uint4*)h1b, e1, rowptr, col, di1, es1,
                                               (const float4*)b1, (uint4*)h1eb);

  gemm_kernel<64, true><<<(N_NODES + 63) / 64, 256, 0, stream>>>(h1eb, W2, h2b);
  attn2_kernel<<<N_NODES / 8, 256, 0, stream>>>(h2b, atts2, attd2, as2, ad2);
  ealpha2_kernel<<<(N_EDGES + 255) / 256, 256, 0, stream>>>(col, cdst, as2, ad2, e2a);
  red2_kernel<<<(N_NODES + 15) / 16, 256, 0, stream>>>(e2a, rowptr, as2, ad2, di2a, es2a);
  agg2_kernel<<<N_NODES / 4, 256, 0, stream>>>((const uint4*)h2b, e2a, rowptr, col, di2a, es2a,
                                               (const float4*)b2, pooled);

  final_kernel<<<1, 64, 0, stream>>>(pooled, Wl, bl, out);
}

// Round 7
// 331.096 us; speedup vs baseline: 2.4051x; 1.0480x over previous
//
#include <hip/hip_runtime.h>

#define N_NODES 50000
#define N_EDGES 800000
#define SCAN_BLOCKS ((N_NODES + 255) / 256)  // 196

__device__ __forceinline__ float lrelu(float x) { return x > 0.f ? x : 0.2f * x; }
__device__ __forceinline__ float elu(float x) { return x > 0.f ? x : expf(x) - 1.f; }

// bf16 helpers: lo/hi halves of a uint holding 2 consecutive bf16 elements
__device__ __forceinline__ float bfl(unsigned u) { return __uint_as_float(u << 16); }
__device__ __forceinline__ float bfh(unsigned u) { return __uint_as_float(u & 0xffff0000u); }
__device__ __forceinline__ unsigned f2bf_rn(float x) {
  unsigned u = __float_as_uint(x);
  return (u + 0x7fffu + ((u >> 16) & 1u)) >> 16;
}
__device__ __forceinline__ unsigned pack2bf(float a, float b) {
  return f2bf_rn(a) | (f2bf_rn(b) << 16);
}

// ---------------- CSR build ----------------
__global__ __launch_bounds__(256) void hist_kernel(const int* __restrict__ ei, int* __restrict__ deg) {
  int e = blockIdx.x * 256 + threadIdx.x;
  if (e < N_EDGES) atomicAdd(&deg[ei[N_EDGES + e]], 1);
}

__device__ __forceinline__ int block_excl_scan(int v, int* total_out) {
  int lane = threadIdx.x & 63;
  int wid = threadIdx.x >> 6;
  int x = v;
#pragma unroll
  for (int off = 1; off < 64; off <<= 1) {
    int u = __shfl_up(x, off);
    if (lane >= off) x += u;
  }
  __shared__ int wsum[4];
  if (lane == 63) wsum[wid] = x;
  __syncthreads();
  int add = 0;
#pragma unroll
  for (int k = 0; k < 4; ++k)
    if (k < wid) add += wsum[k];
  if (total_out) *total_out = wsum[0] + wsum[1] + wsum[2] + wsum[3];
  return x + add - v;
}

__global__ __launch_bounds__(256) void scan_part_kernel(const int* __restrict__ deg, int* __restrict__ rowptr,
                                                        int* __restrict__ blocksum) {
  int g = blockIdx.x * 256 + threadIdx.x;
  int v = (g < N_NODES) ? deg[g] : 0;
  int total;
  int ex = block_excl_scan(v, &total);
  if (g < N_NODES) rowptr[g] = ex;
  if (threadIdx.x == 0) blocksum[blockIdx.x] = total;
}

__global__ __launch_bounds__(256) void scan_top_kernel(const int* __restrict__ blocksum, int* __restrict__ blockoff) {
  int t = threadIdx.x;
  int v = (t < SCAN_BLOCKS) ? blocksum[t] : 0;
  int ex = block_excl_scan(v, nullptr);
  if (t < SCAN_BLOCKS) blockoff[t] = ex;
}

__global__ __launch_bounds__(256) void scan_add_kernel(const int* __restrict__ blockoff, int* __restrict__ rowptr) {
  int g = blockIdx.x * 256 + threadIdx.x;
  if (g < N_NODES) rowptr[g] += blockoff[g >> 8];
  if (g == 0) rowptr[N_NODES] = N_EDGES;
}

__global__ __launch_bounds__(256) void scatter_kernel(const int* __restrict__ ei, const int* __restrict__ rowptr,
                                                      int* __restrict__ cursor, int* __restrict__ col) {
  int e = blockIdx.x * 256 + threadIdx.x;
  if (e < N_EDGES) {
    int d = ei[N_EDGES + e];
    int pos = rowptr[d] + atomicAdd(&cursor[d], 1);
    col[pos] = ei[e];
  }
}

// ---------------- GEMM: Yb[N,COLS](bf16) = A[N,128] @ W[128,COLS]; A fp32 or bf16 ----------------
template <int COLS, bool ABF16>
__global__ __launch_bounds__(256) void gemm_kernel(const void* __restrict__ Ap, const float* __restrict__ W,
                                                   unsigned* __restrict__ Yb) {
  constexpr int CPT = COLS / 16;  // cols per thread (8 or 4)
  __shared__ float ws[64 * COLS];
  __shared__ float xs[64 * 64];
  int t = threadIdx.x;
  int rbase = blockIdx.x * 64;
  int tx = t & 15, ty = t >> 4;
  float acc[4][CPT];
#pragma unroll
  for (int r = 0; r < 4; ++r)
#pragma unroll
    for (int c = 0; c < CPT; ++c) acc[r][c] = 0.f;

  const float4* W4 = (const float4*)W;
  for (int kt = 0; kt < 2; ++kt) {
    float4* ws4 = (float4*)ws;
    for (int i = t; i < 64 * COLS / 4; i += 256) ws4[i] = W4[kt * 16 * COLS + i];
    if constexpr (ABF16) {
      const uint4* A4 = (const uint4*)Ap;  // row = 128 bf16 = 16 uint4
      for (int i = t; i < 512; i += 256) {
        int row = i >> 3, q = i & 7;
        int gr = rbase + row; if (gr >= N_NODES) gr = N_NODES - 1;
        uint4 u = A4[gr * 16 + kt * 8 + q];
        float4 lo = make_float4(bfl(u.x), bfh(u.x), bfl(u.y), bfh(u.y));
        float4 hi = make_float4(bfl(u.z), bfh(u.z), bfl(u.w), bfh(u.w));
        float4* dst = (float4*)&xs[row * 64 + q * 8];
        dst[0] = lo; dst[1] = hi;
      }
    } else {
      const float4* A4 = (const float4*)Ap;
      float4* xs4 = (float4*)xs;
      for (int i = t; i < 1024; i += 256) {
        int row = i >> 4, kc = i & 15;
        int gr = rbase + row; if (gr >= N_NODES) gr = N_NODES - 1;
        xs4[i] = A4[gr * 32 + kt * 16 + kc];
      }
    }
    __syncthreads();
#pragma unroll 8
    for (int k = 0; k < 64; ++k) {
      float xr[4];
#pragma unroll
      for (int r = 0; r < 4; ++r) xr[r] = xs[(ty * 4 + r) * 64 + k];
#pragma unroll
      for (int c4 = 0; c4 < CPT / 4; ++c4) {
        float4 wv = *(const float4*)&ws[k * COLS + tx * CPT + c4 * 4];
#pragma unroll
        for (int r = 0; r < 4; ++r) {
          acc[r][c4 * 4 + 0] += xr[r] * wv.x;
          acc[r][c4 * 4 + 1] += xr[r] * wv.y;
          acc[r][c4 * 4 + 2] += xr[r] * wv.z;
          acc[r][c4 * 4 + 3] += xr[r] * wv.w;
        }
      }
    }
    __syncthreads();
  }
#pragma unroll
  for (int r = 0; r < 4; ++r) {
    int row = rbase + ty * 4 + r;
    if (row < N_NODES) {
      if constexpr (CPT == 8) {
        uint4 o;
        o.x = pack2bf(acc[r][0], acc[r][1]);
        o.y = pack2bf(acc[r][2], acc[r][3]);
        o.z = pack2bf(acc[r][4], acc[r][5]);
        o.w = pack2bf(acc[r][6], acc[r][7]);
        ((uint4*)Yb)[row * 16 + tx] = o;
      } else {
        uint2 o;
        o.x = pack2bf(acc[r][0], acc[r][1]);
        o.y = pack2bf(acc[r][2], acc[r][3]);
        ((uint2*)Yb)[row * 16 + tx] = o;
      }
    }
  }
}

// ---------------- attention dot products (bf16 inputs) ----------------
__global__ __launch_bounds__(256) void attn1_kernel(const unsigned* __restrict__ h1b, const float* __restrict__ atts,
                                                    const float* __restrict__ attd, float* __restrict__ as1,
                                                    float* __restrict__ ad1) {
  int n = (blockIdx.x * 256 + threadIdx.x) >> 6;
  int lane = threadIdx.x & 63;
  unsigned u = h1b[n * 64 + lane];
  float v0 = bfl(u), v1 = bfh(u);
  int f = lane * 2;
  float s = v0 * atts[f] + v1 * atts[f + 1];
  float d = v0 * attd[f] + v1 * attd[f + 1];
#pragma unroll
  for (int off = 1; off < 16; off <<= 1) {
    s += __shfl_xor(s, off);
    d += __shfl_xor(d, off);
  }
  if ((lane & 15) == 0) {
    int h = lane >> 4;
    as1[n * 4 + h] = s;
    ad1[n * 4 + h] = d;
  }
}

__global__ __launch_bounds__(256) void attn2_kernel(const unsigned* __restrict__ h2b, const float* __restrict__ atts,
                                                    const float* __restrict__ attd, float* __restrict__ as2,
                                                    float* __restrict__ ad2) {
  int n = (blockIdx.x * 256 + threadIdx.x) >> 5;
  int l = threadIdx.x & 31;
  unsigned u = h2b[n * 32 + l];
  float v0 = bfl(u), v1 = bfh(u);
  int f = l * 2;
  float s = v0 * atts[f] + v1 * atts[f + 1];
  float d = v0 * attd[f] + v1 * attd[f + 1];
#pragma unroll
  for (int off = 1; off < 32; off <<= 1) {
    s += __shfl_xor(s, off);
    d += __shfl_xor(d, off);
  }
  if (l == 0) { as2[n] = s; ad2[n] = d; }
}

// ---------------- fused e-compute + denom: per-node CSR walk, 16 lanes/node ----------------
// e1v[i] written contiguously; dst index is implicit (the CSR row).
__global__ __launch_bounds__(256) void ered1_kernel(const int* __restrict__ col, const int* __restrict__ rowptr,
                                                    const float4* __restrict__ as1v, const float4* __restrict__ ad1v,
                                                    float4* __restrict__ e1v, float4* __restrict__ di1v,
                                                    float4* __restrict__ es1v) {
  int n = blockIdx.x * 16 + (threadIdx.x >> 4);
  int sub = threadIdx.x & 15;
  int beg = rowptr[n], end = rowptr[n + 1];
  float4 ad = ad1v[n];
  float4 s = make_float4(0.f, 0.f, 0.f, 0.f);
  for (int i = beg + sub; i < end; i += 16) {
    float4 a = as1v[col[i]];
    float4 o;
    o.x = expf(lrelu(a.x + ad.x));
    o.y = expf(lrelu(a.y + ad.y));
    o.z = expf(lrelu(a.z + ad.z));
    o.w = expf(lrelu(a.w + ad.w));
    e1v[i] = o;
    s.x += o.x; s.y += o.y; s.z += o.z; s.w += o.w;
  }
#pragma unroll
  for (int off = 1; off < 16; off <<= 1) {
    s.x += __shfl_xor(s.x, off);
    s.y += __shfl_xor(s.y, off);
    s.z += __shfl_xor(s.z, off);
    s.w += __shfl_xor(s.w, off);
  }
  if (sub == 0) {
    float4 a = as1v[n];
    float4 es;
    es.x = expf(lrelu(a.x + ad.x));
    es.y = expf(lrelu(a.y + ad.y));
    es.z = expf(lrelu(a.z + ad.z));
    es.w = expf(lrelu(a.w + ad.w));
    es1v[n] = es;
    di1v[n] = make_float4(1.f / (s.x + es.x), 1.f / (s.y + es.y), 1.f / (s.z + es.z), 1.f / (s.w + es.w));
  }
}

__global__ __launch_bounds__(256) void ered2_kernel(const int* __restrict__ col, const int* __restrict__ rowptr,
                                                    const float* __restrict__ as2, const float* __restrict__ ad2,
                                                    float* __restrict__ e2a, float* __restrict__ di2a,
                                                    float* __restrict__ es2a) {
  int n = blockIdx.x * 16 + (threadIdx.x >> 4);
  int sub = threadIdx.x & 15;
  int beg = rowptr[n], end = rowptr[n + 1];
  float ad = ad2[n];
  float s = 0.f;
  for (int i = beg + sub; i < end; i += 16) {
    float o = expf(lrelu(as2[col[i]] + ad));
    e2a[i] = o;
    s += o;
  }
#pragma unroll
  for (int off = 1; off < 16; off <<= 1) s += __shfl_xor(s, off);
  if (sub == 0) {
    float es = expf(lrelu(as2[n] + ad));
    es2a[n] = es;
    di2a[n] = 1.f / (s + es);
  }
}

// ---------------- layer-1 gather: bf16 rows, 4 rows per wave-load ----------------
__global__ __launch_bounds__(256) void agg1_kernel(const uint4* __restrict__ h1b4, const float* __restrict__ e1,
                                                   const int* __restrict__ rowptr, const int* __restrict__ col,
                                                   const float* __restrict__ di1, const float* __restrict__ es1,
                                                   const float4* __restrict__ b1v, uint4* __restrict__ h1eb4) {
  int n = (blockIdx.x * 256 + threadIdx.x) >> 6;
  int lane = threadIdx.x & 63;
  int slot = lane >> 4;  // 0..3
  int fo = lane & 15;    // feats fo*8 .. fo*8+7
  int h = fo >> 2;       // head for these 8 feats
  int beg = rowptr[n], end = rowptr[n + 1];

  float acc[8];
#pragma unroll
  for (int j = 0; j < 8; ++j) acc[j] = 0.f;

#define ACC_EDGE1(E)                                        \
  {                                                         \
    int src = col[E];                                       \
    float a = e1[(E) * 4 + h];                              \
    uint4 uu = h1b4[src * 16 + fo];                         \
    acc[0] += a * bfl(uu.x); acc[1] += a * bfh(uu.x);       \
    acc[2] += a * bfl(uu.y); acc[3] += a * bfh(uu.y);       \
    acc[4] += a * bfl(uu.z); acc[5] += a * bfh(uu.z);       \
    acc[6] += a * bfl(uu.w); acc[7] += a * bfh(uu.w);       \
  }

  int i = beg;
  for (; i + 16 <= end; i += 16) {
#pragma unroll
    for (int u = 0; u < 4; ++u) ACC_EDGE1(i + u * 4 + slot);
  }
  for (; i + 4 <= end; i += 4) ACC_EDGE1(i + slot);
  int rem = end - i;
  if (slot < rem) ACC_EDGE1(i + slot);
  // self loop
  if (slot == 0) {
    float wv = es1[n * 4 + h];
    uint4 uu = h1b4[n * 16 + fo];
    acc[0] += wv * bfl(uu.x); acc[1] += wv * bfh(uu.x);
    acc[2] += wv * bfl(uu.y); acc[3] += wv * bfh(uu.y);
    acc[4] += wv * bfl(uu.z); acc[5] += wv * bfh(uu.z);
    acc[6] += wv * bfl(uu.w); acc[7] += wv * bfh(uu.w);
  }
#pragma unroll
  for (int j = 0; j < 8; ++j) {
    acc[j] += __shfl_xor(acc[j], 16);
    acc[j] += __shfl_xor(acc[j], 32);
  }
  if (slot == 0) {
    float dsc = di1[n * 4 + h];
    float4 b0 = b1v[fo * 2], b1 = b1v[fo * 2 + 1];
    float f0 = elu(acc[0] * dsc + b0.x), f1 = elu(acc[1] * dsc + b0.y);
    float f2 = elu(acc[2] * dsc + b0.z), f3 = elu(acc[3] * dsc + b0.w);
    float f4 = elu(acc[4] * dsc + b1.x), f5 = elu(acc[5] * dsc + b1.y);
    float f6 = elu(acc[6] * dsc + b1.z), f7 = elu(acc[7] * dsc + b1.w);
    uint4 o;
    o.x = pack2bf(f0, f1); o.y = pack2bf(f2, f3);
    o.z = pack2bf(f4, f5); o.w = pack2bf(f6, f7);
    h1eb4[n * 16 + fo] = o;
  }
#undef ACC_EDGE1
}

// ---------------- layer-2 gather + fused global add pool: bf16 rows, 8 rows per wave-load ----------------
__global__ __launch_bounds__(256) void agg2_kernel(const uint4* __restrict__ h2b4, const float* __restrict__ e2a,
                                                   const int* __restrict__ rowptr, const int* __restrict__ col,
                                                   const float* __restrict__ di2a, const float* __restrict__ es2a,
                                                   const float4* __restrict__ b2v, float* __restrict__ pooled) {
  __shared__ float red[4][64];
  int n = (blockIdx.x * 256 + threadIdx.x) >> 6;
  int lane = threadIdx.x & 63;
  int wid = threadIdx.x >> 6;
  int slot = lane >> 3;  // 0..7
  int fo = lane & 7;     // feats fo*8 .. fo*8+7
  int beg = rowptr[n], end = rowptr[n + 1];

  float acc[8];
#pragma unroll
  for (int j = 0; j < 8; ++j) acc[j] = 0.f;

#define ACC_EDGE2(E)                                        \
  {                                                         \
    int src = col[E];                                       \
    float a = e2a[E];                                       \
    uint4 uu = h2b4[src * 8 + fo];                          \
    acc[0] += a * bfl(uu.x); acc[1] += a * bfh(uu.x);       \
    acc[2] += a * bfl(uu.y); acc[3] += a * bfh(uu.y);       \
    acc[4] += a * bfl(uu.z); acc[5] += a * bfh(uu.z);       \
    acc[6] += a * bfl(uu.w); acc[7] += a * bfh(uu.w);       \
  }

  int i = beg;
  for (; i + 32 <= end; i += 32) {
#pragma unroll
    for (int u = 0; u < 4; ++u) ACC_EDGE2(i + u * 8 + slot);
  }
  for (; i + 8 <= end; i += 8) ACC_EDGE2(i + slot);
  int rem = end - i;
  if (slot < rem) ACC_EDGE2(i + slot);
  // self loop
  if (slot == 0) {
    float wv = es2a[n];
    uint4 uu = h2b4[n * 8 + fo];
    acc[0] += wv * bfl(uu.x); acc[1] += wv * bfh(uu.x);
    acc[2] += wv * bfl(uu.y); acc[3] += wv * bfh(uu.y);
    acc[4] += wv * bfl(uu.z); acc[5] += wv * bfh(uu.z);
    acc[6] += wv * bfl(uu.w); acc[7] += wv * bfh(uu.w);
  }
#pragma unroll
  for (int j = 0; j < 8; ++j) {
    acc[j] += __shfl_xor(acc[j], 8);
    acc[j] += __shfl_xor(acc[j], 16);
    acc[j] += __shfl_xor(acc[j], 32);
  }
  if (slot == 0) {
    float dsc = di2a[n];
    float4 b0 = b2v[fo * 2], b1 = b2v[fo * 2 + 1];
    red[wid][fo * 8 + 0] = elu(acc[0] * dsc + b0.x);
    red[wid][fo * 8 + 1] = elu(acc[1] * dsc + b0.y);
    red[wid][fo * 8 + 2] = elu(acc[2] * dsc + b0.z);
    red[wid][fo * 8 + 3] = elu(acc[3] * dsc + b0.w);
    red[wid][fo * 8 + 4] = elu(acc[4] * dsc + b1.x);
    red[wid][fo * 8 + 5] = elu(acc[5] * dsc + b1.y);
    red[wid][fo * 8 + 6] = elu(acc[6] * dsc + b1.z);
    red[wid][fo * 8 + 7] = elu(acc[7] * dsc + b1.w);
  }
  __syncthreads();
  if (threadIdx.x < 64) {
    float sum = red[0][threadIdx.x] + red[1][threadIdx.x] + red[2][threadIdx.x] + red[3][threadIdx.x];
    atomicAdd(&pooled[(blockIdx.x & 63) * 64 + threadIdx.x], sum);
  }
#undef ACC_EDGE2
}

// ---------------- final: reduce pooled stripes + pooled@Wl+bl ----------------
__global__ void final_kernel(const float* __restrict__ pooledS, const float* __restrict__ Wl,
                             const float* __restrict__ bl, float* __restrict__ out) {
  __shared__ float p[64];
  int t = threadIdx.x;
  float v = 0.f;
  for (int k = 0; k < 64; ++k) v += pooledS[k * 64 + t];
  p[t] = v;
  out[t] = v;
  __syncthreads();
  if (t < 2) {
    float s = bl[t];
    for (int k = 0; k < 64; ++k) s += p[k] * Wl[k * 2 + t];
    out[64 + t] = s;
  }
}

extern "C" void kernel_launch(void* const* d_in, const int* in_sizes, int n_in,
                              void* d_out, int out_size, void* d_ws, size_t ws_size,
                              hipStream_t stream) {
  (void)in_sizes; (void)n_in; (void)out_size; (void)ws_size;
  const float* x     = (const float*)d_in[0];
  const int*   ei    = (const int*)d_in[1];
  const float* W1    = (const float*)d_in[2];
  const float* atts1 = (const float*)d_in[3];
  const float* attd1 = (const float*)d_in[4];
  const float* b1    = (const float*)d_in[5];
  const float* W2    = (const float*)d_in[6];
  const float* atts2 = (const float*)d_in[7];
  const float* attd2 = (const float*)d_in[8];
  const float* b2    = (const float*)d_in[9];
  const float* Wl    = (const float*)d_in[10];
  const float* bl    = (const float*)d_in[11];
  float* out = (float*)d_out;

  char* w = (char*)d_ws;
  unsigned* h1b  = (unsigned*)w; w += (size_t)N_NODES * 128 * 2;  // 12.8 MB bf16
  unsigned* h1eb = (unsigned*)w; w += (size_t)N_NODES * 128 * 2;  // 12.8 MB bf16
  unsigned* h2b  = (unsigned*)w; w += (size_t)N_NODES * 64 * 2;   // 6.4 MB bf16
  float* e1   = (float*)w; w += (size_t)N_EDGES * 16;             // 12.8 MB
  float* e2a  = (float*)w; w += (size_t)N_EDGES * 4;              // 3.2 MB
  float* as1  = (float*)w; w += (size_t)N_NODES * 16;
  float* ad1  = (float*)w; w += (size_t)N_NODES * 16;
  float* di1  = (float*)w; w += (size_t)N_NODES * 16;
  float* es1  = (float*)w; w += (size_t)N_NODES * 16;
  float* as2  = (float*)w; w += (size_t)N_NODES * 4;
  float* ad2  = (float*)w; w += (size_t)N_NODES * 4;
  float* di2a = (float*)w; w += (size_t)N_NODES * 4;
  float* es2a = (float*)w; w += (size_t)N_NODES * 4;
  int* deg    = (int*)w; w += (size_t)N_NODES * 4;
  int* cursor = (int*)w; w += (size_t)N_NODES * 4;
  float* pooled = (float*)w; w += 64 * 64 * 4;                    // 64 stripes x 64
  int* rowptr = (int*)w; w += (size_t)(N_NODES + 1) * 4 + 12;
  int* col    = (int*)w; w += (size_t)N_EDGES * 4;
  int* blocksum = (int*)w; w += 256 * 4;
  int* blockoff = (int*)w; w += 256 * 4;

  // zero deg + cursor + pooled (contiguous)
  hipMemsetAsync(deg, 0, (size_t)N_NODES * 8 + 64 * 64 * 4, stream);

  hist_kernel<<<(N_EDGES + 255) / 256, 256, 0, stream>>>(ei, deg);
  scan_part_kernel<<<SCAN_BLOCKS, 256, 0, stream>>>(deg, rowptr, blocksum);
  scan_top_kernel<<<1, 256, 0, stream>>>(blocksum, blockoff);
  scan_add_kernel<<<SCAN_BLOCKS, 256, 0, stream>>>(blockoff, rowptr);
  scatter_kernel<<<(N_EDGES + 255) / 256, 256, 0, stream>>>(ei, rowptr, cursor, col);

  gemm_kernel<128, false><<<(N_NODES + 63) / 64, 256, 0, stream>>>(x, W1, h1b);
  attn1_kernel<<<N_NODES / 4, 256, 0, stream>>>(h1b, atts1, attd1, as1, ad1);
  ered1_kernel<<<(N_NODES + 15) / 16, 256, 0, stream>>>(col, rowptr, (const float4*)as1, (const float4*)ad1,
                                                        (float4*)e1, (float4*)di1, (float4*)es1);
  agg1_kernel<<<N_NODES / 4, 256, 0, stream>>>((const uint4*)h1b, e1, rowptr, col, di1, es1,
                                               (const float4*)b1, (uint4*)h1eb);

  gemm_kernel<64, true><<<(N_NODES + 63) / 64, 256, 0, stream>>>(h1eb, W2, h2b);
  attn2_kernel<<<N_NODES / 8, 256, 0, stream>>>(h2b, atts2, attd2, as2, ad2);
  ered2_kernel<<<(N_NODES + 15) / 16, 256, 0, stream>>>(col, rowptr, as2, ad2, e2a, di2a, es2a);
  agg2_kernel<<<N_NODES / 4, 256, 0, stream>>>((const uint4*)h2b, e2a, rowptr, col, di2a, es2a,
                                               (const float4*)b2, pooled);

  final_kernel<<<1, 64, 0, stream>>>(pooled, Wl, bl, out);
}

// Round 8
// 298.589 us; speedup vs baseline: 2.6669x; 1.1089x over previous
//
#include <hip/hip_runtime.h>

#define N_NODES 50000
#define N_EDGES 800000
#define SCAN_BLOCKS ((N_NODES + 255) / 256)  // 196

__device__ __forceinline__ float lrelu(float x) { return x > 0.f ? x : 0.2f * x; }
__device__ __forceinline__ float elu(float x) { return x > 0.f ? x : expf(x) - 1.f; }

// bf16 helpers: lo/hi halves of a uint holding 2 consecutive bf16 elements
__device__ __forceinline__ float bfl(unsigned u) { return __uint_as_float(u << 16); }
__device__ __forceinline__ float bfh(unsigned u) { return __uint_as_float(u & 0xffff0000u); }
__device__ __forceinline__ unsigned f2bf_rn(float x) {
  unsigned u = __float_as_uint(x);
  return (u + 0x7fffu + ((u >> 16) & 1u)) >> 16;
}
__device__ __forceinline__ unsigned pack2bf(float a, float b) {
  return f2bf_rn(a) | (f2bf_rn(b) << 16);
}

// ---------------- CSR build ----------------
// hist also records each edge's rank within its dst (atomic return value),
// so the scatter pass needs no atomics at all.
__global__ __launch_bounds__(256) void hist_kernel(const int* __restrict__ ei, int* __restrict__ deg,
                                                   int* __restrict__ rank) {
  int e = blockIdx.x * 256 + threadIdx.x;
  if (e < N_EDGES) rank[e] = atomicAdd(&deg[ei[N_EDGES + e]], 1);
}

__device__ __forceinline__ int block_excl_scan(int v, int* total_out) {
  int lane = threadIdx.x & 63;
  int wid = threadIdx.x >> 6;
  int x = v;
#pragma unroll
  for (int off = 1; off < 64; off <<= 1) {
    int u = __shfl_up(x, off);
    if (lane >= off) x += u;
  }
  __shared__ int wsum[4];
  if (lane == 63) wsum[wid] = x;
  __syncthreads();
  int add = 0;
#pragma unroll
  for (int k = 0; k < 4; ++k)
    if (k < wid) add += wsum[k];
  if (total_out) *total_out = wsum[0] + wsum[1] + wsum[2] + wsum[3];
  return x + add - v;
}

__global__ __launch_bounds__(256) void scan_part_kernel(const int* __restrict__ deg, int* __restrict__ rowptr,
                                                        int* __restrict__ blocksum) {
  int g = blockIdx.x * 256 + threadIdx.x;
  int v = (g < N_NODES) ? deg[g] : 0;
  int total;
  int ex = block_excl_scan(v, &total);
  if (g < N_NODES) rowptr[g] = ex;
  if (threadIdx.x == 0) blocksum[blockIdx.x] = total;
}

__global__ __launch_bounds__(256) void scan_top_kernel(const int* __restrict__ blocksum, int* __restrict__ blockoff) {
  int t = threadIdx.x;
  int v = (t < SCAN_BLOCKS) ? blocksum[t] : 0;
  int ex = block_excl_scan(v, nullptr);
  if (t < SCAN_BLOCKS) blockoff[t] = ex;
}

__global__ __launch_bounds__(256) void scan_add_kernel(const int* __restrict__ blockoff, int* __restrict__ rowptr) {
  int g = blockIdx.x * 256 + threadIdx.x;
  if (g < N_NODES) rowptr[g] += blockoff[g >> 8];
  if (g == 0) rowptr[N_NODES] = N_EDGES;
}

// atomic-free scatter: position = rowptr[dst] + rank[e]
__global__ __launch_bounds__(256) void scatter_kernel(const int* __restrict__ ei, const int* __restrict__ rowptr,
                                                      const int* __restrict__ rank, int* __restrict__ col) {
  int e = blockIdx.x * 256 + threadIdx.x;
  if (e < N_EDGES) {
    int d = ei[N_EDGES + e];
    col[rowptr[d] + rank[e]] = ei[e];
  }
}

// ---------------- GEMM: Yb[N,COLS](bf16) = A[N,128] @ W[128,COLS]; A fp32 or bf16 ----------------
template <int COLS, bool ABF16>
__global__ __launch_bounds__(256) void gemm_kernel(const void* __restrict__ Ap, const float* __restrict__ W,
                                                   unsigned* __restrict__ Yb) {
  constexpr int CPT = COLS / 16;  // cols per thread (8 or 4)
  __shared__ float ws[64 * COLS];
  __shared__ float xs[64 * 64];
  int t = threadIdx.x;
  int rbase = blockIdx.x * 64;
  int tx = t & 15, ty = t >> 4;
  float acc[4][CPT];
#pragma unroll
  for (int r = 0; r < 4; ++r)
#pragma unroll
    for (int c = 0; c < CPT; ++c) acc[r][c] = 0.f;

  const float4* W4 = (const float4*)W;
  for (int kt = 0; kt < 2; ++kt) {
    float4* ws4 = (float4*)ws;
    for (int i = t; i < 64 * COLS / 4; i += 256) ws4[i] = W4[kt * 16 * COLS + i];
    if constexpr (ABF16) {
      const uint4* A4 = (const uint4*)Ap;  // row = 128 bf16 = 16 uint4
      for (int i = t; i < 512; i += 256) {
        int row = i >> 3, q = i & 7;
        int gr = rbase + row; if (gr >= N_NODES) gr = N_NODES - 1;
        uint4 u = A4[gr * 16 + kt * 8 + q];
        float4 lo = make_float4(bfl(u.x), bfh(u.x), bfl(u.y), bfh(u.y));
        float4 hi = make_float4(bfl(u.z), bfh(u.z), bfl(u.w), bfh(u.w));
        float4* dst = (float4*)&xs[row * 64 + q * 8];
        dst[0] = lo; dst[1] = hi;
      }
    } else {
      const float4* A4 = (const float4*)Ap;
      float4* xs4 = (float4*)xs;
      for (int i = t; i < 1024; i += 256) {
        int row = i >> 4, kc = i & 15;
        int gr = rbase + row; if (gr >= N_NODES) gr = N_NODES - 1;
        xs4[i] = A4[gr * 32 + kt * 16 + kc];
      }
    }
    __syncthreads();
#pragma unroll 8
    for (int k = 0; k < 64; ++k) {
      float xr[4];
#pragma unroll
      for (int r = 0; r < 4; ++r) xr[r] = xs[(ty * 4 + r) * 64 + k];
#pragma unroll
      for (int c4 = 0; c4 < CPT / 4; ++c4) {
        float4 wv = *(const float4*)&ws[k * COLS + tx * CPT + c4 * 4];
#pragma unroll
        for (int r = 0; r < 4; ++r) {
          acc[r][c4 * 4 + 0] += xr[r] * wv.x;
          acc[r][c4 * 4 + 1] += xr[r] * wv.y;
          acc[r][c4 * 4 + 2] += xr[r] * wv.z;
          acc[r][c4 * 4 + 3] += xr[r] * wv.w;
        }
      }
    }
    __syncthreads();
  }
#pragma unroll
  for (int r = 0; r < 4; ++r) {
    int row = rbase + ty * 4 + r;
    if (row < N_NODES) {
      if constexpr (CPT == 8) {
        uint4 o;
        o.x = pack2bf(acc[r][0], acc[r][1]);
        o.y = pack2bf(acc[r][2], acc[r][3]);
        o.z = pack2bf(acc[r][4], acc[r][5]);
        o.w = pack2bf(acc[r][6], acc[r][7]);
        ((uint4*)Yb)[row * 16 + tx] = o;
      } else {
        uint2 o;
        o.x = pack2bf(acc[r][0], acc[r][1]);
        o.y = pack2bf(acc[r][2], acc[r][3]);
        ((uint2*)Yb)[row * 16 + tx] = o;
      }
    }
  }
}

// ---------------- attention dot products (bf16 inputs) ----------------
__global__ __launch_bounds__(256) void attn1_kernel(const unsigned* __restrict__ h1b, const float* __restrict__ atts,
                                                    const float* __restrict__ attd, float* __restrict__ as1,
                                                    float* __restrict__ ad1) {
  int n = (blockIdx.x * 256 + threadIdx.x) >> 6;
  int lane = threadIdx.x & 63;
  unsigned u = h1b[n * 64 + lane];
  float v0 = bfl(u), v1 = bfh(u);
  int f = lane * 2;
  float s = v0 * atts[f] + v1 * atts[f + 1];
  float d = v0 * attd[f] + v1 * attd[f + 1];
#pragma unroll
  for (int off = 1; off < 16; off <<= 1) {
    s += __shfl_xor(s, off);
    d += __shfl_xor(d, off);
  }
  if ((lane & 15) == 0) {
    int h = lane >> 4;
    as1[n * 4 + h] = s;
    ad1[n * 4 + h] = d;
  }
}

__global__ __launch_bounds__(256) void attn2_kernel(const unsigned* __restrict__ h2b, const float* __restrict__ atts,
                                                    const float* __restrict__ attd, float* __restrict__ as2,
                                                    float* __restrict__ ad2) {
  int n = (blockIdx.x * 256 + threadIdx.x) >> 5;
  int l = threadIdx.x & 31;
  unsigned u = h2b[n * 32 + l];
  float v0 = bfl(u), v1 = bfh(u);
  int f = l * 2;
  float s = v0 * atts[f] + v1 * atts[f + 1];
  float d = v0 * attd[f] + v1 * attd[f + 1];
#pragma unroll
  for (int off = 1; off < 32; off <<= 1) {
    s += __shfl_xor(s, off);
    d += __shfl_xor(d, off);
  }
  if (l == 0) { as2[n] = s; ad2[n] = d; }
}

// ---------------- fused e-compute + denom: per-node CSR walk, 16 lanes/node ----------------
__global__ __launch_bounds__(256) void ered1_kernel(const int* __restrict__ col, const int* __restrict__ rowptr,
                                                    const float4* __restrict__ as1v, const float4* __restrict__ ad1v,
                                                    float4* __restrict__ e1v, float4* __restrict__ di1v,
                                                    float4* __restrict__ es1v) {
  int n = blockIdx.x * 16 + (threadIdx.x >> 4);
  int sub = threadIdx.x & 15;
  int beg = rowptr[n], end = rowptr[n + 1];
  float4 ad = ad1v[n];
  float4 s = make_float4(0.f, 0.f, 0.f, 0.f);
  for (int i = beg + sub; i < end; i += 16) {
    float4 a = as1v[col[i]];
    float4 o;
    o.x = expf(lrelu(a.x + ad.x));
    o.y = expf(lrelu(a.y + ad.y));
    o.z = expf(lrelu(a.z + ad.z));
    o.w = expf(lrelu(a.w + ad.w));
    e1v[i] = o;
    s.x += o.x; s.y += o.y; s.z += o.z; s.w += o.w;
  }
#pragma unroll
  for (int off = 1; off < 16; off <<= 1) {
    s.x += __shfl_xor(s.x, off);
    s.y += __shfl_xor(s.y, off);
    s.z += __shfl_xor(s.z, off);
    s.w += __shfl_xor(s.w, off);
  }
  if (sub == 0) {
    float4 a = as1v[n];
    float4 es;
    es.x = expf(lrelu(a.x + ad.x));
    es.y = expf(lrelu(a.y + ad.y));
    es.z = expf(lrelu(a.z + ad.z));
    es.w = expf(lrelu(a.w + ad.w));
    es1v[n] = es;
    di1v[n] = make_float4(1.f / (s.x + es.x), 1.f / (s.y + es.y), 1.f / (s.z + es.z), 1.f / (s.w + es.w));
  }
}

__global__ __launch_bounds__(256) void ered2_kernel(const int* __restrict__ col, const int* __restrict__ rowptr,
                                                    const float* __restrict__ as2, const float* __restrict__ ad2,
                                                    float* __restrict__ e2a, float* __restrict__ di2a,
                                                    float* __restrict__ es2a) {
  int n = blockIdx.x * 16 + (threadIdx.x >> 4);
  int sub = threadIdx.x & 15;
  int beg = rowptr[n], end = rowptr[n + 1];
  float ad = ad2[n];
  float s = 0.f;
  for (int i = beg + sub; i < end; i += 16) {
    float o = expf(lrelu(as2[col[i]] + ad));
    e2a[i] = o;
    s += o;
  }
#pragma unroll
  for (int off = 1; off < 16; off <<= 1) s += __shfl_xor(s, off);
  if (sub == 0) {
    float es = expf(lrelu(as2[n] + ad));
    es2a[n] = es;
    di2a[n] = 1.f / (s + es);
  }
}

// ---------------- layer-1 gather: bf16 rows, 4 rows per wave-load ----------------
__global__ __launch_bounds__(256) void agg1_kernel(const uint4* __restrict__ h1b4, const float* __restrict__ e1,
                                                   const int* __restrict__ rowptr, const int* __restrict__ col,
                                                   const float* __restrict__ di1, const float* __restrict__ es1,
                                                   const float4* __restrict__ b1v, uint4* __restrict__ h1eb4) {
  int n = (blockIdx.x * 256 + threadIdx.x) >> 6;
  int lane = threadIdx.x & 63;
  int slot = lane >> 4;  // 0..3
  int fo = lane & 15;    // feats fo*8 .. fo*8+7
  int h = fo >> 2;       // head for these 8 feats
  int beg = rowptr[n], end = rowptr[n + 1];

  float acc[8];
#pragma unroll
  for (int j = 0; j < 8; ++j) acc[j] = 0.f;

#define ACC_EDGE1(E)                                        \
  {                                                         \
    int src = col[E];                                       \
    float a = e1[(E) * 4 + h];                              \
    uint4 uu = h1b4[src * 16 + fo];                         \
    acc[0] += a * bfl(uu.x); acc[1] += a * bfh(uu.x);       \
    acc[2] += a * bfl(uu.y); acc[3] += a * bfh(uu.y);       \
    acc[4] += a * bfl(uu.z); acc[5] += a * bfh(uu.z);       \
    acc[6] += a * bfl(uu.w); acc[7] += a * bfh(uu.w);       \
  }

  int i = beg;
  for (; i + 16 <= end; i += 16) {
#pragma unroll
    for (int u = 0; u < 4; ++u) ACC_EDGE1(i + u * 4 + slot);
  }
  for (; i + 4 <= end; i += 4) ACC_EDGE1(i + slot);
  int rem = end - i;
  if (slot < rem) ACC_EDGE1(i + slot);
  // self loop
  if (slot == 0) {
    float wv = es1[n * 4 + h];
    uint4 uu = h1b4[n * 16 + fo];
    acc[0] += wv * bfl(uu.x); acc[1] += wv * bfh(uu.x);
    acc[2] += wv * bfl(uu.y); acc[3] += wv * bfh(uu.y);
    acc[4] += wv * bfl(uu.z); acc[5] += wv * bfh(uu.z);
    acc[6] += wv * bfl(uu.w); acc[7] += wv * bfh(uu.w);
  }
#pragma unroll
  for (int j = 0; j < 8; ++j) {
    acc[j] += __shfl_xor(acc[j], 16);
    acc[j] += __shfl_xor(acc[j], 32);
  }
  if (slot == 0) {
    float dsc = di1[n * 4 + h];
    float4 b0 = b1v[fo * 2], b1 = b1v[fo * 2 + 1];
    float f0 = elu(acc[0] * dsc + b0.x), f1 = elu(acc[1] * dsc + b0.y);
    float f2 = elu(acc[2] * dsc + b0.z), f3 = elu(acc[3] * dsc + b0.w);
    float f4 = elu(acc[4] * dsc + b1.x), f5 = elu(acc[5] * dsc + b1.y);
    float f6 = elu(acc[6] * dsc + b1.z), f7 = elu(acc[7] * dsc + b1.w);
    uint4 o;
    o.x = pack2bf(f0, f1); o.y = pack2bf(f2, f3);
    o.z = pack2bf(f4, f5); o.w = pack2bf(f6, f7);
    h1eb4[n * 16 + fo] = o;
  }
#undef ACC_EDGE1
}

// ---------------- layer-2 gather + fused global add pool: bf16 rows, 8 rows per wave-load ----------------
__global__ __launch_bounds__(256) void agg2_kernel(const uint4* __restrict__ h2b4, const float* __restrict__ e2a,
                                                   const int* __restrict__ rowptr, const int* __restrict__ col,
                                                   const float* __restrict__ di2a, const float* __restrict__ es2a,
                                                   const float4* __restrict__ b2v, float* __restrict__ pooled) {
  __shared__ float red[4][64];
  int n = (blockIdx.x * 256 + threadIdx.x) >> 6;
  int lane = threadIdx.x & 63;
  int wid = threadIdx.x >> 6;
  int slot = lane >> 3;  // 0..7
  int fo = lane & 7;     // feats fo*8 .. fo*8+7
  int beg = rowptr[n], end = rowptr[n + 1];

  float acc[8];
#pragma unroll
  for (int j = 0; j < 8; ++j) acc[j] = 0.f;

#define ACC_EDGE2(E)                                        \
  {                                                         \
    int src = col[E];                                       \
    float a = e2a[E];                                       \
    uint4 uu = h2b4[src * 8 + fo];                          \
    acc[0] += a * bfl(uu.x); acc[1] += a * bfh(uu.x);       \
    acc[2] += a * bfl(uu.y); acc[3] += a * bfh(uu.y);       \
    acc[4] += a * bfl(uu.z); acc[5] += a * bfh(uu.z);       \
    acc[6] += a * bfl(uu.w); acc[7] += a * bfh(uu.w);       \
  }

  int i = beg;
  for (; i + 32 <= end; i += 32) {
#pragma unroll
    for (int u = 0; u < 4; ++u) ACC_EDGE2(i + u * 8 + slot);
  }
  for (; i + 8 <= end; i += 8) ACC_EDGE2(i + slot);
  int rem = end - i;
  if (slot < rem) ACC_EDGE2(i + slot);
  // self loop
  if (slot == 0) {
    float wv = es2a[n];
    uint4 uu = h2b4[n * 8 + fo];
    acc[0] += wv * bfl(uu.x); acc[1] += wv * bfh(uu.x);
    acc[2] += wv * bfl(uu.y); acc[3] += wv * bfh(uu.y);
    acc[4] += wv * bfl(uu.z); acc[5] += wv * bfh(uu.z);
    acc[6] += wv * bfl(uu.w); acc[7] += wv * bfh(uu.w);
  }
#pragma unroll
  for (int j = 0; j < 8; ++j) {
    acc[j] += __shfl_xor(acc[j], 8);
    acc[j] += __shfl_xor(acc[j], 16);
    acc[j] += __shfl_xor(acc[j], 32);
  }
  if (slot == 0) {
    float dsc = di2a[n];
    float4 b0 = b2v[fo * 2], b1 = b2v[fo * 2 + 1];
    red[wid][fo * 8 + 0] = elu(acc[0] * dsc + b0.x);
    red[wid][fo * 8 + 1] = elu(acc[1] * dsc + b0.y);
    red[wid][fo * 8 + 2] = elu(acc[2] * dsc + b0.z);
    red[wid][fo * 8 + 3] = elu(acc[3] * dsc + b0.w);
    red[wid][fo * 8 + 4] = elu(acc[4] * dsc + b1.x);
    red[wid][fo * 8 + 5] = elu(acc[5] * dsc + b1.y);
    red[wid][fo * 8 + 6] = elu(acc[6] * dsc + b1.z);
    red[wid][fo * 8 + 7] = elu(acc[7] * dsc + b1.w);
  }
  __syncthreads();
  if (threadIdx.x < 64) {
    float sum = red[0][threadIdx.x] + red[1][threadIdx.x] + red[2][threadIdx.x] + red[3][threadIdx.x];
    atomicAdd(&pooled[(blockIdx.x & 63) * 64 + threadIdx.x], sum);
  }
#undef ACC_EDGE2
}

// ---------------- final: reduce pooled stripes + pooled@Wl+bl ----------------
__global__ void final_kernel(const float* __restrict__ pooledS, const float* __restrict__ Wl,
                             const float* __restrict__ bl, float* __restrict__ out) {
  __shared__ float p[64];
  int t = threadIdx.x;
  float v = 0.f;
  for (int k = 0; k < 64; ++k) v += pooledS[k * 64 + t];
  p[t] = v;
  out[t] = v;
  __syncthreads();
  if (t < 2) {
    float s = bl[t];
    for (int k = 0; k < 64; ++k) s += p[k] * Wl[k * 2 + t];
    out[64 + t] = s;
  }
}

extern "C" void kernel_launch(void* const* d_in, const int* in_sizes, int n_in,
                              void* d_out, int out_size, void* d_ws, size_t ws_size,
                              hipStream_t stream) {
  (void)in_sizes; (void)n_in; (void)out_size; (void)ws_size;
  const float* x     = (const float*)d_in[0];
  const int*   ei    = (const int*)d_in[1];
  const float* W1    = (const float*)d_in[2];
  const float* atts1 = (const float*)d_in[3];
  const float* attd1 = (const float*)d_in[4];
  const float* b1    = (const float*)d_in[5];
  const float* W2    = (const float*)d_in[6];
  const float* atts2 = (const float*)d_in[7];
  const float* attd2 = (const float*)d_in[8];
  const float* b2    = (const float*)d_in[9];
  const float* Wl    = (const float*)d_in[10];
  const float* bl    = (const float*)d_in[11];
  float* out = (float*)d_out;

  char* w = (char*)d_ws;
  unsigned* h1b  = (unsigned*)w; w += (size_t)N_NODES * 128 * 2;  // 12.8 MB bf16
  unsigned* h1eb = (unsigned*)w; w += (size_t)N_NODES * 128 * 2;  // 12.8 MB bf16
  unsigned* h2b  = (unsigned*)w; w += (size_t)N_NODES * 64 * 2;   // 6.4 MB bf16
  float* e1   = (float*)w; w += (size_t)N_EDGES * 16;             // 12.8 MB
  float* e2a  = (float*)w; w += (size_t)N_EDGES * 4;              // 3.2 MB
  float* as1  = (float*)w; w += (size_t)N_NODES * 16;
  float* ad1  = (float*)w; w += (size_t)N_NODES * 16;
  float* di1  = (float*)w; w += (size_t)N_NODES * 16;
  float* es1  = (float*)w; w += (size_t)N_NODES * 16;
  float* as2  = (float*)w; w += (size_t)N_NODES * 4;
  float* ad2  = (float*)w; w += (size_t)N_NODES * 4;
  float* di2a = (float*)w; w += (size_t)N_NODES * 4;
  float* es2a = (float*)w; w += (size_t)N_NODES * 4;
  int* deg    = (int*)w; w += (size_t)N_NODES * 4;
  float* pooled = (float*)w; w += 64 * 64 * 4;                    // 64 stripes x 64
  int* rowptr = (int*)w; w += (size_t)(N_NODES + 1) * 4 + 12;
  int* col    = (int*)w; w += (size_t)N_EDGES * 4;
  int* rank   = (int*)w; w += (size_t)N_EDGES * 4;
  int* blocksum = (int*)w; w += 256 * 4;
  int* blockoff = (int*)w; w += 256 * 4;

  // zero deg + pooled (contiguous)
  hipMemsetAsync(deg, 0, (size_t)N_NODES * 4 + 64 * 64 * 4, stream);

  hist_kernel<<<(N_EDGES + 255) / 256, 256, 0, stream>>>(ei, deg, rank);
  scan_part_kernel<<<SCAN_BLOCKS, 256, 0, stream>>>(deg, rowptr, blocksum);
  scan_top_kernel<<<1, 256, 0, stream>>>(blocksum, blockoff);
  scan_add_kernel<<<SCAN_BLOCKS, 256, 0, stream>>>(blockoff, rowptr);
  scatter_kernel<<<(N_EDGES + 255) / 256, 256, 0, stream>>>(ei, rowptr, rank, col);

  gemm_kernel<128, false><<<(N_NODES + 63) / 64, 256, 0, stream>>>(x, W1, h1b);
  attn1_kernel<<<N_NODES / 4, 256, 0, stream>>>(h1b, atts1, attd1, as1, ad1);
  ered1_kernel<<<(N_NODES + 15) / 16, 256, 0, stream>>>(col, rowptr, (const float4*)as1, (const float4*)ad1,
                                                        (float4*)e1, (float4*)di1, (float4*)es1);
  agg1_kernel<<<N_NODES / 4, 256, 0, stream>>>((const uint4*)h1b, e1, rowptr, col, di1, es1,
                                               (const float4*)b1, (uint4*)h1eb);

  gemm_kernel<64, true><<<(N_NODES + 63) / 64, 256, 0, stream>>>(h1eb, W2, h2b);
  attn2_kernel<<<N_NODES / 8, 256, 0, stream>>>(h2b, atts2, attd2, as2, ad2);
  ered2_kernel<<<(N_NODES + 15) / 16, 256, 0, stream>>>(col, rowptr, as2, ad2, e2a, di2a, es2a);
  agg2_kernel<<<N_NODES / 4, 256, 0, stream>>>((const uint4*)h2b, e2a, rowptr, col, di2a, es2a,
                                               (const float4*)b2, pooled);

  final_kernel<<<1, 64, 0, stream>>>(pooled, Wl, bl, out);
}

// Round 9
// 296.655 us; speedup vs baseline: 2.6843x; 1.0065x over previous
//
#include <hip/hip_runtime.h>

#define N_NODES 50000
#define N_EDGES 800000
#define SCAN_BLOCKS ((N_NODES + 255) / 256)  // 196

__device__ __forceinline__ float lrelu(float x) { return x > 0.f ? x : 0.2f * x; }
__device__ __forceinline__ float elu(float x) { return x > 0.f ? x : expf(x) - 1.f; }

// bf16 helpers: lo/hi halves of a uint holding 2 consecutive bf16 elements
__device__ __forceinline__ float bfl(unsigned u) { return __uint_as_float(u << 16); }
__device__ __forceinline__ float bfh(unsigned u) { return __uint_as_float(u & 0xffff0000u); }
__device__ __forceinline__ unsigned f2bf_rn(float x) {
  unsigned u = __float_as_uint(x);
  return (u + 0x7fffu + ((u >> 16) & 1u)) >> 16;
}
__device__ __forceinline__ unsigned pack2bf(float a, float b) {
  return f2bf_rn(a) | (f2bf_rn(b) << 16);
}

// ---------------- CSR build ----------------
__global__ __launch_bounds__(256) void hist_kernel(const int* __restrict__ ei, int* __restrict__ deg,
                                                   int* __restrict__ rank) {
  int e = blockIdx.x * 256 + threadIdx.x;
  if (e < N_EDGES) rank[e] = atomicAdd(&deg[ei[N_EDGES + e]], 1);
}

__device__ __forceinline__ int block_excl_scan(int v, int* total_out) {
  int lane = threadIdx.x & 63;
  int wid = threadIdx.x >> 6;
  int x = v;
#pragma unroll
  for (int off = 1; off < 64; off <<= 1) {
    int u = __shfl_up(x, off);
    if (lane >= off) x += u;
  }
  __shared__ int wsum[4];
  if (lane == 63) wsum[wid] = x;
  __syncthreads();
  int add = 0;
#pragma unroll
  for (int k = 0; k < 4; ++k)
    if (k < wid) add += wsum[k];
  if (total_out) *total_out = wsum[0] + wsum[1] + wsum[2] + wsum[3];
  return x + add - v;
}

__global__ __launch_bounds__(256) void scan_part_kernel(const int* __restrict__ deg, int* __restrict__ rowptr,
                                                        int* __restrict__ blocksum) {
  int g = blockIdx.x * 256 + threadIdx.x;
  int v = (g < N_NODES) ? deg[g] : 0;
  int total;
  int ex = block_excl_scan(v, &total);
  if (g < N_NODES) rowptr[g] = ex;
  if (threadIdx.x == 0) blocksum[blockIdx.x] = total;
}

__global__ __launch_bounds__(256) void scan_top_kernel(const int* __restrict__ blocksum, int* __restrict__ blockoff) {
  int t = threadIdx.x;
  int v = (t < SCAN_BLOCKS) ? blocksum[t] : 0;
  int ex = block_excl_scan(v, nullptr);
  if (t < SCAN_BLOCKS) blockoff[t] = ex;
}

__global__ __launch_bounds__(256) void scan_add_kernel(const int* __restrict__ blockoff, int* __restrict__ rowptr) {
  int g = blockIdx.x * 256 + threadIdx.x;
  if (g < N_NODES) rowptr[g] += blockoff[g >> 8];
  if (g == 0) rowptr[N_NODES] = N_EDGES;
}

__global__ __launch_bounds__(256) void scatter_kernel(const int* __restrict__ ei, const int* __restrict__ rowptr,
                                                      const int* __restrict__ rank, int* __restrict__ col) {
  int e = blockIdx.x * 256 + threadIdx.x;
  if (e < N_EDGES) {
    int d = ei[N_EDGES + e];
    col[rowptr[d] + rank[e]] = ei[e];
  }
}

// ---------------- GEMM: Yb[N,COLS](bf16) = A[N,128] @ W[128,COLS]; A fp32 or bf16 ----------------
// LDS layouts tuned for bank-conflict-free reads:
//   ws: swizzled [k][c4][tx] float4 slots -> compute reads hit 16 consecutive float4s (2-way, free)
//   xs: row stride 68 floats (padded)     -> broadcast reads land on banks {0,16} (2-way, free)
#define XS_STRIDE 68
template <int COLS, bool ABF16>
__global__ __launch_bounds__(256) void gemm_kernel(const void* __restrict__ Ap, const float* __restrict__ W,
                                                   unsigned* __restrict__ Yb) {
  constexpr int CPT = COLS / 16;   // cols per thread (8 or 4)
  constexpr int G = COLS / 4;      // float4 groups per k-row (32 or 16)
  __shared__ float ws[64 * COLS];
  __shared__ float xs[64 * XS_STRIDE];
  int t = threadIdx.x;
  int rbase = blockIdx.x * 64;
  int tx = t & 15, ty = t >> 4;
  float acc[4][CPT];
#pragma unroll
  for (int r = 0; r < 4; ++r)
#pragma unroll
    for (int c = 0; c < CPT; ++c) acc[r][c] = 0.f;

  const float4* W4 = (const float4*)W;
  float4* ws4 = (float4*)ws;
  for (int kt = 0; kt < 2; ++kt) {
    // ws staging with swizzle: original col group g = txg*(CPT/4) + c4g
    for (int i = t; i < 64 * G; i += 256) {
      int k = i / G;
      int g = i - k * G;
      int c4g = g & (CPT / 4 - 1);
      int txg = g / (CPT / 4);
      ws4[k * G + c4g * 16 + txg] = W4[kt * 16 * COLS + i];
    }
    if constexpr (ABF16) {
      const uint4* A4 = (const uint4*)Ap;  // row = 128 bf16 = 16 uint4
      for (int i = t; i < 512; i += 256) {
        int row = i >> 3, q = i & 7;
        int gr = rbase + row; if (gr >= N_NODES) gr = N_NODES - 1;
        uint4 u = A4[gr * 16 + kt * 8 + q];
        float4 lo = make_float4(bfl(u.x), bfh(u.x), bfl(u.y), bfh(u.y));
        float4 hi = make_float4(bfl(u.z), bfh(u.z), bfl(u.w), bfh(u.w));
        float4* dst = (float4*)&xs[row * XS_STRIDE + q * 8];
        dst[0] = lo; dst[1] = hi;
      }
    } else {
      const float4* A4 = (const float4*)Ap;
      for (int i = t; i < 1024; i += 256) {
        int row = i >> 4, kc = i & 15;
        int gr = rbase + row; if (gr >= N_NODES) gr = N_NODES - 1;
        *(float4*)&xs[row * XS_STRIDE + kc * 4] = A4[gr * 32 + kt * 16 + kc];
      }
    }
    __syncthreads();
#pragma unroll 8
    for (int k = 0; k < 64; ++k) {
      float xr[4];
#pragma unroll
      for (int r = 0; r < 4; ++r) xr[r] = xs[(ty * 4 + r) * XS_STRIDE + k];
#pragma unroll
      for (int c4 = 0; c4 < CPT / 4; ++c4) {
        float4 wv = ws4[k * G + c4 * 16 + tx];
#pragma unroll
        for (int r = 0; r < 4; ++r) {
          acc[r][c4 * 4 + 0] += xr[r] * wv.x;
          acc[r][c4 * 4 + 1] += xr[r] * wv.y;
          acc[r][c4 * 4 + 2] += xr[r] * wv.z;
          acc[r][c4 * 4 + 3] += xr[r] * wv.w;
        }
      }
    }
    __syncthreads();
  }
#pragma unroll
  for (int r = 0; r < 4; ++r) {
    int row = rbase + ty * 4 + r;
    if (row < N_NODES) {
      if constexpr (CPT == 8) {
        uint4 o;
        o.x = pack2bf(acc[r][0], acc[r][1]);
        o.y = pack2bf(acc[r][2], acc[r][3]);
        o.z = pack2bf(acc[r][4], acc[r][5]);
        o.w = pack2bf(acc[r][6], acc[r][7]);
        ((uint4*)Yb)[row * 16 + tx] = o;
      } else {
        uint2 o;
        o.x = pack2bf(acc[r][0], acc[r][1]);
        o.y = pack2bf(acc[r][2], acc[r][3]);
        ((uint2*)Yb)[row * 16 + tx] = o;
      }
    }
  }
}

// ---------------- attention dot products (bf16 inputs) ----------------
__global__ __launch_bounds__(256) void attn1_kernel(const unsigned* __restrict__ h1b, const float* __restrict__ atts,
                                                    const float* __restrict__ attd, float* __restrict__ as1,
                                                    float* __restrict__ ad1) {
  int n = (blockIdx.x * 256 + threadIdx.x) >> 6;
  int lane = threadIdx.x & 63;
  unsigned u = h1b[n * 64 + lane];
  float v0 = bfl(u), v1 = bfh(u);
  int f = lane * 2;
  float s = v0 * atts[f] + v1 * atts[f + 1];
  float d = v0 * attd[f] + v1 * attd[f + 1];
#pragma unroll
  for (int off = 1; off < 16; off <<= 1) {
    s += __shfl_xor(s, off);
    d += __shfl_xor(d, off);
  }
  if ((lane & 15) == 0) {
    int h = lane >> 4;
    as1[n * 4 + h] = s;
    ad1[n * 4 + h] = d;
  }
}

__global__ __launch_bounds__(256) void attn2_kernel(const unsigned* __restrict__ h2b, const float* __restrict__ atts,
                                                    const float* __restrict__ attd, float* __restrict__ as2,
                                                    float* __restrict__ ad2) {
  int n = (blockIdx.x * 256 + threadIdx.x) >> 5;
  int l = threadIdx.x & 31;
  unsigned u = h2b[n * 32 + l];
  float v0 = bfl(u), v1 = bfh(u);
  int f = l * 2;
  float s = v0 * atts[f] + v1 * atts[f + 1];
  float d = v0 * attd[f] + v1 * attd[f + 1];
#pragma unroll
  for (int off = 1; off < 32; off <<= 1) {
    s += __shfl_xor(s, off);
    d += __shfl_xor(d, off);
  }
  if (l == 0) { as2[n] = s; ad2[n] = d; }
}

// ---------------- fused e-compute + denom: per-node CSR walk, 16 lanes/node ----------------
__global__ __launch_bounds__(256) void ered1_kernel(const int* __restrict__ col, const int* __restrict__ rowptr,
                                                    const float4* __restrict__ as1v, const float4* __restrict__ ad1v,
                                                    float4* __restrict__ e1v, float4* __restrict__ di1v,
                                                    float4* __restrict__ es1v) {
  int n = blockIdx.x * 16 + (threadIdx.x >> 4);
  int sub = threadIdx.x & 15;
  int beg = rowptr[n], end = rowptr[n + 1];
  float4 ad = ad1v[n];
  float4 s = make_float4(0.f, 0.f, 0.f, 0.f);
  for (int i = beg + sub; i < end; i += 16) {
    float4 a = as1v[col[i]];
    float4 o;
    o.x = expf(lrelu(a.x + ad.x));
    o.y = expf(lrelu(a.y + ad.y));
    o.z = expf(lrelu(a.z + ad.z));
    o.w = expf(lrelu(a.w + ad.w));
    e1v[i] = o;
    s.x += o.x; s.y += o.y; s.z += o.z; s.w += o.w;
  }
#pragma unroll
  for (int off = 1; off < 16; off <<= 1) {
    s.x += __shfl_xor(s.x, off);
    s.y += __shfl_xor(s.y, off);
    s.z += __shfl_xor(s.z, off);
    s.w += __shfl_xor(s.w, off);
  }
  if (sub == 0) {
    float4 a = as1v[n];
    float4 es;
    es.x = expf(lrelu(a.x + ad.x));
    es.y = expf(lrelu(a.y + ad.y));
    es.z = expf(lrelu(a.z + ad.z));
    es.w = expf(lrelu(a.w + ad.w));
    es1v[n] = es;
    di1v[n] = make_float4(1.f / (s.x + es.x), 1.f / (s.y + es.y), 1.f / (s.z + es.z), 1.f / (s.w + es.w));
  }
}

__global__ __launch_bounds__(256) void ered2_kernel(const int* __restrict__ col, const int* __restrict__ rowptr,
                                                    const float* __restrict__ as2, const float* __restrict__ ad2,
                                                    float* __restrict__ e2a, float* __restrict__ di2a,
                                                    float* __restrict__ es2a) {
  int n = blockIdx.x * 16 + (threadIdx.x >> 4);
  int sub = threadIdx.x & 15;
  int beg = rowptr[n], end = rowptr[n + 1];
  float ad = ad2[n];
  float s = 0.f;
  for (int i = beg + sub; i < end; i += 16) {
    float o = expf(lrelu(as2[col[i]] + ad));
    e2a[i] = o;
    s += o;
  }
#pragma unroll
  for (int off = 1; off < 16; off <<= 1) s += __shfl_xor(s, off);
  if (sub == 0) {
    float es = expf(lrelu(as2[n] + ad));
    es2a[n] = es;
    di2a[n] = 1.f / (s + es);
  }
}

// ---------------- layer-1 gather: bf16 rows, 4 rows per wave-load ----------------
__global__ __launch_bounds__(256) void agg1_kernel(const uint4* __restrict__ h1b4, const float* __restrict__ e1,
                                                   const int* __restrict__ rowptr, const int* __restrict__ col,
                                                   const float* __restrict__ di1, const float* __restrict__ es1,
                                                   const float4* __restrict__ b1v, uint4* __restrict__ h1eb4) {
  int n = (blockIdx.x * 256 + threadIdx.x) >> 6;
  int lane = threadIdx.x & 63;
  int slot = lane >> 4;  // 0..3
  int fo = lane & 15;    // feats fo*8 .. fo*8+7
  int h = fo >> 2;       // head for these 8 feats
  int beg = rowptr[n], end = rowptr[n + 1];

  float acc[8];
#pragma unroll
  for (int j = 0; j < 8; ++j) acc[j] = 0.f;

#define ACC_EDGE1(E)                                        \
  {                                                         \
    int src = col[E];                                       \
    float a = e1[(E) * 4 + h];                              \
    uint4 uu = h1b4[src * 16 + fo];                         \
    acc[0] += a * bfl(uu.x); acc[1] += a * bfh(uu.x);       \
    acc[2] += a * bfl(uu.y); acc[3] += a * bfh(uu.y);       \
    acc[4] += a * bfl(uu.z); acc[5] += a * bfh(uu.z);       \
    acc[6] += a * bfl(uu.w); acc[7] += a * bfh(uu.w);       \
  }

  int i = beg;
  for (; i + 16 <= end; i += 16) {
#pragma unroll
    for (int u = 0; u < 4; ++u) ACC_EDGE1(i + u * 4 + slot);
  }
  for (; i + 4 <= end; i += 4) ACC_EDGE1(i + slot);
  int rem = end - i;
  if (slot < rem) ACC_EDGE1(i + slot);
  // self loop
  if (slot == 0) {
    float wv = es1[n * 4 + h];
    uint4 uu = h1b4[n * 16 + fo];
    acc[0] += wv * bfl(uu.x); acc[1] += wv * bfh(uu.x);
    acc[2] += wv * bfl(uu.y); acc[3] += wv * bfh(uu.y);
    acc[4] += wv * bfl(uu.z); acc[5] += wv * bfh(uu.z);
    acc[6] += wv * bfl(uu.w); acc[7] += wv * bfh(uu.w);
  }
#pragma unroll
  for (int j = 0; j < 8; ++j) {
    acc[j] += __shfl_xor(acc[j], 16);
    acc[j] += __shfl_xor(acc[j], 32);
  }
  if (slot == 0) {
    float dsc = di1[n * 4 + h];
    float4 b0 = b1v[fo * 2], b1 = b1v[fo * 2 + 1];
    float f0 = elu(acc[0] * dsc + b0.x), f1 = elu(acc[1] * dsc + b0.y);
    float f2 = elu(acc[2] * dsc + b0.z), f3 = elu(acc[3] * dsc + b0.w);
    float f4 = elu(acc[4] * dsc + b1.x), f5 = elu(acc[5] * dsc + b1.y);
    float f6 = elu(acc[6] * dsc + b1.z), f7 = elu(acc[7] * dsc + b1.w);
    uint4 o;
    o.x = pack2bf(f0, f1); o.y = pack2bf(f2, f3);
    o.z = pack2bf(f4, f5); o.w = pack2bf(f6, f7);
    h1eb4[n * 16 + fo] = o;
  }
#undef ACC_EDGE1
}

// ---------------- layer-2 gather + fused global add pool: bf16 rows, 8 rows per wave-load ----------------
__global__ __launch_bounds__(256) void agg2_kernel(const uint4* __restrict__ h2b4, const float* __restrict__ e2a,
                                                   const int* __restrict__ rowptr, const int* __restrict__ col,
                                                   const float* __restrict__ di2a, const float* __restrict__ es2a,
                                                   const float4* __restrict__ b2v, float* __restrict__ pooled) {
  __shared__ float red[4][64];
  int n = (blockIdx.x * 256 + threadIdx.x) >> 6;
  int lane = threadIdx.x & 63;
  int wid = threadIdx.x >> 6;
  int slot = lane >> 3;  // 0..7
  int fo = lane & 7;     // feats fo*8 .. fo*8+7
  int beg = rowptr[n], end = rowptr[n + 1];

  float acc[8];
#pragma unroll
  for (int j = 0; j < 8; ++j) acc[j] = 0.f;

#define ACC_EDGE2(E)                                        \
  {                                                         \
    int src = col[E];                                       \
    float a = e2a[E];                                       \
    uint4 uu = h2b4[src * 8 + fo];                          \
    acc[0] += a * bfl(uu.x); acc[1] += a * bfh(uu.x);       \
    acc[2] += a * bfl(uu.y); acc[3] += a * bfh(uu.y);       \
    acc[4] += a * bfl(uu.z); acc[5] += a * bfh(uu.z);       \
    acc[6] += a * bfl(uu.w); acc[7] += a * bfh(uu.w);       \
  }

  int i = beg;
  for (; i + 32 <= end; i += 32) {
#pragma unroll
    for (int u = 0; u < 4; ++u) ACC_EDGE2(i + u * 8 + slot);
  }
  for (; i + 8 <= end; i += 8) ACC_EDGE2(i + slot);
  int rem = end - i;
  if (slot < rem) ACC_EDGE2(i + slot);
  // self loop
  if (slot == 0) {
    float wv = es2a[n];
    uint4 uu = h2b4[n * 8 + fo];
    acc[0] += wv * bfl(uu.x); acc[1] += wv * bfh(uu.x);
    acc[2] += wv * bfl(uu.y); acc[3] += wv * bfh(uu.y);
    acc[4] += wv * bfl(uu.z); acc[5] += wv * bfh(uu.z);
    acc[6] += wv * bfl(uu.w); acc[7] += wv * bfh(uu.w);
  }
#pragma unroll
  for (int j = 0; j < 8; ++j) {
    acc[j] += __shfl_xor(acc[j], 8);
    acc[j] += __shfl_xor(acc[j], 16);
    acc[j] += __shfl_xor(acc[j], 32);
  }
  if (slot == 0) {
    float dsc = di2a[n];
    float4 b0 = b2v[fo * 2], b1 = b2v[fo * 2 + 1];
    red[wid][fo * 8 + 0] = elu(acc[0] * dsc + b0.x);
    red[wid][fo * 8 + 1] = elu(acc[1] * dsc + b0.y);
    red[wid][fo * 8 + 2] = elu(acc[2] * dsc + b0.z);
    red[wid][fo * 8 + 3] = elu(acc[3] * dsc + b0.w);
    red[wid][fo * 8 + 4] = elu(acc[4] * dsc + b1.x);
    red[wid][fo * 8 + 5] = elu(acc[5] * dsc + b1.y);
    red[wid][fo * 8 + 6] = elu(acc[6] * dsc + b1.z);
    red[wid][fo * 8 + 7] = elu(acc[7] * dsc + b1.w);
  }
  __syncthreads();
  if (threadIdx.x < 64) {
    float sum = red[0][threadIdx.x] + red[1][threadIdx.x] + red[2][threadIdx.x] + red[3][threadIdx.x];
    atomicAdd(&pooled[(blockIdx.x & 63) * 64 + threadIdx.x], sum);
  }
#undef ACC_EDGE2
}

// ---------------- final: reduce pooled stripes + pooled@Wl+bl ----------------
__global__ void final_kernel(const float* __restrict__ pooledS, const float* __restrict__ Wl,
                             const float* __restrict__ bl, float* __restrict__ out) {
  __shared__ float p[64];
  int t = threadIdx.x;
  float v = 0.f;
  for (int k = 0; k < 64; ++k) v += pooledS[k * 64 + t];
  p[t] = v;
  out[t] = v;
  __syncthreads();
  if (t < 2) {
    float s = bl[t];
    for (int k = 0; k < 64; ++k) s += p[k] * Wl[k * 2 + t];
    out[64 + t] = s;
  }
}

extern "C" void kernel_launch(void* const* d_in, const int* in_sizes, int n_in,
                              void* d_out, int out_size, void* d_ws, size_t ws_size,
                              hipStream_t stream) {
  (void)in_sizes; (void)n_in; (void)out_size; (void)ws_size;
  const float* x     = (const float*)d_in[0];
  const int*   ei    = (const int*)d_in[1];
  const float* W1    = (const float*)d_in[2];
  const float* atts1 = (const float*)d_in[3];
  const float* attd1 = (const float*)d_in[4];
  const float* b1    = (const float*)d_in[5];
  const float* W2    = (const float*)d_in[6];
  const float* atts2 = (const float*)d_in[7];
  const float* attd2 = (const float*)d_in[8];
  const float* b2    = (const float*)d_in[9];
  const float* Wl    = (const float*)d_in[10];
  const float* bl    = (const float*)d_in[11];
  float* out = (float*)d_out;

  char* w = (char*)d_ws;
  unsigned* h1b  = (unsigned*)w; w += (size_t)N_NODES * 128 * 2;  // 12.8 MB bf16
  unsigned* h1eb = (unsigned*)w; w += (size_t)N_NODES * 128 * 2;  // 12.8 MB bf16
  unsigned* h2b  = (unsigned*)w; w += (size_t)N_NODES * 64 * 2;   // 6.4 MB bf16
  float* e1   = (float*)w; w += (size_t)N_EDGES * 16;             // 12.8 MB
  float* e2a  = (float*)w; w += (size_t)N_EDGES * 4;              // 3.2 MB
  float* as1  = (float*)w; w += (size_t)N_NODES * 16;
  float* ad1  = (float*)w; w += (size_t)N_NODES * 16;
  float* di1  = (float*)w; w += (size_t)N_NODES * 16;
  float* es1  = (float*)w; w += (size_t)N_NODES * 16;
  float* as2  = (float*)w; w += (size_t)N_NODES * 4;
  float* ad2  = (float*)w; w += (size_t)N_NODES * 4;
  float* di2a = (float*)w; w += (size_t)N_NODES * 4;
  float* es2a = (float*)w; w += (size_t)N_NODES * 4;
  int* deg    = (int*)w; w += (size_t)N_NODES * 4;
  float* pooled = (float*)w; w += 64 * 64 * 4;                    // 64 stripes x 64
  int* rowptr = (int*)w; w += (size_t)(N_NODES + 1) * 4 + 12;
  int* col    = (int*)w; w += (size_t)N_EDGES * 4;
  int* rank   = (int*)w; w += (size_t)N_EDGES * 4;
  int* blocksum = (int*)w; w += 256 * 4;
  int* blockoff = (int*)w; w += 256 * 4;

  // zero deg + pooled (contiguous)
  hipMemsetAsync(deg, 0, (size_t)N_NODES * 4 + 64 * 64 * 4, stream);

  hist_kernel<<<(N_EDGES + 255) / 256, 256, 0, stream>>>(ei, deg, rank);
  scan_part_kernel<<<SCAN_BLOCKS, 256, 0, stream>>>(deg, rowptr, blocksum);
  scan_top_kernel<<<1, 256, 0, stream>>>(blocksum, blockoff);
  scan_add_kernel<<<SCAN_BLOCKS, 256, 0, stream>>>(blockoff, rowptr);
  scatter_kernel<<<(N_EDGES + 255) / 256, 256, 0, stream>>>(ei, rowptr, rank, col);

  gemm_kernel<128, false><<<(N_NODES + 63) / 64, 256, 0, stream>>>(x, W1, h1b);
  attn1_kernel<<<N_NODES / 4, 256, 0, stream>>>(h1b, atts1, attd1, as1, ad1);
  ered1_kernel<<<(N_NODES + 15) / 16, 256, 0, stream>>>(col, rowptr, (const float4*)as1, (const float4*)ad1,
                                                        (float4*)e1, (float4*)di1, (float4*)es1);
  agg1_kernel<<<N_NODES / 4, 256, 0, stream>>>((const uint4*)h1b, e1, rowptr, col, di1, es1,
                                               (const float4*)b1, (uint4*)h1eb);

  gemm_kernel<64, true><<<(N_NODES + 63) / 64, 256, 0, stream>>>(h1eb, W2, h2b);
  attn2_kernel<<<N_NODES / 8, 256, 0, stream>>>(h2b, atts2, attd2, as2, ad2);
  ered2_kernel<<<(N_NODES + 15) / 16, 256, 0, stream>>>(col, rowptr, as2, ad2, e2a, di2a, es2a);
  agg2_kernel<<<N_NODES / 4, 256, 0, stream>>>((const uint4*)h2b, e2a, rowptr, col, di2a, es2a,
                                               (const float4*)b2, pooled);

  final_kernel<<<1, 64, 0, stream>>>(pooled, Wl, bl, out);
}

// Round 10
// 276.743 us; speedup vs baseline: 2.8774x; 1.0720x over previous
//
#include <hip/hip_runtime.h>

#define N_NODES 50000
#define N_EDGES 800000
#define SCAN_BLOCKS ((N_NODES + 255) / 256)  // 196

__device__ __forceinline__ float lrelu(float x) { return x > 0.f ? x : 0.2f * x; }
__device__ __forceinline__ float elu(float x) { return x > 0.f ? x : expf(x) - 1.f; }

// bf16 helpers: lo/hi halves of a uint holding 2 consecutive bf16 elements
__device__ __forceinline__ float bfl(unsigned u) { return __uint_as_float(u << 16); }
__device__ __forceinline__ float bfh(unsigned u) { return __uint_as_float(u & 0xffff0000u); }
__device__ __forceinline__ unsigned f2bf_rn(float x) {
  unsigned u = __float_as_uint(x);
  return (u + 0x7fffu + ((u >> 16) & 1u)) >> 16;
}
__device__ __forceinline__ unsigned pack2bf(float a, float b) {
  return f2bf_rn(a) | (f2bf_rn(b) << 16);
}

// ---------------- CSR build ----------------
__global__ __launch_bounds__(256) void hist_kernel(const int* __restrict__ ei, int* __restrict__ deg,
                                                   int* __restrict__ rank) {
  int e = blockIdx.x * 256 + threadIdx.x;
  if (e < N_EDGES) rank[e] = atomicAdd(&deg[ei[N_EDGES + e]], 1);
}

__device__ __forceinline__ int block_excl_scan(int v, int* total_out) {
  int lane = threadIdx.x & 63;
  int wid = threadIdx.x >> 6;
  int x = v;
#pragma unroll
  for (int off = 1; off < 64; off <<= 1) {
    int u = __shfl_up(x, off);
    if (lane >= off) x += u;
  }
  __shared__ int wsum[4];
  if (lane == 63) wsum[wid] = x;
  __syncthreads();
  int add = 0;
#pragma unroll
  for (int k = 0; k < 4; ++k)
    if (k < wid) add += wsum[k];
  if (total_out) *total_out = wsum[0] + wsum[1] + wsum[2] + wsum[3];
  return x + add - v;
}

__global__ __launch_bounds__(256) void scan_part_kernel(const int* __restrict__ deg, int* __restrict__ rowptr,
                                                        int* __restrict__ blocksum) {
  int g = blockIdx.x * 256 + threadIdx.x;
  int v = (g < N_NODES) ? deg[g] : 0;
  int total;
  int ex = block_excl_scan(v, &total);
  if (g < N_NODES) rowptr[g] = ex;
  if (threadIdx.x == 0) blocksum[blockIdx.x] = total;
}

__global__ __launch_bounds__(256) void scan_top_kernel(const int* __restrict__ blocksum, int* __restrict__ blockoff) {
  int t = threadIdx.x;
  int v = (t < SCAN_BLOCKS) ? blocksum[t] : 0;
  int ex = block_excl_scan(v, nullptr);
  if (t < SCAN_BLOCKS) blockoff[t] = ex;
}

__global__ __launch_bounds__(256) void scan_add_kernel(const int* __restrict__ blockoff, int* __restrict__ rowptr) {
  int g = blockIdx.x * 256 + threadIdx.x;
  if (g < N_NODES) rowptr[g] += blockoff[g >> 8];
  if (g == 0) rowptr[N_NODES] = N_EDGES;
}

__global__ __launch_bounds__(256) void scatter_kernel(const int* __restrict__ ei, const int* __restrict__ rowptr,
                                                      const int* __restrict__ rank, int* __restrict__ col) {
  int e = blockIdx.x * 256 + threadIdx.x;
  if (e < N_EDGES) {
    int d = ei[N_EDGES + e];
    col[rowptr[d] + rank[e]] = ei[e];
  }
}

// ---------------- GEMM + fused attention dots ----------------
// Yb[N,COLS](bf16) = A[N,128] @ W[128,COLS]; epilogue computes per-node
// as/ad = einsum('nhf,hf->nh') from the fp32 accumulators.
// LDS: ws swizzled [k][c4][tx] (2-way, free); xs row stride 68 (2-way, free).
#define XS_STRIDE 68
template <int COLS, bool ABF16>
__global__ __launch_bounds__(256) void gemm_kernel(const void* __restrict__ Ap, const float* __restrict__ W,
                                                   const float* __restrict__ atts, const float* __restrict__ attd,
                                                   unsigned* __restrict__ Yb, float* __restrict__ as_out,
                                                   float* __restrict__ ad_out) {
  constexpr int CPT = COLS / 16;   // cols per thread (8 or 4)
  constexpr int G = COLS / 4;      // float4 groups per k-row (32 or 16)
  __shared__ float ws[64 * COLS];
  __shared__ float xs[64 * XS_STRIDE];
  int t = threadIdx.x;
  int rbase = blockIdx.x * 64;
  int tx = t & 15, ty = t >> 4;
  float acc[4][CPT];
#pragma unroll
  for (int r = 0; r < 4; ++r)
#pragma unroll
    for (int c = 0; c < CPT; ++c) acc[r][c] = 0.f;

  const float4* W4 = (const float4*)W;
  float4* ws4 = (float4*)ws;
  for (int kt = 0; kt < 2; ++kt) {
    for (int i = t; i < 64 * G; i += 256) {
      int k = i / G;
      int g = i - k * G;
      int c4g = g & (CPT / 4 - 1);
      int txg = g / (CPT / 4);
      ws4[k * G + c4g * 16 + txg] = W4[kt * 16 * COLS + i];
    }
    if constexpr (ABF16) {
      const uint4* A4 = (const uint4*)Ap;  // row = 128 bf16 = 16 uint4
      for (int i = t; i < 512; i += 256) {
        int row = i >> 3, q = i & 7;
        int gr = rbase + row; if (gr >= N_NODES) gr = N_NODES - 1;
        uint4 u = A4[gr * 16 + kt * 8 + q];
        float4 lo = make_float4(bfl(u.x), bfh(u.x), bfl(u.y), bfh(u.y));
        float4 hi = make_float4(bfl(u.z), bfh(u.z), bfl(u.w), bfh(u.w));
        float4* dst = (float4*)&xs[row * XS_STRIDE + q * 8];
        dst[0] = lo; dst[1] = hi;
      }
    } else {
      const float4* A4 = (const float4*)Ap;
      for (int i = t; i < 1024; i += 256) {
        int row = i >> 4, kc = i & 15;
        int gr = rbase + row; if (gr >= N_NODES) gr = N_NODES - 1;
        *(float4*)&xs[row * XS_STRIDE + kc * 4] = A4[gr * 32 + kt * 16 + kc];
      }
    }
    __syncthreads();
#pragma unroll 8
    for (int k = 0; k < 64; ++k) {
      float xr[4];
#pragma unroll
      for (int r = 0; r < 4; ++r) xr[r] = xs[(ty * 4 + r) * XS_STRIDE + k];
#pragma unroll
      for (int c4 = 0; c4 < CPT / 4; ++c4) {
        float4 wv = ws4[k * G + c4 * 16 + tx];
#pragma unroll
        for (int r = 0; r < 4; ++r) {
          acc[r][c4 * 4 + 0] += xr[r] * wv.x;
          acc[r][c4 * 4 + 1] += xr[r] * wv.y;
          acc[r][c4 * 4 + 2] += xr[r] * wv.z;
          acc[r][c4 * 4 + 3] += xr[r] * wv.w;
        }
      }
    }
    __syncthreads();
  }

  // fused attention dots
  if constexpr (COLS == 128) {
    // 4 heads x 32 feats; this thread covers cols tx*8..tx*8+7 -> head tx>>2
    int h = tx >> 2;
    int base = h * 32 + (tx & 3) * 8;
#pragma unroll
    for (int r = 0; r < 4; ++r) {
      float ps = 0.f, pd = 0.f;
#pragma unroll
      for (int c = 0; c < 8; ++c) {
        ps += acc[r][c] * atts[base + c];
        pd += acc[r][c] * attd[base + c];
      }
      ps += __shfl_xor(ps, 1); pd += __shfl_xor(pd, 1);
      ps += __shfl_xor(ps, 2); pd += __shfl_xor(pd, 2);
      int row = rbase + ty * 4 + r;
      if ((tx & 3) == 0 && row < N_NODES) {
        as_out[row * 4 + h] = ps;
        ad_out[row * 4 + h] = pd;
      }
    }
  } else {
    // 1 head x 64 feats; cols tx*4..tx*4+3
#pragma unroll
    for (int r = 0; r < 4; ++r) {
      float ps = 0.f, pd = 0.f;
#pragma unroll
      for (int c = 0; c < 4; ++c) {
        ps += acc[r][c] * atts[tx * 4 + c];
        pd += acc[r][c] * attd[tx * 4 + c];
      }
#pragma unroll
      for (int off = 1; off < 16; off <<= 1) {
        ps += __shfl_xor(ps, off);
        pd += __shfl_xor(pd, off);
      }
      int row = rbase + ty * 4 + r;
      if (tx == 0 && row < N_NODES) {
        as_out[row] = ps;
        ad_out[row] = pd;
      }
    }
  }

#pragma unroll
  for (int r = 0; r < 4; ++r) {
    int row = rbase + ty * 4 + r;
    if (row < N_NODES) {
      if constexpr (CPT == 8) {
        uint4 o;
        o.x = pack2bf(acc[r][0], acc[r][1]);
        o.y = pack2bf(acc[r][2], acc[r][3]);
        o.z = pack2bf(acc[r][4], acc[r][5]);
        o.w = pack2bf(acc[r][6], acc[r][7]);
        ((uint4*)Yb)[row * 16 + tx] = o;
      } else {
        uint2 o;
        o.x = pack2bf(acc[r][0], acc[r][1]);
        o.y = pack2bf(acc[r][2], acc[r][3]);
        ((uint2*)Yb)[row * 16 + tx] = o;
      }
    }
  }
}

// ---------------- layer-1 gather, fused e-compute + denom ----------------
// e recomputed inline from as1/ad1 (L2-resident); denominator falls out of the
// same slot-shuffle reduction as the feature accumulator.
__global__ __launch_bounds__(256) void agg1_kernel(const uint4* __restrict__ h1b4, const int* __restrict__ rowptr,
                                                   const int* __restrict__ col, const float* __restrict__ as1,
                                                   const float* __restrict__ ad1, const float4* __restrict__ b1v,
                                                   uint4* __restrict__ h1eb4) {
  int n = (blockIdx.x * 256 + threadIdx.x) >> 6;
  int lane = threadIdx.x & 63;
  int slot = lane >> 4;  // 0..3
  int fo = lane & 15;    // feats fo*8 .. fo*8+7
  int h = fo >> 2;       // head for these 8 feats
  int beg = rowptr[n], end = rowptr[n + 1];
  float adh = ad1[n * 4 + h];

  float acc[8];
#pragma unroll
  for (int j = 0; j < 8; ++j) acc[j] = 0.f;
  float esum = 0.f;

#define ACC_EDGE1(E)                                        \
  {                                                         \
    int src = col[E];                                       \
    float a = expf(lrelu(as1[src * 4 + h] + adh));          \
    esum += a;                                              \
    uint4 uu = h1b4[src * 16 + fo];                         \
    acc[0] += a * bfl(uu.x); acc[1] += a * bfh(uu.x);       \
    acc[2] += a * bfl(uu.y); acc[3] += a * bfh(uu.y);       \
    acc[4] += a * bfl(uu.z); acc[5] += a * bfh(uu.z);       \
    acc[6] += a * bfl(uu.w); acc[7] += a * bfh(uu.w);       \
  }

  int i = beg;
  for (; i + 16 <= end; i += 16) {
#pragma unroll
    for (int u = 0; u < 4; ++u) ACC_EDGE1(i + u * 4 + slot);
  }
  for (; i + 4 <= end; i += 4) ACC_EDGE1(i + slot);
  int rem = end - i;
  if (slot < rem) ACC_EDGE1(i + slot);
  // self loop (slot 0 only -> counted once after reduction)
  if (slot == 0) {
    float a = expf(lrelu(as1[n * 4 + h] + adh));
    esum += a;
    uint4 uu = h1b4[n * 16 + fo];
    acc[0] += a * bfl(uu.x); acc[1] += a * bfh(uu.x);
    acc[2] += a * bfl(uu.y); acc[3] += a * bfh(uu.y);
    acc[4] += a * bfl(uu.z); acc[5] += a * bfh(uu.z);
    acc[6] += a * bfl(uu.w); acc[7] += a * bfh(uu.w);
  }
#pragma unroll
  for (int j = 0; j < 8; ++j) {
    acc[j] += __shfl_xor(acc[j], 16);
    acc[j] += __shfl_xor(acc[j], 32);
  }
  esum += __shfl_xor(esum, 16);
  esum += __shfl_xor(esum, 32);
  if (slot == 0) {
    float dsc = 1.f / esum;
    float4 b0 = b1v[fo * 2], b1 = b1v[fo * 2 + 1];
    float f0 = elu(acc[0] * dsc + b0.x), f1 = elu(acc[1] * dsc + b0.y);
    float f2 = elu(acc[2] * dsc + b0.z), f3 = elu(acc[3] * dsc + b0.w);
    float f4 = elu(acc[4] * dsc + b1.x), f5 = elu(acc[5] * dsc + b1.y);
    float f6 = elu(acc[6] * dsc + b1.z), f7 = elu(acc[7] * dsc + b1.w);
    uint4 o;
    o.x = pack2bf(f0, f1); o.y = pack2bf(f2, f3);
    o.z = pack2bf(f4, f5); o.w = pack2bf(f6, f7);
    h1eb4[n * 16 + fo] = o;
  }
#undef ACC_EDGE1
}

// ---------------- layer-2 gather, fused e + denom + global add pool ----------------
__global__ __launch_bounds__(256) void agg2_kernel(const uint4* __restrict__ h2b4, const int* __restrict__ rowptr,
                                                   const int* __restrict__ col, const float* __restrict__ as2,
                                                   const float* __restrict__ ad2, const float4* __restrict__ b2v,
                                                   float* __restrict__ pooled) {
  __shared__ float red[4][64];
  int n = (blockIdx.x * 256 + threadIdx.x) >> 6;
  int lane = threadIdx.x & 63;
  int wid = threadIdx.x >> 6;
  int slot = lane >> 3;  // 0..7
  int fo = lane & 7;     // feats fo*8 .. fo*8+7
  int beg = rowptr[n], end = rowptr[n + 1];
  float ad = ad2[n];

  float acc[8];
#pragma unroll
  for (int j = 0; j < 8; ++j) acc[j] = 0.f;
  float esum = 0.f;

#define ACC_EDGE2(E)                                        \
  {                                                         \
    int src = col[E];                                       \
    float a = expf(lrelu(as2[src] + ad));                   \
    esum += a;                                              \
    uint4 uu = h2b4[src * 8 + fo];                          \
    acc[0] += a * bfl(uu.x); acc[1] += a * bfh(uu.x);       \
    acc[2] += a * bfl(uu.y); acc[3] += a * bfh(uu.y);       \
    acc[4] += a * bfl(uu.z); acc[5] += a * bfh(uu.z);       \
    acc[6] += a * bfl(uu.w); acc[7] += a * bfh(uu.w);       \
  }

  int i = beg;
  for (; i + 32 <= end; i += 32) {
#pragma unroll
    for (int u = 0; u < 4; ++u) ACC_EDGE2(i + u * 8 + slot);
  }
  for (; i + 8 <= end; i += 8) ACC_EDGE2(i + slot);
  int rem = end - i;
  if (slot < rem) ACC_EDGE2(i + slot);
  // self loop
  if (slot == 0) {
    float a = expf(lrelu(as2[n] + ad));
    esum += a;
    uint4 uu = h2b4[n * 8 + fo];
    acc[0] += a * bfl(uu.x); acc[1] += a * bfh(uu.x);
    acc[2] += a * bfl(uu.y); acc[3] += a * bfh(uu.y);
    acc[4] += a * bfl(uu.z); acc[5] += a * bfh(uu.z);
    acc[6] += a * bfl(uu.w); acc[7] += a * bfh(uu.w);
  }
#pragma unroll
  for (int j = 0; j < 8; ++j) {
    acc[j] += __shfl_xor(acc[j], 8);
    acc[j] += __shfl_xor(acc[j], 16);
    acc[j] += __shfl_xor(acc[j], 32);
  }
  esum += __shfl_xor(esum, 8);
  esum += __shfl_xor(esum, 16);
  esum += __shfl_xor(esum, 32);
  if (slot == 0) {
    float dsc = 1.f / esum;
    float4 b0 = b2v[fo * 2], b1 = b2v[fo * 2 + 1];
    red[wid][fo * 8 + 0] = elu(acc[0] * dsc + b0.x);
    red[wid][fo * 8 + 1] = elu(acc[1] * dsc + b0.y);
    red[wid][fo * 8 + 2] = elu(acc[2] * dsc + b0.z);
    red[wid][fo * 8 + 3] = elu(acc[3] * dsc + b0.w);
    red[wid][fo * 8 + 4] = elu(acc[4] * dsc + b1.x);
    red[wid][fo * 8 + 5] = elu(acc[5] * dsc + b1.y);
    red[wid][fo * 8 + 6] = elu(acc[6] * dsc + b1.z);
    red[wid][fo * 8 + 7] = elu(acc[7] * dsc + b1.w);
  }
  __syncthreads();
  if (threadIdx.x < 64) {
    float sum = red[0][threadIdx.x] + red[1][threadIdx.x] + red[2][threadIdx.x] + red[3][threadIdx.x];
    atomicAdd(&pooled[(blockIdx.x & 63) * 64 + threadIdx.x], sum);
  }
#undef ACC_EDGE2
}

// ---------------- final: reduce pooled stripes + pooled@Wl+bl ----------------
__global__ void final_kernel(const float* __restrict__ pooledS, const float* __restrict__ Wl,
                             const float* __restrict__ bl, float* __restrict__ out) {
  __shared__ float p[64];
  int t = threadIdx.x;
  float v = 0.f;
  for (int k = 0; k < 64; ++k) v += pooledS[k * 64 + t];
  p[t] = v;
  out[t] = v;
  __syncthreads();
  if (t < 2) {
    float s = bl[t];
    for (int k = 0; k < 64; ++k) s += p[k] * Wl[k * 2 + t];
    out[64 + t] = s;
  }
}

extern "C" void kernel_launch(void* const* d_in, const int* in_sizes, int n_in,
                              void* d_out, int out_size, void* d_ws, size_t ws_size,
                              hipStream_t stream) {
  (void)in_sizes; (void)n_in; (void)out_size; (void)ws_size;
  const float* x     = (const float*)d_in[0];
  const int*   ei    = (const int*)d_in[1];
  const float* W1    = (const float*)d_in[2];
  const float* atts1 = (const float*)d_in[3];
  const float* attd1 = (const float*)d_in[4];
  const float* b1    = (const float*)d_in[5];
  const float* W2    = (const float*)d_in[6];
  const float* atts2 = (const float*)d_in[7];
  const float* attd2 = (const float*)d_in[8];
  const float* b2    = (const float*)d_in[9];
  const float* Wl    = (const float*)d_in[10];
  const float* bl    = (const float*)d_in[11];
  float* out = (float*)d_out;

  char* w = (char*)d_ws;
  unsigned* h1b  = (unsigned*)w; w += (size_t)N_NODES * 128 * 2;  // 12.8 MB bf16
  unsigned* h1eb = (unsigned*)w; w += (size_t)N_NODES * 128 * 2;  // 12.8 MB bf16
  unsigned* h2b  = (unsigned*)w; w += (size_t)N_NODES * 64 * 2;   // 6.4 MB bf16
  float* as1  = (float*)w; w += (size_t)N_NODES * 16;
  float* ad1  = (float*)w; w += (size_t)N_NODES * 16;
  float* as2  = (float*)w; w += (size_t)N_NODES * 4;
  float* ad2  = (float*)w; w += (size_t)N_NODES * 4;
  int* deg    = (int*)w; w += (size_t)N_NODES * 4;
  float* pooled = (float*)w; w += 64 * 64 * 4;                    // 64 stripes x 64
  int* rowptr = (int*)w; w += (size_t)(N_NODES + 1) * 4 + 12;
  int* col    = (int*)w; w += (size_t)N_EDGES * 4;
  int* rank   = (int*)w; w += (size_t)N_EDGES * 4;
  int* blocksum = (int*)w; w += 256 * 4;
  int* blockoff = (int*)w; w += 256 * 4;

  // zero deg + pooled (contiguous)
  hipMemsetAsync(deg, 0, (size_t)N_NODES * 4 + 64 * 64 * 4, stream);

  hist_kernel<<<(N_EDGES + 255) / 256, 256, 0, stream>>>(ei, deg, rank);
  scan_part_kernel<<<SCAN_BLOCKS, 256, 0, stream>>>(deg, rowptr, blocksum);
  scan_top_kernel<<<1, 256, 0, stream>>>(blocksum, blockoff);
  scan_add_kernel<<<SCAN_BLOCKS, 256, 0, stream>>>(blockoff, rowptr);
  scatter_kernel<<<(N_EDGES + 255) / 256, 256, 0, stream>>>(ei, rowptr, rank, col);

  gemm_kernel<128, false><<<(N_NODES + 63) / 64, 256, 0, stream>>>(x, W1, atts1, attd1, h1b, as1, ad1);
  agg1_kernel<<<N_NODES / 4, 256, 0, stream>>>((const uint4*)h1b, rowptr, col, as1, ad1,
                                               (const float4*)b1, (uint4*)h1eb);

  gemm_kernel<64, true><<<(N_NODES + 63) / 64, 256, 0, stream>>>(h1eb, W2, atts2, attd2, h2b, as2, ad2);
  agg2_kernel<<<N_NODES / 4, 256, 0, stream>>>((const uint4*)h2b, rowptr, col, as2, ad2,
                                               (const float4*)b2, pooled);

  final_kernel<<<1, 64, 0, stream>>>(pooled, Wl, bl, out);
}

// Round 11
// 271.559 us; speedup vs baseline: 2.9323x; 1.0191x over previous
//
#include <hip/hip_runtime.h>

#define N_NODES 50000
#define N_EDGES 800000
#define SCAN_BLOCKS ((N_NODES + 255) / 256)   // 196
#define HIST_BLOCKS ((N_EDGES + 255) / 256)   // 3125
#define GEMM_BLOCKS ((N_NODES + 63) / 64)     // 782

__device__ __forceinline__ float lrelu(float x) { return x > 0.f ? x : 0.2f * x; }
__device__ __forceinline__ float elu(float x) { return x > 0.f ? x : expf(x) - 1.f; }

typedef float f32x2 __attribute__((ext_vector_type(2)));

// bf16 helpers: lo/hi halves of a uint holding 2 consecutive bf16 elements
__device__ __forceinline__ float bfl(unsigned u) { return __uint_as_float(u << 16); }
__device__ __forceinline__ float bfh(unsigned u) { return __uint_as_float(u & 0xffff0000u); }
__device__ __forceinline__ unsigned f2bf_rn(float x) {
  unsigned u = __float_as_uint(x);
  return (u + 0x7fffu + ((u >> 16) & 1u)) >> 16;
}
__device__ __forceinline__ unsigned pack2bf(float a, float b) {
  return f2bf_rn(a) | (f2bf_rn(b) << 16);
}

// ---------------- scan ----------------
__device__ __forceinline__ int block_excl_scan(int v, int* total_out) {
  int lane = threadIdx.x & 63;
  int wid = threadIdx.x >> 6;
  int x = v;
#pragma unroll
  for (int off = 1; off < 64; off <<= 1) {
    int u = __shfl_up(x, off);
    if (lane >= off) x += u;
  }
  __shared__ int wsum[4];
  if (lane == 63) wsum[wid] = x;
  __syncthreads();
  int add = 0;
#pragma unroll
  for (int k = 0; k < 4; ++k)
    if (k < wid) add += wsum[k];
  if (total_out) *total_out = wsum[0] + wsum[1] + wsum[2] + wsum[3];
  return x + add - v;
}

__global__ __launch_bounds__(256) void scan_part_kernel(const int* __restrict__ deg, int* __restrict__ rowptr,
                                                        int* __restrict__ blocksum) {
  int g = blockIdx.x * 256 + threadIdx.x;
  int v = (g < N_NODES) ? deg[g] : 0;
  int total;
  int ex = block_excl_scan(v, &total);
  if (g < N_NODES) rowptr[g] = ex;
  if (threadIdx.x == 0) blocksum[blockIdx.x] = total;
}

__global__ __launch_bounds__(256) void scan_top_kernel(const int* __restrict__ blocksum, int* __restrict__ blockoff) {
  int t = threadIdx.x;
  int v = (t < SCAN_BLOCKS) ? blocksum[t] : 0;
  int ex = block_excl_scan(v, nullptr);
  if (t < SCAN_BLOCKS) blockoff[t] = ex;
}

__global__ __launch_bounds__(256) void scan_add_kernel(const int* __restrict__ blockoff, int* __restrict__ rowptr) {
  int g = blockIdx.x * 256 + threadIdx.x;
  if (g < N_NODES) rowptr[g] += blockoff[g >> 8];
  if (g == 0) rowptr[N_NODES] = N_EDGES;
}

__global__ __launch_bounds__(256) void scatter_kernel(const int* __restrict__ ei, const int* __restrict__ rowptr,
                                                      const int* __restrict__ rank, int* __restrict__ col) {
  int e = blockIdx.x * 256 + threadIdx.x;
  if (e < N_EDGES) {
    int d = ei[N_EDGES + e];
    col[rowptr[d] + rank[e]] = ei[e];
  }
}

// ---------------- GEMM body + fused attention dots ----------------
#define XS_STRIDE 68
template <int COLS, bool ABF16>
__device__ __forceinline__ void gemm_body(int bx, const void* __restrict__ Ap, const float* __restrict__ W,
                                          const float* __restrict__ atts, const float* __restrict__ attd,
                                          unsigned* __restrict__ Yb, float* __restrict__ as_out,
                                          float* __restrict__ ad_out) {
  constexpr int CPT = COLS / 16;   // cols per thread (8 or 4)
  constexpr int G = COLS / 4;      // float4 groups per k-row (32 or 16)
  __shared__ float ws[64 * COLS];
  __shared__ float xs[64 * XS_STRIDE];
  int t = threadIdx.x;
  int rbase = bx * 64;
  int tx = t & 15, ty = t >> 4;
  float acc[4][CPT];
#pragma unroll
  for (int r = 0; r < 4; ++r)
#pragma unroll
    for (int c = 0; c < CPT; ++c) acc[r][c] = 0.f;

  const float4* W4 = (const float4*)W;
  float4* ws4 = (float4*)ws;
  for (int kt = 0; kt < 2; ++kt) {
    for (int i = t; i < 64 * G; i += 256) {
      int k = i / G;
      int g = i - k * G;
      int c4g = g & (CPT / 4 - 1);
      int txg = g / (CPT / 4);
      ws4[k * G + c4g * 16 + txg] = W4[kt * 16 * COLS + i];
    }
    if constexpr (ABF16) {
      const uint4* A4 = (const uint4*)Ap;  // row = 128 bf16 = 16 uint4
      for (int i = t; i < 512; i += 256) {
        int row = i >> 3, q = i & 7;
        int gr = rbase + row; if (gr >= N_NODES) gr = N_NODES - 1;
        uint4 u = A4[gr * 16 + kt * 8 + q];
        float4 lo = make_float4(bfl(u.x), bfh(u.x), bfl(u.y), bfh(u.y));
        float4 hi = make_float4(bfl(u.z), bfh(u.z), bfl(u.w), bfh(u.w));
        float4* dst = (float4*)&xs[row * XS_STRIDE + q * 8];
        dst[0] = lo; dst[1] = hi;
      }
    } else {
      const float4* A4 = (const float4*)Ap;
      for (int i = t; i < 1024; i += 256) {
        int row = i >> 4, kc = i & 15;
        int gr = rbase + row; if (gr >= N_NODES) gr = N_NODES - 1;
        *(float4*)&xs[row * XS_STRIDE + kc * 4] = A4[gr * 32 + kt * 16 + kc];
      }
    }
    __syncthreads();
#pragma unroll 8
    for (int k = 0; k < 64; ++k) {
      float xr[4];
#pragma unroll
      for (int r = 0; r < 4; ++r) xr[r] = xs[(ty * 4 + r) * XS_STRIDE + k];
#pragma unroll
      for (int c4 = 0; c4 < CPT / 4; ++c4) {
        float4 wv = ws4[k * G + c4 * 16 + tx];
#pragma unroll
        for (int r = 0; r < 4; ++r) {
          acc[r][c4 * 4 + 0] += xr[r] * wv.x;
          acc[r][c4 * 4 + 1] += xr[r] * wv.y;
          acc[r][c4 * 4 + 2] += xr[r] * wv.z;
          acc[r][c4 * 4 + 3] += xr[r] * wv.w;
        }
      }
    }
    __syncthreads();
  }

  // fused attention dots
  if constexpr (COLS == 128) {
    int h = tx >> 2;
    int base = h * 32 + (tx & 3) * 8;
#pragma unroll
    for (int r = 0; r < 4; ++r) {
      float ps = 0.f, pd = 0.f;
#pragma unroll
      for (int c = 0; c < 8; ++c) {
        ps += acc[r][c] * atts[base + c];
        pd += acc[r][c] * attd[base + c];
      }
      ps += __shfl_xor(ps, 1); pd += __shfl_xor(pd, 1);
      ps += __shfl_xor(ps, 2); pd += __shfl_xor(pd, 2);
      int row = rbase + ty * 4 + r;
      if ((tx & 3) == 0 && row < N_NODES) {
        as_out[row * 4 + h] = ps;
        ad_out[row * 4 + h] = pd;
      }
    }
  } else {
#pragma unroll
    for (int r = 0; r < 4; ++r) {
      float ps = 0.f, pd = 0.f;
#pragma unroll
      for (int c = 0; c < 4; ++c) {
        ps += acc[r][c] * atts[tx * 4 + c];
        pd += acc[r][c] * attd[tx * 4 + c];
      }
#pragma unroll
      for (int off = 1; off < 16; off <<= 1) {
        ps += __shfl_xor(ps, off);
        pd += __shfl_xor(pd, off);
      }
      int row = rbase + ty * 4 + r;
      if (tx == 0 && row < N_NODES) {
        as_out[row] = ps;
        ad_out[row] = pd;
      }
    }
  }

#pragma unroll
  for (int r = 0; r < 4; ++r) {
    int row = rbase + ty * 4 + r;
    if (row < N_NODES) {
      if constexpr (CPT == 8) {
        uint4 o;
        o.x = pack2bf(acc[r][0], acc[r][1]);
        o.y = pack2bf(acc[r][2], acc[r][3]);
        o.z = pack2bf(acc[r][4], acc[r][5]);
        o.w = pack2bf(acc[r][6], acc[r][7]);
        ((uint4*)Yb)[row * 16 + tx] = o;
      } else {
        uint2 o;
        o.x = pack2bf(acc[r][0], acc[r][1]);
        o.y = pack2bf(acc[r][2], acc[r][3]);
        ((uint2*)Yb)[row * 16 + tx] = o;
      }
    }
  }
}

// ---------------- fused: hist (blocks [0,HIST_BLOCKS)) + gemm128 (rest) ----------------
// The two halves touch disjoint data; co-scheduling hides the ~40us atomic
// histogram under the GEMM (and vice versa).
__global__ __launch_bounds__(256) void gemm128_hist_kernel(const float* __restrict__ x, const float* __restrict__ W1,
                                                           const float* __restrict__ atts, const float* __restrict__ attd,
                                                           unsigned* __restrict__ h1b, float* __restrict__ as1,
                                                           float* __restrict__ ad1, const int* __restrict__ ei,
                                                           int* __restrict__ deg, int* __restrict__ rank) {
  if (blockIdx.x < HIST_BLOCKS) {
    int e = blockIdx.x * 256 + threadIdx.x;
    if (e < N_EDGES) rank[e] = atomicAdd(&deg[ei[N_EDGES + e]], 1);
    return;
  }
  gemm_body<128, false>(blockIdx.x - HIST_BLOCKS, x, W1, atts, attd, h1b, as1, ad1);
}

__global__ __launch_bounds__(256) void gemm64_kernel(const unsigned* __restrict__ h1eb, const float* __restrict__ W2,
                                                     const float* __restrict__ atts, const float* __restrict__ attd,
                                                     unsigned* __restrict__ h2b, float* __restrict__ as2,
                                                     float* __restrict__ ad2) {
  gemm_body<64, true>(blockIdx.x, h1eb, W2, atts, attd, h2b, as2, ad2);
}

// ---------------- layer-1 gather, fused e-compute + denom; f32x2 packed FMA ----------------
__global__ __launch_bounds__(256) void agg1_kernel(const uint4* __restrict__ h1b4, const int* __restrict__ rowptr,
                                                   const int* __restrict__ col, const float* __restrict__ as1,
                                                   const float* __restrict__ ad1, const float4* __restrict__ b1v,
                                                   uint4* __restrict__ h1eb4) {
  int n = (blockIdx.x * 256 + threadIdx.x) >> 6;
  int lane = threadIdx.x & 63;
  int slot = lane >> 4;  // 0..3
  int fo = lane & 15;    // feats fo*8 .. fo*8+7
  int h = fo >> 2;       // head for these 8 feats
  int beg = rowptr[n], end = rowptr[n + 1];
  float adh = ad1[n * 4 + h];

  f32x2 acc2[4];
#pragma unroll
  for (int j = 0; j < 4; ++j) acc2[j] = (f32x2){0.f, 0.f};
  float esum = 0.f;

#define ACC_EDGE1(E)                                            \
  {                                                             \
    int src = col[E];                                           \
    float a = expf(lrelu(as1[src * 4 + h] + adh));              \
    esum += a;                                                  \
    f32x2 av = {a, a};                                          \
    uint4 uu = h1b4[src * 16 + fo];                             \
    acc2[0] += av * (f32x2){bfl(uu.x), bfh(uu.x)};              \
    acc2[1] += av * (f32x2){bfl(uu.y), bfh(uu.y)};              \
    acc2[2] += av * (f32x2){bfl(uu.z), bfh(uu.z)};              \
    acc2[3] += av * (f32x2){bfl(uu.w), bfh(uu.w)};              \
  }

  int i = beg;
  for (; i + 16 <= end; i += 16) {
#pragma unroll
    for (int u = 0; u < 4; ++u) ACC_EDGE1(i + u * 4 + slot);
  }
  for (; i + 4 <= end; i += 4) ACC_EDGE1(i + slot);
  int rem = end - i;
  if (slot < rem) ACC_EDGE1(i + slot);
  // self loop (slot 0 only -> counted once after reduction)
  if (slot == 0) ACC_EDGE1_SELF: {
    float a = expf(lrelu(as1[n * 4 + h] + adh));
    esum += a;
    f32x2 av = {a, a};
    uint4 uu = h1b4[n * 16 + fo];
    acc2[0] += av * (f32x2){bfl(uu.x), bfh(uu.x)};
    acc2[1] += av * (f32x2){bfl(uu.y), bfh(uu.y)};
    acc2[2] += av * (f32x2){bfl(uu.z), bfh(uu.z)};
    acc2[3] += av * (f32x2){bfl(uu.w), bfh(uu.w)};
  }
#pragma unroll
  for (int j = 0; j < 4; ++j) {
    acc2[j].x += __shfl_xor(acc2[j].x, 16);
    acc2[j].y += __shfl_xor(acc2[j].y, 16);
    acc2[j].x += __shfl_xor(acc2[j].x, 32);
    acc2[j].y += __shfl_xor(acc2[j].y, 32);
  }
  esum += __shfl_xor(esum, 16);
  esum += __shfl_xor(esum, 32);
  if (slot == 0) {
    float dsc = 1.f / esum;
    float4 b0 = b1v[fo * 2], b1 = b1v[fo * 2 + 1];
    float f0 = elu(acc2[0].x * dsc + b0.x), f1 = elu(acc2[0].y * dsc + b0.y);
    float f2 = elu(acc2[1].x * dsc + b0.z), f3 = elu(acc2[1].y * dsc + b0.w);
    float f4 = elu(acc2[2].x * dsc + b1.x), f5 = elu(acc2[2].y * dsc + b1.y);
    float f6 = elu(acc2[3].x * dsc + b1.z), f7 = elu(acc2[3].y * dsc + b1.w);
    uint4 o;
    o.x = pack2bf(f0, f1); o.y = pack2bf(f2, f3);
    o.z = pack2bf(f4, f5); o.w = pack2bf(f6, f7);
    h1eb4[n * 16 + fo] = o;
  }
#undef ACC_EDGE1
}

// ---------------- layer-2 gather, fused e + denom + global add pool ----------------
__global__ __launch_bounds__(256) void agg2_kernel(const uint4* __restrict__ h2b4, const int* __restrict__ rowptr,
                                                   const int* __restrict__ col, const float* __restrict__ as2,
                                                   const float* __restrict__ ad2, const float4* __restrict__ b2v,
                                                   float* __restrict__ pooled) {
  __shared__ float red[4][64];
  int n = (blockIdx.x * 256 + threadIdx.x) >> 6;
  int lane = threadIdx.x & 63;
  int wid = threadIdx.x >> 6;
  int slot = lane >> 3;  // 0..7
  int fo = lane & 7;     // feats fo*8 .. fo*8+7
  int beg = rowptr[n], end = rowptr[n + 1];
  float ad = ad2[n];

  f32x2 acc2[4];
#pragma unroll
  for (int j = 0; j < 4; ++j) acc2[j] = (f32x2){0.f, 0.f};
  float esum = 0.f;

#define ACC_EDGE2(E)                                            \
  {                                                             \
    int src = col[E];                                           \
    float a = expf(lrelu(as2[src] + ad));                       \
    esum += a;                                                  \
    f32x2 av = {a, a};                                          \
    uint4 uu = h2b4[src * 8 + fo];                              \
    acc2[0] += av * (f32x2){bfl(uu.x), bfh(uu.x)};              \
    acc2[1] += av * (f32x2){bfl(uu.y), bfh(uu.y)};              \
    acc2[2] += av * (f32x2){bfl(uu.z), bfh(uu.z)};              \
    acc2[3] += av * (f32x2){bfl(uu.w), bfh(uu.w)};              \
  }

  int i = beg;
  for (; i + 32 <= end; i += 32) {
#pragma unroll
    for (int u = 0; u < 4; ++u) ACC_EDGE2(i + u * 8 + slot);
  }
  for (; i + 8 <= end; i += 8) ACC_EDGE2(i + slot);
  int rem = end - i;
  if (slot < rem) ACC_EDGE2(i + slot);
  // self loop
  if (slot == 0) {
    float a = expf(lrelu(as2[n] + ad));
    esum += a;
    f32x2 av = {a, a};
    uint4 uu = h2b4[n * 8 + fo];
    acc2[0] += av * (f32x2){bfl(uu.x), bfh(uu.x)};
    acc2[1] += av * (f32x2){bfl(uu.y), bfh(uu.y)};
    acc2[2] += av * (f32x2){bfl(uu.z), bfh(uu.z)};
    acc2[3] += av * (f32x2){bfl(uu.w), bfh(uu.w)};
  }
#pragma unroll
  for (int j = 0; j < 4; ++j) {
#pragma unroll
    for (int off = 8; off <= 32; off <<= 1) {
      acc2[j].x += __shfl_xor(acc2[j].x, off);
      acc2[j].y += __shfl_xor(acc2[j].y, off);
    }
  }
  esum += __shfl_xor(esum, 8);
  esum += __shfl_xor(esum, 16);
  esum += __shfl_xor(esum, 32);
  if (slot == 0) {
    float dsc = 1.f / esum;
    float4 b0 = b2v[fo * 2], b1 = b2v[fo * 2 + 1];
    red[wid][fo * 8 + 0] = elu(acc2[0].x * dsc + b0.x);
    red[wid][fo * 8 + 1] = elu(acc2[0].y * dsc + b0.y);
    red[wid][fo * 8 + 2] = elu(acc2[1].x * dsc + b0.z);
    red[wid][fo * 8 + 3] = elu(acc2[1].y * dsc + b0.w);
    red[wid][fo * 8 + 4] = elu(acc2[2].x * dsc + b1.x);
    red[wid][fo * 8 + 5] = elu(acc2[2].y * dsc + b1.y);
    red[wid][fo * 8 + 6] = elu(acc2[3].x * dsc + b1.z);
    red[wid][fo * 8 + 7] = elu(acc2[3].y * dsc + b1.w);
  }
  __syncthreads();
  if (threadIdx.x < 64) {
    float sum = red[0][threadIdx.x] + red[1][threadIdx.x] + red[2][threadIdx.x] + red[3][threadIdx.x];
    atomicAdd(&pooled[(blockIdx.x & 63) * 64 + threadIdx.x], sum);
  }
#undef ACC_EDGE2
}

// ---------------- final: reduce pooled stripes + pooled@Wl+bl ----------------
__global__ void final_kernel(const float* __restrict__ pooledS, const float* __restrict__ Wl,
                             const float* __restrict__ bl, float* __restrict__ out) {
  __shared__ float p[64];
  int t = threadIdx.x;
  float v = 0.f;
  for (int k = 0; k < 64; ++k) v += pooledS[k * 64 + t];
  p[t] = v;
  out[t] = v;
  __syncthreads();
  if (t < 2) {
    float s = bl[t];
    for (int k = 0; k < 64; ++k) s += p[k] * Wl[k * 2 + t];
    out[64 + t] = s;
  }
}

extern "C" void kernel_launch(void* const* d_in, const int* in_sizes, int n_in,
                              void* d_out, int out_size, void* d_ws, size_t ws_size,
                              hipStream_t stream) {
  (void)in_sizes; (void)n_in; (void)out_size; (void)ws_size;
  const float* x     = (const float*)d_in[0];
  const int*   ei    = (const int*)d_in[1];
  const float* W1    = (const float*)d_in[2];
  const float* atts1 = (const float*)d_in[3];
  const float* attd1 = (const float*)d_in[4];
  const float* b1    = (const float*)d_in[5];
  const float* W2    = (const float*)d_in[6];
  const float* atts2 = (const float*)d_in[7];
  const float* attd2 = (const float*)d_in[8];
  const float* b2    = (const float*)d_in[9];
  const float* Wl    = (const float*)d_in[10];
  const float* bl    = (const float*)d_in[11];
  float* out = (float*)d_out;

  char* w = (char*)d_ws;
  unsigned* h1b  = (unsigned*)w; w += (size_t)N_NODES * 128 * 2;  // 12.8 MB bf16
  unsigned* h1eb = (unsigned*)w; w += (size_t)N_NODES * 128 * 2;  // 12.8 MB bf16
  unsigned* h2b  = (unsigned*)w; w += (size_t)N_NODES * 64 * 2;   // 6.4 MB bf16
  float* as1  = (float*)w; w += (size_t)N_NODES * 16;
  float* ad1  = (float*)w; w += (size_t)N_NODES * 16;
  float* as2  = (float*)w; w += (size_t)N_NODES * 4;
  float* ad2  = (float*)w; w += (size_t)N_NODES * 4;
  int* deg    = (int*)w; w += (size_t)N_NODES * 4;
  float* pooled = (float*)w; w += 64 * 64 * 4;                    // 64 stripes x 64
  int* rowptr = (int*)w; w += (size_t)(N_NODES + 1) * 4 + 12;
  int* col    = (int*)w; w += (size_t)N_EDGES * 4;
  int* rank   = (int*)w; w += (size_t)N_EDGES * 4;
  int* blocksum = (int*)w; w += 256 * 4;
  int* blockoff = (int*)w; w += 256 * 4;

  // zero deg + pooled (contiguous)
  hipMemsetAsync(deg, 0, (size_t)N_NODES * 4 + 64 * 64 * 4, stream);

  // hist (atomic-bound) co-scheduled with gemm128 (VALU/LDS-bound)
  gemm128_hist_kernel<<<HIST_BLOCKS + GEMM_BLOCKS, 256, 0, stream>>>(x, W1, atts1, attd1, h1b, as1, ad1,
                                                                     ei, deg, rank);
  scan_part_kernel<<<SCAN_BLOCKS, 256, 0, stream>>>(deg, rowptr, blocksum);
  scan_top_kernel<<<1, 256, 0, stream>>>(blocksum, blockoff);
  scan_add_kernel<<<SCAN_BLOCKS, 256, 0, stream>>>(blockoff, rowptr);
  scatter_kernel<<<HIST_BLOCKS, 256, 0, stream>>>(ei, rowptr, rank, col);

  agg1_kernel<<<N_NODES / 4, 256, 0, stream>>>((const uint4*)h1b, rowptr, col, as1, ad1,
                                               (const float4*)b1, (uint4*)h1eb);

  gemm64_kernel<<<GEMM_BLOCKS, 256, 0, stream>>>(h1eb, W2, atts2, attd2, h2b, as2, ad2);
  agg2_kernel<<<N_NODES / 4, 256, 0, stream>>>((const uint4*)h2b, rowptr, col, as2, ad2,
                                               (const float4*)b2, pooled);

  final_kernel<<<1, 64, 0, stream>>>(pooled, Wl, bl, out);
}

// Round 12
// 265.731 us; speedup vs baseline: 2.9967x; 1.0219x over previous
//
#include <hip/hip_runtime.h>

#define N_NODES 50000
#define N_EDGES 800000
#define SCAN_BLOCKS ((N_NODES + 255) / 256)   // 196
#define HIST_BLOCKS ((N_EDGES + 255) / 256)   // 3125
#define GEMM_BLOCKS ((N_NODES + 63) / 64)     // 782
#define FUSED_BLOCKS (5 * GEMM_BLOCKS)        // 3910: 4 hist-role + 1 gemm-role per 5

__device__ __forceinline__ float lrelu(float x) { return fmaxf(x, 0.2f * x); }
__device__ __forceinline__ float elu(float x) { return x > 0.f ? x : __expf(x) - 1.f; }

typedef float f32x2 __attribute__((ext_vector_type(2)));

// bf16 helpers: lo/hi halves of a uint holding 2 consecutive bf16 elements
__device__ __forceinline__ float bfl(unsigned u) { return __uint_as_float(u << 16); }
__device__ __forceinline__ float bfh(unsigned u) { return __uint_as_float(u & 0xffff0000u); }
__device__ __forceinline__ unsigned f2bf_rn(float x) {
  unsigned u = __float_as_uint(x);
  return (u + 0x7fffu + ((u >> 16) & 1u)) >> 16;
}
__device__ __forceinline__ unsigned pack2bf(float a, float b) {
  return f2bf_rn(a) | (f2bf_rn(b) << 16);
}

// ---------------- scan ----------------
__device__ __forceinline__ int block_excl_scan(int v, int* total_out) {
  int lane = threadIdx.x & 63;
  int wid = threadIdx.x >> 6;
  int x = v;
#pragma unroll
  for (int off = 1; off < 64; off <<= 1) {
    int u = __shfl_up(x, off);
    if (lane >= off) x += u;
  }
  __shared__ int wsum[4];
  if (lane == 63) wsum[wid] = x;
  __syncthreads();
  int add = 0;
#pragma unroll
  for (int k = 0; k < 4; ++k)
    if (k < wid) add += wsum[k];
  if (total_out) *total_out = wsum[0] + wsum[1] + wsum[2] + wsum[3];
  return x + add - v;
}

__global__ __launch_bounds__(256) void scan_part_kernel(const int* __restrict__ deg, int* __restrict__ rowptr,
                                                        int* __restrict__ blocksum) {
  int g = blockIdx.x * 256 + threadIdx.x;
  int v = (g < N_NODES) ? deg[g] : 0;
  int total;
  int ex = block_excl_scan(v, &total);
  if (g < N_NODES) rowptr[g] = ex;
  if (threadIdx.x == 0) blocksum[blockIdx.x] = total;
}

__global__ __launch_bounds__(256) void scan_top_kernel(const int* __restrict__ blocksum, int* __restrict__ blockoff) {
  int t = threadIdx.x;
  int v = (t < SCAN_BLOCKS) ? blocksum[t] : 0;
  int ex = block_excl_scan(v, nullptr);
  if (t < SCAN_BLOCKS) blockoff[t] = ex;
}

__global__ __launch_bounds__(256) void scan_add_kernel(const int* __restrict__ blockoff, int* __restrict__ rowptr) {
  int g = blockIdx.x * 256 + threadIdx.x;
  if (g < N_NODES) rowptr[g] += blockoff[g >> 8];
  if (g == 0) rowptr[N_NODES] = N_EDGES;
}

__global__ __launch_bounds__(256) void scatter_kernel(const int* __restrict__ ei, const int* __restrict__ rowptr,
                                                      const int* __restrict__ rank, int* __restrict__ col) {
  int e = blockIdx.x * 256 + threadIdx.x;
  if (e < N_EDGES) {
    int d = ei[N_EDGES + e];
    col[rowptr[d] + rank[e]] = ei[e];
  }
}

// ---------------- GEMM body + fused attention dots ----------------
// K staged in 4 phases of 32 rows: LDS = 32*COLS*4 + 64*36*4 (25 KB for COLS=128)
// -> 6 blocks/CU so interleaved hist blocks keep high occupancy.
// ws swizzled [k][c4][tx] (2-way, free); xs row stride 36 (2-way, free).
#define XS_STRIDE 36
template <int COLS, bool ABF16>
__device__ __forceinline__ void gemm_body(int bx, const void* __restrict__ Ap, const float* __restrict__ W,
                                          const float* __restrict__ atts, const float* __restrict__ attd,
                                          unsigned* __restrict__ Yb, float* __restrict__ as_out,
                                          float* __restrict__ ad_out) {
  constexpr int CPT = COLS / 16;   // cols per thread (8 or 4)
  constexpr int G = COLS / 4;      // float4 groups per k-row (32 or 16)
  __shared__ float ws[32 * COLS];
  __shared__ float xs[64 * XS_STRIDE];
  int t = threadIdx.x;
  int rbase = bx * 64;
  int tx = t & 15, ty = t >> 4;
  float acc[4][CPT];
#pragma unroll
  for (int r = 0; r < 4; ++r)
#pragma unroll
    for (int c = 0; c < CPT; ++c) acc[r][c] = 0.f;

  const float4* W4 = (const float4*)W;
  float4* ws4 = (float4*)ws;
  for (int kt = 0; kt < 4; ++kt) {
    for (int i = t; i < 32 * G; i += 256) {
      int k = i / G;
      int g = i - k * G;
      int c4g = g & (CPT / 4 - 1);
      int txg = g / (CPT / 4);
      ws4[k * G + c4g * 16 + txg] = W4[kt * 32 * G + i];
    }
    if constexpr (ABF16) {
      const uint4* A4 = (const uint4*)Ap;  // row = 128 bf16 = 16 uint4; 4 per phase
      {
        int i = t;  // exactly 256 items
        int row = i >> 2, q = i & 3;
        int gr = rbase + row; if (gr >= N_NODES) gr = N_NODES - 1;
        uint4 u = A4[gr * 16 + kt * 4 + q];
        float4 lo = make_float4(bfl(u.x), bfh(u.x), bfl(u.y), bfh(u.y));
        float4 hi = make_float4(bfl(u.z), bfh(u.z), bfl(u.w), bfh(u.w));
        float4* dst = (float4*)&xs[row * XS_STRIDE + q * 8];
        dst[0] = lo; dst[1] = hi;
      }
    } else {
      const float4* A4 = (const float4*)Ap;  // row = 32 float4; 8 per phase
      for (int i = t; i < 512; i += 256) {
        int row = i >> 3, kc = i & 7;
        int gr = rbase + row; if (gr >= N_NODES) gr = N_NODES - 1;
        *(float4*)&xs[row * XS_STRIDE + kc * 4] = A4[gr * 32 + kt * 8 + kc];
      }
    }
    __syncthreads();
#pragma unroll 8
    for (int k = 0; k < 32; ++k) {
      float xr[4];
#pragma unroll
      for (int r = 0; r < 4; ++r) xr[r] = xs[(ty * 4 + r) * XS_STRIDE + k];
#pragma unroll
      for (int c4 = 0; c4 < CPT / 4; ++c4) {
        float4 wv = ws4[k * G + c4 * 16 + tx];
#pragma unroll
        for (int r = 0; r < 4; ++r) {
          acc[r][c4 * 4 + 0] += xr[r] * wv.x;
          acc[r][c4 * 4 + 1] += xr[r] * wv.y;
          acc[r][c4 * 4 + 2] += xr[r] * wv.z;
          acc[r][c4 * 4 + 3] += xr[r] * wv.w;
        }
      }
    }
    __syncthreads();
  }

  // fused attention dots
  if constexpr (COLS == 128) {
    int h = tx >> 2;
    int base = h * 32 + (tx & 3) * 8;
#pragma unroll
    for (int r = 0; r < 4; ++r) {
      float ps = 0.f, pd = 0.f;
#pragma unroll
      for (int c = 0; c < 8; ++c) {
        ps += acc[r][c] * atts[base + c];
        pd += acc[r][c] * attd[base + c];
      }
      ps += __shfl_xor(ps, 1); pd += __shfl_xor(pd, 1);
      ps += __shfl_xor(ps, 2); pd += __shfl_xor(pd, 2);
      int row = rbase + ty * 4 + r;
      if ((tx & 3) == 0 && row < N_NODES) {
        as_out[row * 4 + h] = ps;
        ad_out[row * 4 + h] = pd;
      }
    }
  } else {
#pragma unroll
    for (int r = 0; r < 4; ++r) {
      float ps = 0.f, pd = 0.f;
#pragma unroll
      for (int c = 0; c < 4; ++c) {
        ps += acc[r][c] * atts[tx * 4 + c];
        pd += acc[r][c] * attd[tx * 4 + c];
      }
#pragma unroll
      for (int off = 1; off < 16; off <<= 1) {
        ps += __shfl_xor(ps, off);
        pd += __shfl_xor(pd, off);
      }
      int row = rbase + ty * 4 + r;
      if (tx == 0 && row < N_NODES) {
        as_out[row] = ps;
        ad_out[row] = pd;
      }
    }
  }

#pragma unroll
  for (int r = 0; r < 4; ++r) {
    int row = rbase + ty * 4 + r;
    if (row < N_NODES) {
      if constexpr (CPT == 8) {
        uint4 o;
        o.x = pack2bf(acc[r][0], acc[r][1]);
        o.y = pack2bf(acc[r][2], acc[r][3]);
        o.z = pack2bf(acc[r][4], acc[r][5]);
        o.w = pack2bf(acc[r][6], acc[r][7]);
        ((uint4*)Yb)[row * 16 + tx] = o;
      } else {
        uint2 o;
        o.x = pack2bf(acc[r][0], acc[r][1]);
        o.y = pack2bf(acc[r][2], acc[r][3]);
        ((uint2*)Yb)[row * 16 + tx] = o;
      }
    }
  }
}

// ---------------- fused hist + gemm128, roles INTERLEAVED 4:1 ----------------
// role = bx % 5: 0..3 -> histogram blocks, 4 -> GEMM block. Both populations
// are co-resident for the whole dispatch, so the atomic-bound histogram and
// the VALU/LDS-bound GEMM overlap instead of serializing.
__global__ __launch_bounds__(256) void gemm128_hist_kernel(const float* __restrict__ x, const float* __restrict__ W1,
                                                           const float* __restrict__ atts, const float* __restrict__ attd,
                                                           unsigned* __restrict__ h1b, float* __restrict__ as1,
                                                           float* __restrict__ ad1, const int* __restrict__ ei,
                                                           int* __restrict__ deg, int* __restrict__ rank) {
  int role = blockIdx.x % 5;
  int base = blockIdx.x / 5;
  if (role != 4) {
    int e = (base * 4 + role) * 256 + threadIdx.x;
    if (e < N_EDGES) rank[e] = atomicAdd(&deg[ei[N_EDGES + e]], 1);
    return;
  }
  gemm_body<128, false>(base, x, W1, atts, attd, h1b, as1, ad1);
}

__global__ __launch_bounds__(256) void gemm64_kernel(const unsigned* __restrict__ h1eb, const float* __restrict__ W2,
                                                     const float* __restrict__ atts, const float* __restrict__ attd,
                                                     unsigned* __restrict__ h2b, float* __restrict__ as2,
                                                     float* __restrict__ ad2) {
  gemm_body<64, true>(blockIdx.x, h1eb, W2, atts, attd, h2b, as2, ad2);
}

// ---------------- layer-1 gather, fused e-compute + denom; f32x2 packed FMA ----------------
__global__ __launch_bounds__(256) void agg1_kernel(const uint4* __restrict__ h1b4, const int* __restrict__ rowptr,
                                                   const int* __restrict__ col, const float* __restrict__ as1,
                                                   const float* __restrict__ ad1, const float4* __restrict__ b1v,
                                                   uint4* __restrict__ h1eb4) {
  int n = (blockIdx.x * 256 + threadIdx.x) >> 6;
  int lane = threadIdx.x & 63;
  int slot = lane >> 4;  // 0..3
  int fo = lane & 15;    // feats fo*8 .. fo*8+7
  int h = fo >> 2;       // head for these 8 feats
  int beg = rowptr[n], end = rowptr[n + 1];
  float adh = ad1[n * 4 + h];

  f32x2 acc2[4];
#pragma unroll
  for (int j = 0; j < 4; ++j) acc2[j] = (f32x2){0.f, 0.f};
  float esum = 0.f;

#define ACC_EDGE1(E)                                            \
  {                                                             \
    int src = col[E];                                           \
    float a = __expf(lrelu(as1[src * 4 + h] + adh));            \
    esum += a;                                                  \
    f32x2 av = {a, a};                                          \
    uint4 uu = h1b4[src * 16 + fo];                             \
    acc2[0] += av * (f32x2){bfl(uu.x), bfh(uu.x)};              \
    acc2[1] += av * (f32x2){bfl(uu.y), bfh(uu.y)};              \
    acc2[2] += av * (f32x2){bfl(uu.z), bfh(uu.z)};              \
    acc2[3] += av * (f32x2){bfl(uu.w), bfh(uu.w)};              \
  }

  int i = beg;
  for (; i + 16 <= end; i += 16) {
#pragma unroll
    for (int u = 0; u < 4; ++u) ACC_EDGE1(i + u * 4 + slot);
  }
  for (; i + 4 <= end; i += 4) ACC_EDGE1(i + slot);
  int rem = end - i;
  if (slot < rem) ACC_EDGE1(i + slot);
  // self loop (slot 0 only -> counted once after reduction)
  if (slot == 0) {
    float a = __expf(lrelu(as1[n * 4 + h] + adh));
    esum += a;
    f32x2 av = {a, a};
    uint4 uu = h1b4[n * 16 + fo];
    acc2[0] += av * (f32x2){bfl(uu.x), bfh(uu.x)};
    acc2[1] += av * (f32x2){bfl(uu.y), bfh(uu.y)};
    acc2[2] += av * (f32x2){bfl(uu.z), bfh(uu.z)};
    acc2[3] += av * (f32x2){bfl(uu.w), bfh(uu.w)};
  }
#pragma unroll
  for (int j = 0; j < 4; ++j) {
    acc2[j].x += __shfl_xor(acc2[j].x, 16);
    acc2[j].y += __shfl_xor(acc2[j].y, 16);
    acc2[j].x += __shfl_xor(acc2[j].x, 32);
    acc2[j].y += __shfl_xor(acc2[j].y, 32);
  }
  esum += __shfl_xor(esum, 16);
  esum += __shfl_xor(esum, 32);
  if (slot == 0) {
    float dsc = 1.f / esum;
    float4 b0 = b1v[fo * 2], b1 = b1v[fo * 2 + 1];
    float f0 = elu(acc2[0].x * dsc + b0.x), f1 = elu(acc2[0].y * dsc + b0.y);
    float f2 = elu(acc2[1].x * dsc + b0.z), f3 = elu(acc2[1].y * dsc + b0.w);
    float f4 = elu(acc2[2].x * dsc + b1.x), f5 = elu(acc2[2].y * dsc + b1.y);
    float f6 = elu(acc2[3].x * dsc + b1.z), f7 = elu(acc2[3].y * dsc + b1.w);
    uint4 o;
    o.x = pack2bf(f0, f1); o.y = pack2bf(f2, f3);
    o.z = pack2bf(f4, f5); o.w = pack2bf(f6, f7);
    h1eb4[n * 16 + fo] = o;
  }
#undef ACC_EDGE1
}

// ---------------- layer-2 gather, fused e + denom + global add pool ----------------
__global__ __launch_bounds__(256) void agg2_kernel(const uint4* __restrict__ h2b4, const int* __restrict__ rowptr,
                                                   const int* __restrict__ col, const float* __restrict__ as2,
                                                   const float* __restrict__ ad2, const float4* __restrict__ b2v,
                                                   float* __restrict__ pooled) {
  __shared__ float red[4][64];
  int n = (blockIdx.x * 256 + threadIdx.x) >> 6;
  int lane = threadIdx.x & 63;
  int wid = threadIdx.x >> 6;
  int slot = lane >> 3;  // 0..7
  int fo = lane & 7;     // feats fo*8 .. fo*8+7
  int beg = rowptr[n], end = rowptr[n + 1];
  float ad = ad2[n];

  f32x2 acc2[4];
#pragma unroll
  for (int j = 0; j < 4; ++j) acc2[j] = (f32x2){0.f, 0.f};
  float esum = 0.f;

#define ACC_EDGE2(E)                                            \
  {                                                             \
    int src = col[E];                                           \
    float a = __expf(lrelu(as2[src] + ad));                     \
    esum += a;                                                  \
    f32x2 av = {a, a};                                          \
    uint4 uu = h2b4[src * 8 + fo];                              \
    acc2[0] += av * (f32x2){bfl(uu.x), bfh(uu.x)};              \
    acc2[1] += av * (f32x2){bfl(uu.y), bfh(uu.y)};              \
    acc2[2] += av * (f32x2){bfl(uu.z), bfh(uu.z)};              \
    acc2[3] += av * (f32x2){bfl(uu.w), bfh(uu.w)};              \
  }

  int i = beg;
  for (; i + 32 <= end; i += 32) {
#pragma unroll
    for (int u = 0; u < 4; ++u) ACC_EDGE2(i + u * 8 + slot);
  }
  for (; i + 8 <= end; i += 8) ACC_EDGE2(i + slot);
  int rem = end - i;
  if (slot < rem) ACC_EDGE2(i + slot);
  // self loop
  if (slot == 0) {
    float a = __expf(lrelu(as2[n] + ad));
    esum += a;
    f32x2 av = {a, a};
    uint4 uu = h2b4[n * 8 + fo];
    acc2[0] += av * (f32x2){bfl(uu.x), bfh(uu.x)};
    acc2[1] += av * (f32x2){bfl(uu.y), bfh(uu.y)};
    acc2[2] += av * (f32x2){bfl(uu.z), bfh(uu.z)};
    acc2[3] += av * (f32x2){bfl(uu.w), bfh(uu.w)};
  }
#pragma unroll
  for (int j = 0; j < 4; ++j) {
#pragma unroll
    for (int off = 8; off <= 32; off <<= 1) {
      acc2[j].x += __shfl_xor(acc2[j].x, off);
      acc2[j].y += __shfl_xor(acc2[j].y, off);
    }
  }
  esum += __shfl_xor(esum, 8);
  esum += __shfl_xor(esum, 16);
  esum += __shfl_xor(esum, 32);
  if (slot == 0) {
    float dsc = 1.f / esum;
    float4 b0 = b2v[fo * 2], b1 = b2v[fo * 2 + 1];
    red[wid][fo * 8 + 0] = elu(acc2[0].x * dsc + b0.x);
    red[wid][fo * 8 + 1] = elu(acc2[0].y * dsc + b0.y);
    red[wid][fo * 8 + 2] = elu(acc2[1].x * dsc + b0.z);
    red[wid][fo * 8 + 3] = elu(acc2[1].y * dsc + b0.w);
    red[wid][fo * 8 + 4] = elu(acc2[2].x * dsc + b1.x);
    red[wid][fo * 8 + 5] = elu(acc2[2].y * dsc + b1.y);
    red[wid][fo * 8 + 6] = elu(acc2[3].x * dsc + b1.z);
    red[wid][fo * 8 + 7] = elu(acc2[3].y * dsc + b1.w);
  }
  __syncthreads();
  if (threadIdx.x < 64) {
    float sum = red[0][threadIdx.x] + red[1][threadIdx.x] + red[2][threadIdx.x] + red[3][threadIdx.x];
    atomicAdd(&pooled[(blockIdx.x & 63) * 64 + threadIdx.x], sum);
  }
#undef ACC_EDGE2
}

// ---------------- final: reduce pooled stripes + pooled@Wl+bl ----------------
__global__ void final_kernel(const float* __restrict__ pooledS, const float* __restrict__ Wl,
                             const float* __restrict__ bl, float* __restrict__ out) {
  __shared__ float p[64];
  int t = threadIdx.x;
  float v = 0.f;
  for (int k = 0; k < 64; ++k) v += pooledS[k * 64 + t];
  p[t] = v;
  out[t] = v;
  __syncthreads();
  if (t < 2) {
    float s = bl[t];
    for (int k = 0; k < 64; ++k) s += p[k] * Wl[k * 2 + t];
    out[64 + t] = s;
  }
}

extern "C" void kernel_launch(void* const* d_in, const int* in_sizes, int n_in,
                              void* d_out, int out_size, void* d_ws, size_t ws_size,
                              hipStream_t stream) {
  (void)in_sizes; (void)n_in; (void)out_size; (void)ws_size;
  const float* x     = (const float*)d_in[0];
  const int*   ei    = (const int*)d_in[1];
  const float* W1    = (const float*)d_in[2];
  const float* atts1 = (const float*)d_in[3];
  const float* attd1 = (const float*)d_in[4];
  const float* b1    = (const float*)d_in[5];
  const float* W2    = (const float*)d_in[6];
  const float* atts2 = (const float*)d_in[7];
  const float* attd2 = (const float*)d_in[8];
  const float* b2    = (const float*)d_in[9];
  const float* Wl    = (const float*)d_in[10];
  const float* bl    = (const float*)d_in[11];
  float* out = (float*)d_out;

  char* w = (char*)d_ws;
  unsigned* h1b  = (unsigned*)w; w += (size_t)N_NODES * 128 * 2;  // 12.8 MB bf16
  unsigned* h1eb = (unsigned*)w; w += (size_t)N_NODES * 128 * 2;  // 12.8 MB bf16
  unsigned* h2b  = (unsigned*)w; w += (size_t)N_NODES * 64 * 2;   // 6.4 MB bf16
  float* as1  = (float*)w; w += (size_t)N_NODES * 16;
  float* ad1  = (float*)w; w += (size_t)N_NODES * 16;
  float* as2  = (float*)w; w += (size_t)N_NODES * 4;
  float* ad2  = (float*)w; w += (size_t)N_NODES * 4;
  int* deg    = (int*)w; w += (size_t)N_NODES * 4;
  float* pooled = (float*)w; w += 64 * 64 * 4;                    // 64 stripes x 64
  int* rowptr = (int*)w; w += (size_t)(N_NODES + 1) * 4 + 12;
  int* col    = (int*)w; w += (size_t)N_EDGES * 4;
  int* rank   = (int*)w; w += (size_t)N_EDGES * 4;
  int* blocksum = (int*)w; w += 256 * 4;
  int* blockoff = (int*)w; w += 256 * 4;

  // zero deg + pooled (contiguous)
  hipMemsetAsync(deg, 0, (size_t)N_NODES * 4 + 64 * 64 * 4, stream);

  // hist (atomic-bound) interleaved 4:1 with gemm128 (VALU/LDS-bound)
  gemm128_hist_kernel<<<FUSED_BLOCKS, 256, 0, stream>>>(x, W1, atts1, attd1, h1b, as1, ad1,
                                                        ei, deg, rank);
  scan_part_kernel<<<SCAN_BLOCKS, 256, 0, stream>>>(deg, rowptr, blocksum);
  scan_top_kernel<<<1, 256, 0, stream>>>(blocksum, blockoff);
  scan_add_kernel<<<SCAN_BLOCKS, 256, 0, stream>>>(blockoff, rowptr);
  scatter_kernel<<<HIST_BLOCKS, 256, 0, stream>>>(ei, rowptr, rank, col);

  agg1_kernel<<<N_NODES / 4, 256, 0, stream>>>((const uint4*)h1b, rowptr, col, as1, ad1,
                                               (const float4*)b1, (uint4*)h1eb);

  gemm64_kernel<<<GEMM_BLOCKS, 256, 0, stream>>>(h1eb, W2, atts2, attd2, h2b, as2, ad2);
  agg2_kernel<<<N_NODES / 4, 256, 0, stream>>>((const uint4*)h2b, rowptr, col, as2, ad2,
                                               (const float4*)b2, pooled);

  final_kernel<<<1, 64, 0, stream>>>(pooled, Wl, bl, out);
}